// Round 2
// baseline (4131.068 us; speedup 1.0000x reference)
//
#include <hip/hip_runtime.h>
#include <hip/hip_bf16.h>

#define N_NODES 30000
#define N_GRAPHS 256
#define HEADS 4

// ---------------------------------------------------------------------------
// index helpers: harness may deliver int64 or int32 indices; a device-side
// probe sets flags[0] (edge_index is64) and flags[1] (batch is64).
// ---------------------------------------------------------------------------
__device__ __forceinline__ int ld_idx(const void* p, long i, int is64) {
    return is64 ? (int)((const long long*)p)[i] : ((const int*)p)[i];
}
__device__ __forceinline__ int clampi(int v, int hi) {
    return v < 0 ? 0 : (v > hi ? hi : v);
}

__global__ void detect_fmt(const void* ei, const void* batch, int E, int* flags)
{
    __shared__ int okE, okB;
    if (threadIdx.x == 0) { okE = 1; okB = 1; }
    __syncthreads();
    const long long* e64 = (const long long*)ei;
    const long long* b64 = (const long long*)batch;
    const int nbslot = N_NODES / 2;           // safe slot count if batch is int32
    for (int i = threadIdx.x; i < 2048; i += 256) {
        long ei_idx = (long)i * E / 2048;     // sample src slots [0,E)
        long long v = e64[ei_idx];
        if (v < 0 || v >= N_NODES) okE = 0;
        long b_idx = (long)i * nbslot / 2048;
        long long b = b64[b_idx];
        if (b < 0 || b >= N_GRAPHS) okB = 0;
    }
    __syncthreads();
    if (threadIdx.x == 0) { flags[0] = okE; flags[1] = okB; }
}

// ---------------------------------------------------------------------------
// f32 tiled GEMM: C[M,N] = A[M,K] @ B[K,N] (+bias, relu), strided.
// ---------------------------------------------------------------------------
#define TS 64
#define KS 32
__global__ __launch_bounds__(256) void gemm_f32(const float* __restrict__ A, int lda,
                                                const float* __restrict__ B, int ldb,
                                                float* __restrict__ C, int ldc,
                                                int M, int N, int K,
                                                const float* __restrict__ bias,
                                                int do_relu)
{
    __shared__ float As[KS][TS + 1];
    __shared__ float Bs[KS][TS + 1];
    const int tid = threadIdx.x;
    const int tx = tid & 15;
    const int ty = tid >> 4;
    const int row0 = blockIdx.y * TS;
    const int col0 = blockIdx.x * TS;

    float acc[4][4] = {};

    for (int k0 = 0; k0 < K; k0 += KS) {
        for (int i = tid; i < TS * KS; i += 256) {
            int r = i >> 5, c = i & (KS - 1);
            int gr = row0 + r, gc = k0 + c;
            As[c][r] = (gr < M && gc < K) ? A[(long)gr * lda + gc] : 0.f;
        }
        for (int i = tid; i < KS * TS; i += 256) {
            int r = i >> 6, c = i & (TS - 1);
            int gr = k0 + r, gc = col0 + c;
            Bs[r][c] = (gr < K && gc < N) ? B[(long)gr * ldb + gc] : 0.f;
        }
        __syncthreads();
#pragma unroll
        for (int kk = 0; kk < KS; ++kk) {
            float a[4], b[4];
#pragma unroll
            for (int i = 0; i < 4; ++i) a[i] = As[kk][ty * 4 + i];
#pragma unroll
            for (int j = 0; j < 4; ++j) b[j] = Bs[kk][tx * 4 + j];
#pragma unroll
            for (int i = 0; i < 4; ++i)
#pragma unroll
                for (int j = 0; j < 4; ++j) acc[i][j] += a[i] * b[j];
        }
        __syncthreads();
    }

#pragma unroll
    for (int i = 0; i < 4; ++i) {
        int gr = row0 + ty * 4 + i;
        if (gr >= M) continue;
#pragma unroll
        for (int j = 0; j < 4; ++j) {
            int gc = col0 + tx * 4 + j;
            if (gc >= N) continue;
            float v = acc[i][j];
            if (bias) v += bias[gc];
            if (do_relu) v = fmaxf(v, 0.f);
            C[(long)gr * ldc + gc] = v;
        }
    }
}

// ---------------------------------------------------------------------------
// Wd[k,h] = sum_c W[k, h*C+c] * att[h, c]     (dst half)
// Ws[k,h] = sum_c W[k, h*C+c] * att[h, C+c]   (src half)
// ---------------------------------------------------------------------------
__global__ void make_watt(const float* __restrict__ W, const float* __restrict__ att,
                          float* __restrict__ Wd, float* __restrict__ Ws,
                          int K, int C, int HC)
{
    int i = blockIdx.x * blockDim.x + threadIdx.x;
    if (i >= K * HEADS) return;
    int k = i >> 2, h = i & 3;
    const float* wrow = W + (long)k * HC + h * C;
    const float* ad = att + h * 2 * C;
    const float* as = ad + C;
    float s1 = 0.f, s2 = 0.f;
    for (int c = 0; c < C; ++c) { float w = wrow[c]; s1 += w * ad[c]; s2 += w * as[c]; }
    Wd[k * HEADS + h] = s1;
    Ws[k * HEADS + h] = s2;
}

// ---------------------------------------------------------------------------
// adst[n,h] = A[n,:] @ Wd[:,h];  asrc[n,h] = A[n,:] @ Ws[:,h].  Wave per node.
// ---------------------------------------------------------------------------
__global__ __launch_bounds__(256) void node_proj(const float* __restrict__ A, int K,
                                                 const float* __restrict__ Wd,
                                                 const float* __restrict__ Ws,
                                                 float* __restrict__ adst,
                                                 float* __restrict__ asrc, int N)
{
    const int wv = threadIdx.x >> 6, lane = threadIdx.x & 63;
    const int n = blockIdx.x * 4 + wv;
    if (n >= N) return;
    const float* a = A + (long)n * K;
    float sd[HEADS] = {}, ss[HEADS] = {};
    for (int k = lane; k < K; k += 64) {
        float v = a[k];
#pragma unroll
        for (int h = 0; h < HEADS; ++h) {
            sd[h] += v * Wd[k * HEADS + h];
            ss[h] += v * Ws[k * HEADS + h];
        }
    }
#pragma unroll
    for (int off = 32; off; off >>= 1) {
#pragma unroll
        for (int h = 0; h < HEADS; ++h) {
            sd[h] += __shfl_down(sd[h], off);
            ss[h] += __shfl_down(ss[h], off);
        }
    }
    if (lane == 0) {
#pragma unroll
        for (int h = 0; h < HEADS; ++h) {
            adst[n * HEADS + h] = sd[h];
            asrc[n * HEADS + h] = ss[h];
        }
    }
}

// ---------------------------------------------------------------------------
// Per-edge softmax over heads -> ALPHA[E,4]
// ---------------------------------------------------------------------------
__global__ void edge_alpha(const void* __restrict__ ei, const int* __restrict__ flags,
                           const float* __restrict__ adst, const float* __restrict__ asrc,
                           float* __restrict__ alpha, int E)
{
    int e = blockIdx.x * blockDim.x + threadIdx.x;
    if (e >= E) return;
    int is64 = flags[0];
    int s = clampi(ld_idx(ei, e, is64), N_NODES - 1);
    int d = clampi(ld_idx(ei, (long)E + e, is64), N_NODES - 1);
    float a[HEADS], m = -1e30f;
#pragma unroll
    for (int h = 0; h < HEADS; ++h) {
        float v = adst[d * HEADS + h] + asrc[s * HEADS + h];
        v = (v > 0.f) ? v : 0.2f * v;
        a[h] = v;
        m = fmaxf(m, v);
    }
    float sum = 0.f;
#pragma unroll
    for (int h = 0; h < HEADS; ++h) { a[h] = __expf(a[h] - m); sum += a[h]; }
    float inv = 1.f / sum;
#pragma unroll
    for (int h = 0; h < HEADS; ++h) alpha[(long)e * HEADS + h] = a[h] * inv;
}

// ---------------------------------------------------------------------------
// agg[dst, :FC] += xh[src, :FC] * alpha[e,h].  One wave per edge.
// ---------------------------------------------------------------------------
__global__ __launch_bounds__(256) void scatter_chunk(const void* __restrict__ ei,
                                                     const int* __restrict__ flags,
                                                     const float* __restrict__ alpha,
                                                     const float* __restrict__ xh,
                                                     float* __restrict__ agg,
                                                     int FC, int h, int E)
{
    const int wv = threadIdx.x >> 6, lane = threadIdx.x & 63;
    const int e = blockIdx.x * 4 + wv;
    if (e >= E) return;
    int is64 = flags[0];
    int s = clampi(ld_idx(ei, e, is64), N_NODES - 1);
    int d = clampi(ld_idx(ei, (long)E + e, is64), N_NODES - 1);
    float w = alpha[(long)e * HEADS + h];
    const float* xs = xh + (long)s * FC;
    float* ag = agg + (long)d * FC;
    for (int c = lane; c < FC; c += 64)
        unsafeAtomicAdd(&ag[c], xs[c] * w);
}

// ---------------------------------------------------------------------------
// out[n, col0+c] = relu(agg[n,c] + b[c])   (layers 1,2)
// ---------------------------------------------------------------------------
__global__ void bias_relu_chunk(const float* __restrict__ agg, const float* __restrict__ b,
                                float* __restrict__ out, int FC, int ldo, int col0, long N)
{
    long total = N * FC;
    long stride = (long)gridDim.x * blockDim.x;
    for (long i = (long)blockIdx.x * blockDim.x + threadIdx.x; i < total; i += stride) {
        long n = i / FC;
        int c = (int)(i - n * FC);
        out[n * ldo + col0 + c] = fmaxf(agg[i] + b[c], 0.f);
    }
}

// ---------------------------------------------------------------------------
// layer3: relu(agg+b) then segment-max straight into G (pre-zeroed).
// ---------------------------------------------------------------------------
__global__ void bias_relu_pool(const float* __restrict__ agg, const float* __restrict__ b,
                               const void* __restrict__ batch, const int* __restrict__ flags,
                               float* __restrict__ G, int FC, int col0, long N)
{
    long total = N * FC;
    long stride = (long)gridDim.x * blockDim.x;
    int is64 = flags[1];
    for (long i = (long)blockIdx.x * blockDim.x + threadIdx.x; i < total; i += stride) {
        long n = i / FC;
        int c = (int)(i - n * FC);
        float v = fmaxf(agg[i] + b[c], 0.f);
        int g = clampi(ld_idx(batch, n, is64), N_GRAPHS - 1);
        atomicMax((unsigned int*)&G[(long)g * 1248 + col0 + c], __float_as_uint(v));
    }
}

// ---------------------------------------------------------------------------
extern "C" void kernel_launch(void* const* d_in, const int* in_sizes, int n_in,
                              void* d_out, int out_size, void* d_ws, size_t ws_size,
                              hipStream_t stream)
{
    const float* x    = (const float*)d_in[0];
    const void*  ei   = d_in[1];
    const void*  batch= d_in[2];
    const float* W1   = (const float*)d_in[3];
    const float* att1 = (const float*)d_in[4];
    const float* b1   = (const float*)d_in[5];
    const float* W2   = (const float*)d_in[6];
    const float* att2 = (const float*)d_in[7];
    const float* b2   = (const float*)d_in[8];
    const float* W3   = (const float*)d_in[9];
    const float* att3 = (const float*)d_in[10];
    const float* b3   = (const float*)d_in[11];
    const float* Wg1  = (const float*)d_in[12];
    const float* bg1  = (const float*)d_in[13];
    const float* Wg2  = (const float*)d_in[14];
    const float* bg2  = (const float*)d_in[15];
    const float* Wo   = (const float*)d_in[16];
    const float* bo   = (const float*)d_in[17];

    const int N = N_NODES;
    const int E = in_sizes[1] / 2;

    // ---- workspace layout (floats), peak ~155 MB ----
    float* ws = (float*)d_ws;
    float* H2  = ws;                       // 18,720,000  (N x 624)
    float* H1  = ws + 18720000;            //  9,360,000  (N x 312)
    float* SCR = ws + 28080000;            //  9,360,000  scratch
    float* SM  = ws + 37440000;
    float* ADST  = SM;                     // 120,000
    float* ASRC  = SM + 120000;            // 120,000
    float* ALPHA = SM + 240000;            // 400,000
    float* WD    = SM + 640000;            // 4,096
    float* WSRC  = SM + 644096;            // 4,096
    float* G     = SM + 648192;            // 319,488 (256 x 1248)
    float* G1    = SM + 967680;            // 262,144
    float* G2    = SM + 1229824;           // 32,768
    int*   FLAGS = (int*)(SM + 1262592);

    dim3 blk(256);

    detect_fmt<<<dim3(1), blk, 0, stream>>>(ei, batch, E, FLAGS);

    // per-layer config
    struct Layer { const float* A; int K; const float* W; const float* att;
                   const float* b; int HC; int C; float* XH; float* AGG;
                   float* out; int pool; };
    Layer L[3] = {
        { x,  78,  W1, att1, b1, 312,  78, SCR, SCR + 2340000, H1, 0 },
        { H1, 312, W2, att2, b2, 624, 156, SCR, SCR + 4680000, H2, 0 },
        { H2, 624, W3, att3, b3, 1248, 312, H1,  SCR,          G,  1 },
    };

    for (int li = 0; li < 3; ++li) {
        const Layer& l = L[li];
        // attention projection vectors + per-node logits + per-edge alpha
        make_watt<<<dim3((l.K * HEADS + 255) / 256), blk, 0, stream>>>(
            l.W, l.att, WD, WSRC, l.K, l.C, l.HC);
        node_proj<<<dim3((N + 3) / 4), blk, 0, stream>>>(l.A, l.K, WD, WSRC, ADST, ASRC, N);
        edge_alpha<<<dim3((E + 255) / 256), blk, 0, stream>>>(ei, FLAGS, ADST, ASRC, ALPHA, E);

        if (l.pool)
            hipMemsetAsync(G, 0, (size_t)N_GRAPHS * 1248 * sizeof(float), stream);

        for (int h = 0; h < HEADS; ++h) {
            const int FC = l.C;
            const int col0 = h * FC;
            dim3 gg((FC + TS - 1) / TS, (N + TS - 1) / TS);
            gemm_f32<<<gg, blk, 0, stream>>>(l.A, l.K, l.W + col0, l.HC,
                                             l.XH, FC, N, FC, l.K, nullptr, 0);
            hipMemsetAsync(l.AGG, 0, (size_t)N * FC * sizeof(float), stream);
            scatter_chunk<<<dim3((E + 3) / 4), blk, 0, stream>>>(
                ei, FLAGS, ALPHA, l.XH, l.AGG, FC, h, E);
            if (l.pool)
                bias_relu_pool<<<dim3(2048), blk, 0, stream>>>(
                    l.AGG, l.b + col0, batch, FLAGS, G, FC, col0, (long)N);
            else
                bias_relu_chunk<<<dim3(2048), blk, 0, stream>>>(
                    l.AGG, l.b + col0, l.out, FC, l.HC, col0, (long)N);
        }
    }

    // ---- MLP head ----
    {
        dim3 g1((1024 + TS - 1) / TS, (N_GRAPHS + TS - 1) / TS);
        gemm_f32<<<g1, blk, 0, stream>>>(G, 1248, Wg1, 1024, G1, 1024,
                                         N_GRAPHS, 1024, 1248, bg1, 1);
        dim3 g2((128 + TS - 1) / TS, (N_GRAPHS + TS - 1) / TS);
        gemm_f32<<<g2, blk, 0, stream>>>(G1, 1024, Wg2, 128, G2, 128,
                                         N_GRAPHS, 128, 1024, bg2, 0);
        dim3 g3(1, (N_GRAPHS + TS - 1) / TS);
        gemm_f32<<<g3, blk, 0, stream>>>(G2, 128, Wo, 1, (float*)d_out, 1,
                                         N_GRAPHS, 1, 128, bo, 0);
    }
}

// Round 3
// 1585.795 us; speedup vs baseline: 2.6050x; 2.6050x over previous
//
#include <hip/hip_runtime.h>
#include <hip/hip_bf16.h>

#define N_NODES 30000
#define N_GRAPHS 256
#define HEADS 4

typedef __attribute__((ext_vector_type(8))) short short8;
typedef __attribute__((ext_vector_type(4))) float f32x4;
typedef unsigned short ushort_t;

__device__ __forceinline__ ushort_t f2bf(float v) {
    __hip_bfloat16 h = __float2bfloat16(v);
    return *reinterpret_cast<ushort_t*>(&h);
}
__device__ __forceinline__ float bf2f(ushort_t u) {
    __hip_bfloat16 h;
    *reinterpret_cast<ushort_t*>(&h) = u;
    return __bfloat162float(h);
}
__device__ __forceinline__ int ld_idx(const void* p, long i, int is64) {
    return is64 ? (int)((const long long*)p)[i] : ((const int*)p)[i];
}
__device__ __forceinline__ int clampi(int v, int hi) {
    return v < 0 ? 0 : (v > hi ? hi : v);
}

// ---------------------------------------------------------------------------
__global__ void detect_fmt(const void* ei, const void* batch, int E, int* flags)
{
    __shared__ int okE, okB;
    if (threadIdx.x == 0) { okE = 1; okB = 1; }
    __syncthreads();
    const long long* e64 = (const long long*)ei;
    const long long* b64 = (const long long*)batch;
    const int nbslot = N_NODES / 2;
    for (int i = threadIdx.x; i < 2048; i += 256) {
        long ei_idx = (long)i * E / 2048;
        long long v = e64[ei_idx];
        if (v < 0 || v >= N_NODES) okE = 0;
        long b_idx = (long)i * nbslot / 2048;
        long long b = b64[b_idx];
        if (b < 0 || b >= N_GRAPHS) okB = 0;
    }
    __syncthreads();
    if (threadIdx.x == 0) { flags[0] = okE; flags[1] = okB; }
}

// ---------------------------------------------------------------------------
// CSR build (by dst)
// ---------------------------------------------------------------------------
__global__ void csr_hist(const void* ei, const int* __restrict__ flags,
                         int* __restrict__ indeg, int E)
{
    int i = blockIdx.x * blockDim.x + threadIdx.x;
    if (i >= E) return;
    int d = clampi(ld_idx(ei, (long)E + i, flags[0]), N_NODES - 1);
    atomicAdd(&indeg[d], 1);
}

__global__ __launch_bounds__(1024) void csr_scan(const int* __restrict__ indeg,
                                                 int* __restrict__ off,
                                                 int* __restrict__ cursor)
{
    __shared__ int ps[1024];
    const int t = threadIdx.x;
    const int CH = (N_NODES + 1023) / 1024;
    const int base = t * CH;
    int s = 0;
    for (int i = 0; i < CH; ++i) { int idx = base + i; if (idx < N_NODES) s += indeg[idx]; }
    ps[t] = s;
    __syncthreads();
    for (int d = 1; d < 1024; d <<= 1) {
        int v = (t >= d) ? ps[t - d] : 0;
        __syncthreads();
        ps[t] += v;
        __syncthreads();
    }
    int excl = (t == 0) ? 0 : ps[t - 1];
    for (int i = 0; i < CH; ++i) {
        int idx = base + i;
        if (idx < N_NODES) { off[idx] = excl; cursor[idx] = excl; excl += indeg[idx]; }
    }
    if (t == 1023) off[N_NODES] = ps[1023];
}

__global__ void csr_fill(const void* ei, const int* __restrict__ flags,
                         int* __restrict__ cursor, int* __restrict__ slots, int E)
{
    int i = blockIdx.x * blockDim.x + threadIdx.x;
    if (i >= E) return;
    int d = clampi(ld_idx(ei, (long)E + i, flags[0]), N_NODES - 1);
    int p = atomicAdd(&cursor[d], 1);
    slots[p] = i;
}

// ---------------------------------------------------------------------------
// conversions
// ---------------------------------------------------------------------------
__global__ void conv_pad_bf16(const float* __restrict__ src, ushort_t* __restrict__ dst,
                              int K, int Kp, long M)
{
    long total = M * Kp;
    long stride = (long)gridDim.x * blockDim.x;
    for (long i = (long)blockIdx.x * blockDim.x + threadIdx.x; i < total; i += stride) {
        long n = i / Kp;
        int k = (int)(i - n * Kp);
        dst[i] = (k < K) ? f2bf(src[n * K + k]) : (ushort_t)0;
    }
}

// WT[n][kp] = bf16(W[k][n]), zero-padded k>=K
__global__ void wt_bf16(const float* __restrict__ W, ushort_t* __restrict__ WT,
                        int K, int Kp, int HC)
{
    int nch = Kp >> 3;
    int i = blockIdx.x * blockDim.x + threadIdx.x;
    if (i >= HC * nch) return;
    int n = i / nch, c8 = i - n * nch;
#pragma unroll
    for (int e = 0; e < 8; ++e) {
        int k = c8 * 8 + e;
        WT[(long)n * Kp + k] = (k < K) ? f2bf(W[(long)k * HC + n]) : (ushort_t)0;
    }
}

// ---------------------------------------------------------------------------
// Wd[k,h], Ws[k,h] = per-head att projections of W (f32, exact)
// ---------------------------------------------------------------------------
__global__ void make_watt(const float* __restrict__ W, const float* __restrict__ att,
                          float* __restrict__ Wd, float* __restrict__ Wsv,
                          int K, int C, int HC)
{
    int i = blockIdx.x * blockDim.x + threadIdx.x;
    if (i >= K * HEADS) return;
    int k = i >> 2, h = i & 3;
    const float* wrow = W + (long)k * HC + h * C;
    const float* ad = att + h * 2 * C;
    const float* as = ad + C;
    float s1 = 0.f, s2 = 0.f;
    for (int c = 0; c < C; ++c) { float w = wrow[c]; s1 += w * ad[c]; s2 += w * as[c]; }
    Wd[k * HEADS + h] = s1;
    Wsv[k * HEADS + h] = s2;
}

// ---------------------------------------------------------------------------
// adst/asrc per node. A may be f32 (lda,K) or bf16 padded (lda=Kp).
// ---------------------------------------------------------------------------
__global__ __launch_bounds__(256) void node_proj_any(const void* __restrict__ A,
                                                     int lda, int K, int isbf,
                                                     const float* __restrict__ Wd,
                                                     const float* __restrict__ Wsv,
                                                     float* __restrict__ adst,
                                                     float* __restrict__ asrc, int N)
{
    const int wv = threadIdx.x >> 6, lane = threadIdx.x & 63;
    const int n = blockIdx.x * 4 + wv;
    if (n >= N) return;
    float sd[HEADS] = {}, ss[HEADS] = {};
    for (int k = lane; k < K; k += 64) {
        float v = isbf ? bf2f(((const ushort_t*)A)[(long)n * lda + k])
                       : ((const float*)A)[(long)n * lda + k];
#pragma unroll
        for (int h = 0; h < HEADS; ++h) {
            sd[h] += v * Wd[k * HEADS + h];
            ss[h] += v * Wsv[k * HEADS + h];
        }
    }
#pragma unroll
    for (int off = 32; off; off >>= 1) {
#pragma unroll
        for (int h = 0; h < HEADS; ++h) {
            sd[h] += __shfl_down(sd[h], off);
            ss[h] += __shfl_down(ss[h], off);
        }
    }
    if (lane == 0) {
#pragma unroll
        for (int h = 0; h < HEADS; ++h) {
            adst[n * HEADS + h] = sd[h];
            asrc[n * HEADS + h] = ss[h];
        }
    }
}

// ---------------------------------------------------------------------------
__global__ void edge_alpha(const void* __restrict__ ei, const int* __restrict__ flags,
                           const float* __restrict__ adst, const float* __restrict__ asrc,
                           float* __restrict__ alpha, int E)
{
    int e = blockIdx.x * blockDim.x + threadIdx.x;
    if (e >= E) return;
    int is64 = flags[0];
    int s = clampi(ld_idx(ei, e, is64), N_NODES - 1);
    int d = clampi(ld_idx(ei, (long)E + e, is64), N_NODES - 1);
    float a[HEADS], m = -1e30f;
#pragma unroll
    for (int h = 0; h < HEADS; ++h) {
        float v = adst[d * HEADS + h] + asrc[s * HEADS + h];
        v = (v > 0.f) ? v : 0.2f * v;
        a[h] = v;
        m = fmaxf(m, v);
    }
    float sum = 0.f;
#pragma unroll
    for (int h = 0; h < HEADS; ++h) { a[h] = __expf(a[h] - m); sum += a[h]; }
    float inv = 1.f / sum;
#pragma unroll
    for (int h = 0; h < HEADS; ++h) alpha[(long)e * HEADS + h] = a[h] * inv;
}

// ---------------------------------------------------------------------------
// bf16 MFMA GEMM: C[M][FC] (bf16) = A[M][Kp] @ WT[col0+n][Kp]^T
// BM=128 BN=64 BK=64, 4 waves (2x2), XOR-swizzled LDS, reg-staged.
// ---------------------------------------------------------------------------
#define BM 128
#define BN 64
#define BK 64
__global__ __launch_bounds__(256) void gemm_bf16(const ushort_t* __restrict__ A,
                                                 const ushort_t* __restrict__ WT,
                                                 ushort_t* __restrict__ C,
                                                 int M, int FC, int Kp,
                                                 int col0, int HCtot)
{
    __shared__ ushort_t As[BM * BK];
    __shared__ ushort_t Bs[BN * BK];
    const int tid = threadIdx.x;
    const int lane = tid & 63;
    const int wid = tid >> 6;
    const int wm = wid >> 1, wn = wid & 1;
    const int row0 = blockIdx.y * BM;
    const int colb = blockIdx.x * BN;

    f32x4 acc[4][2];
#pragma unroll
    for (int i = 0; i < 4; ++i)
#pragma unroll
        for (int j = 0; j < 2; ++j) { f32x4 z = {0.f, 0.f, 0.f, 0.f}; acc[i][j] = z; }

    short8 ra[4], rb[2];

    auto loadG = [&](int k0) {
#pragma unroll
        for (int r = 0; r < 4; ++r) {
            int id = r * 256 + tid;
            int row = id >> 3, j = id & 7;
            long grow = min(row0 + row, M - 1);
            ra[r] = *(const short8*)&A[grow * Kp + k0 + j * 8];
        }
#pragma unroll
        for (int r = 0; r < 2; ++r) {
            int id = r * 256 + tid;
            int row = id >> 3, j = id & 7;
            long gcol = min(col0 + colb + row, HCtot - 1);
            rb[r] = *(const short8*)&WT[gcol * Kp + k0 + j * 8];
        }
    };

    loadG(0);
    for (int k0 = 0; k0 < Kp; k0 += BK) {
        __syncthreads();   // previous iteration's LDS readers done
#pragma unroll
        for (int r = 0; r < 4; ++r) {
            int id = r * 256 + tid;
            int row = id >> 3, j = id & 7;
            *(short8*)&As[row * BK + ((j ^ (row & 7)) << 3)] = ra[r];
        }
#pragma unroll
        for (int r = 0; r < 2; ++r) {
            int id = r * 256 + tid;
            int row = id >> 3, j = id & 7;
            *(short8*)&Bs[row * BK + ((j ^ (row & 7)) << 3)] = rb[r];
        }
        __syncthreads();
        if (k0 + BK < Kp) loadG(k0 + BK);   // prefetch overlaps MFMA below
#pragma unroll
        for (int ks = 0; ks < 2; ++ks) {
            short8 af[4], bfr[2];
            const int jr = ks * 4 + (lane >> 4);
#pragma unroll
            for (int fm = 0; fm < 4; ++fm) {
                int row = wm * 64 + fm * 16 + (lane & 15);
                af[fm] = *(const short8*)&As[row * BK + ((jr ^ (row & 7)) << 3)];
            }
#pragma unroll
            for (int fn = 0; fn < 2; ++fn) {
                int row = wn * 32 + fn * 16 + (lane & 15);
                bfr[fn] = *(const short8*)&Bs[row * BK + ((jr ^ (row & 7)) << 3)];
            }
#pragma unroll
            for (int fm = 0; fm < 4; ++fm)
#pragma unroll
                for (int fn = 0; fn < 2; ++fn)
                    acc[fm][fn] = __builtin_amdgcn_mfma_f32_16x16x32_bf16(
                        af[fm], bfr[fn], acc[fm][fn], 0, 0, 0);
        }
    }

#pragma unroll
    for (int fm = 0; fm < 4; ++fm) {
        int rbase = row0 + wm * 64 + fm * 16 + (lane >> 4) * 4;
#pragma unroll
        for (int fn = 0; fn < 2; ++fn) {
            int col = colb + wn * 32 + fn * 16 + (lane & 15);
            if (col >= FC) continue;
#pragma unroll
            for (int r = 0; r < 4; ++r) {
                int gr = rbase + r;
                if (gr < M) C[(long)gr * FC + col] = f2bf(acc[fm][fn][r]);
            }
        }
    }
}

// ---------------------------------------------------------------------------
// CSR gather: out[n, col0+c] = relu(bias[c] + sum_e alpha[e,h]*xh[src_e, c])
// layers 1/2: write bf16 H (ldo-wide); layer 3: atomicMax into G pool.
// ---------------------------------------------------------------------------
__global__ __launch_bounds__(256) void gat_gather(const int* __restrict__ off,
                                                  const int* __restrict__ slots,
                                                  const void* __restrict__ ei,
                                                  const int* __restrict__ flags,
                                                  const float* __restrict__ alpha,
                                                  const ushort_t* __restrict__ xh,
                                                  const float* __restrict__ bias,
                                                  ushort_t* __restrict__ outb,
                                                  float* __restrict__ G,
                                                  const void* __restrict__ batch,
                                                  int FC, int col0, int ldo, int h)
{
    const int wv = threadIdx.x >> 6, lane = threadIdx.x & 63;
    const int n = blockIdx.x * 4 + wv;
    if (n >= N_NODES) return;
    const int is64 = flags[0];
    float acc[5] = {0.f, 0.f, 0.f, 0.f, 0.f};
    const int s0 = off[n], s1 = off[n + 1];
    for (int i = s0; i < s1; ++i) {
        int e = slots[i];
        float w = alpha[(long)e * HEADS + h];
        int s = clampi(ld_idx(ei, e, is64), N_NODES - 1);
        const ushort_t* xs = xh + (long)s * FC;
        int r = 0;
        for (int c = lane; c < FC; c += 64, ++r)
            acc[r] += w * bf2f(xs[c]);
    }
    if (G) {
        int g = clampi(ld_idx(batch, n, flags[1]), N_GRAPHS - 1);
        int r = 0;
        for (int c = lane; c < FC; c += 64, ++r) {
            float v = fmaxf(acc[r] + bias[c], 0.f);
            atomicMax((unsigned int*)&G[(long)g * 1248 + col0 + c], __float_as_uint(v));
        }
    } else {
        int r = 0;
        for (int c = lane; c < FC; c += 64, ++r) {
            float v = fmaxf(acc[r] + bias[c], 0.f);
            outb[(long)n * ldo + col0 + c] = f2bf(v);
        }
    }
}

// ---------------------------------------------------------------------------
// f32 tiled GEMM (MLP head only)
// ---------------------------------------------------------------------------
#define TS 64
#define KS 32
__global__ __launch_bounds__(256) void gemm_f32(const float* __restrict__ A, int lda,
                                                const float* __restrict__ B, int ldb,
                                                float* __restrict__ C, int ldc,
                                                int M, int N, int K,
                                                const float* __restrict__ bias,
                                                int do_relu)
{
    __shared__ float Asf[KS][TS + 1];
    __shared__ float Bsf[KS][TS + 1];
    const int tid = threadIdx.x;
    const int tx = tid & 15;
    const int ty = tid >> 4;
    const int row0 = blockIdx.y * TS;
    const int col0 = blockIdx.x * TS;

    float acc[4][4] = {};

    for (int k0 = 0; k0 < K; k0 += KS) {
        for (int i = tid; i < TS * KS; i += 256) {
            int r = i >> 5, c = i & (KS - 1);
            int gr = row0 + r, gc = k0 + c;
            Asf[c][r] = (gr < M && gc < K) ? A[(long)gr * lda + gc] : 0.f;
        }
        for (int i = tid; i < KS * TS; i += 256) {
            int r = i >> 6, c = i & (TS - 1);
            int gr = k0 + r, gc = col0 + c;
            Bsf[r][c] = (gr < K && gc < N) ? B[(long)gr * ldb + gc] : 0.f;
        }
        __syncthreads();
#pragma unroll
        for (int kk = 0; kk < KS; ++kk) {
            float a[4], b[4];
#pragma unroll
            for (int i = 0; i < 4; ++i) a[i] = Asf[kk][ty * 4 + i];
#pragma unroll
            for (int j = 0; j < 4; ++j) b[j] = Bsf[kk][tx * 4 + j];
#pragma unroll
            for (int i = 0; i < 4; ++i)
#pragma unroll
                for (int j = 0; j < 4; ++j) acc[i][j] += a[i] * b[j];
        }
        __syncthreads();
    }

#pragma unroll
    for (int i = 0; i < 4; ++i) {
        int gr = row0 + ty * 4 + i;
        if (gr >= M) continue;
#pragma unroll
        for (int j = 0; j < 4; ++j) {
            int gc = col0 + tx * 4 + j;
            if (gc >= N) continue;
            float v = acc[i][j];
            if (bias) v += bias[gc];
            if (do_relu) v = fmaxf(v, 0.f);
            C[(long)gr * ldc + gc] = v;
        }
    }
}

// ---------------------------------------------------------------------------
extern "C" void kernel_launch(void* const* d_in, const int* in_sizes, int n_in,
                              void* d_out, int out_size, void* d_ws, size_t ws_size,
                              hipStream_t stream)
{
    const float* x    = (const float*)d_in[0];
    const void*  ei   = d_in[1];
    const void*  batch= d_in[2];
    const float* W1   = (const float*)d_in[3];
    const float* att1 = (const float*)d_in[4];
    const float* b1   = (const float*)d_in[5];
    const float* W2   = (const float*)d_in[6];
    const float* att2 = (const float*)d_in[7];
    const float* b2   = (const float*)d_in[8];
    const float* W3   = (const float*)d_in[9];
    const float* att3 = (const float*)d_in[10];
    const float* b3   = (const float*)d_in[11];
    const float* Wg1  = (const float*)d_in[12];
    const float* bg1  = (const float*)d_in[13];
    const float* Wg2  = (const float*)d_in[14];
    const float* bg2  = (const float*)d_in[15];
    const float* Wo   = (const float*)d_in[16];
    const float* bo   = (const float*)d_in[17];

    const int N = N_NODES;
    const int E = in_sizes[1] / 2;

    // ---- workspace layout (float units), total ~92 MB ----
    float* ws = (float*)d_ws;
    ushort_t* H1b  = (ushort_t*)ws;                        // 30000*320 shorts = 4.8M fl
    ushort_t* H2b  = (ushort_t*)(ws + 4800000);            // 30000*640 shorts = 9.6M fl
    ushort_t* ABF1 = (ushort_t*)(ws + 14400000);           // 30000*128 shorts = 1.92M fl
    ushort_t* XHb  = (ushort_t*)(ws + 16320000);           // 30000*312 shorts = 4.68M fl
    ushort_t* WT   = (ushort_t*)(ws + 21000000);           // 1248*640 shorts  = 0.4M fl
    float* ADST  = ws + 21400000;                          // 120000
    float* ASRC  = ws + 21520000;                          // 120000
    float* ALPHA = ws + 21640000;                          // 400000
    float* WD    = ws + 22040000;                          // 4096
    float* WSV   = ws + 22044096;                          // 4096
    float* G     = ws + 22048192;                          // 319488
    float* G1    = ws + 22367680;                          // 262144
    float* G2    = ws + 22629824;                          // 32768
    int*   INDEG = (int*)(ws + 22662592);                  // 30000
    int*   OFF   = (int*)(ws + 22692592);                  // 30001
    int*   CURS  = (int*)(ws + 22722593);                  // 30000
    int*   SLOTS = (int*)(ws + 22752593);                  // E (<=100000)
    int*   FLAGS = (int*)(ws + 22852593);                  // 2

    dim3 blk(256);

    detect_fmt<<<dim3(1), blk, 0, stream>>>(ei, batch, E, FLAGS);

    // zero pad-columns of H buffers + pool target + CSR counters
    hipMemsetAsync(H1b, 0, (size_t)N * 320 * sizeof(ushort_t), stream);
    hipMemsetAsync(H2b, 0, (size_t)N * 640 * sizeof(ushort_t), stream);
    hipMemsetAsync(G, 0, (size_t)N_GRAPHS * 1248 * sizeof(float), stream);
    hipMemsetAsync(INDEG, 0, (size_t)N * sizeof(int), stream);

    // CSR build (once, reused by all 12 gathers)
    csr_hist<<<dim3((E + 255) / 256), blk, 0, stream>>>(ei, FLAGS, INDEG, E);
    csr_scan<<<dim3(1), dim3(1024), 0, stream>>>(INDEG, OFF, CURS);
    csr_fill<<<dim3((E + 255) / 256), blk, 0, stream>>>(ei, FLAGS, CURS, SLOTS, E);

    // layer-1 input to bf16 (padded K: 78 -> 128)
    conv_pad_bf16<<<dim3(8192), blk, 0, stream>>>(x, ABF1, 78, 128, (long)N);

    struct Layer {
        const void* A; int lda; int K; int isbf;   // node_proj input
        const ushort_t* Abf; int Kp;               // gemm A
        const float *W, *att, *b;
        int C, HC;
        ushort_t* outb; int ldo;                   // layers 1,2
        int pool;                                  // layer 3
    };
    Layer L[3] = {
        { x,   78,  78,  0, ABF1, 128, W1, att1, b1,  78,  312, H1b, 320, 0 },
        { H1b, 320, 312, 1, H1b,  320, W2, att2, b2, 156,  624, H2b, 640, 0 },
        { H2b, 640, 624, 1, H2b,  640, W3, att3, b3, 312, 1248, nullptr, 0, 1 },
    };

    const dim3 gemmGridY((N + BM - 1) / BM);   // 235

    for (int li = 0; li < 3; ++li) {
        const Layer& l = L[li];
        // weight transpose+convert, attention vectors, logits, per-edge alpha
        int nch = l.Kp >> 3;
        wt_bf16<<<dim3((l.HC * nch + 255) / 256), blk, 0, stream>>>(l.W, WT, l.K, l.Kp, l.HC);
        make_watt<<<dim3((l.K * HEADS + 255) / 256), blk, 0, stream>>>(l.W, l.att, WD, WSV, l.K, l.C, l.HC);
        node_proj_any<<<dim3((N + 3) / 4), blk, 0, stream>>>(l.A, l.lda, l.K, l.isbf, WD, WSV, ADST, ASRC, N);
        edge_alpha<<<dim3((E + 255) / 256), blk, 0, stream>>>(ei, FLAGS, ADST, ASRC, ALPHA, E);

        for (int h = 0; h < HEADS; ++h) {
            const int FC = l.C;
            const int col0 = h * FC;
            dim3 gg((FC + BN - 1) / BN, gemmGridY.x);
            gemm_bf16<<<gg, blk, 0, stream>>>(l.Abf, WT, XHb, N, FC, l.Kp, col0, l.HC);
            gat_gather<<<dim3((N + 3) / 4), blk, 0, stream>>>(
                OFF, SLOTS, ei, FLAGS, ALPHA, XHb, l.b + col0,
                l.pool ? nullptr : l.outb, l.pool ? G : nullptr, batch,
                FC, col0, l.ldo, h);
        }
    }

    // ---- MLP head (f32, exact path near output) ----
    {
        dim3 g1((1024 + TS - 1) / TS, (N_GRAPHS + TS - 1) / TS);
        gemm_f32<<<g1, blk, 0, stream>>>(G, 1248, Wg1, 1024, G1, 1024,
                                         N_GRAPHS, 1024, 1248, bg1, 1);
        dim3 g2((128 + TS - 1) / TS, (N_GRAPHS + TS - 1) / TS);
        gemm_f32<<<g2, blk, 0, stream>>>(G1, 1024, Wg2, 128, G2, 128,
                                         N_GRAPHS, 128, 1024, bg2, 0);
        dim3 g3(1, (N_GRAPHS + TS - 1) / TS);
        gemm_f32<<<g3, blk, 0, stream>>>(G2, 128, Wo, 1, (float*)d_out, 1,
                                         N_GRAPHS, 1, 128, bo, 0);
    }
}

// Round 4
// 1008.325 us; speedup vs baseline: 4.0970x; 1.5727x over previous
//
#include <hip/hip_runtime.h>
#include <hip/hip_bf16.h>

#define N_NODES 30000
#define N_GRAPHS 256
#define HEADS 4

typedef __attribute__((ext_vector_type(8))) short short8;
typedef __attribute__((ext_vector_type(4))) float f32x4;
typedef __attribute__((ext_vector_type(4))) unsigned short ushort4_t;
typedef unsigned short ushort_t;

__device__ __forceinline__ ushort_t f2bf(float v) {
    __hip_bfloat16 h = __float2bfloat16(v);
    return *reinterpret_cast<ushort_t*>(&h);
}
__device__ __forceinline__ float bf2f(ushort_t u) {
    __hip_bfloat16 h;
    *reinterpret_cast<ushort_t*>(&h) = u;
    return __bfloat162float(h);
}
__device__ __forceinline__ int ld_idx(const void* p, long i, int is64) {
    return is64 ? (int)((const long long*)p)[i] : ((const int*)p)[i];
}
__device__ __forceinline__ int clampi(int v, int hi) {
    return v < 0 ? 0 : (v > hi ? hi : v);
}

// ---------------------------------------------------------------------------
__global__ void detect_fmt(const void* ei, const void* batch, int E, int* flags)
{
    __shared__ int okE, okB;
    if (threadIdx.x == 0) { okE = 1; okB = 1; }
    __syncthreads();
    const long long* e64 = (const long long*)ei;
    const long long* b64 = (const long long*)batch;
    const int nbslot = N_NODES / 2;
    for (int i = threadIdx.x; i < 2048; i += 256) {
        long ei_idx = (long)i * E / 2048;
        long long v = e64[ei_idx];
        if (v < 0 || v >= N_NODES) okE = 0;
        long b_idx = (long)i * nbslot / 2048;
        long long b = b64[b_idx];
        if (b < 0 || b >= N_GRAPHS) okB = 0;
    }
    __syncthreads();
    if (threadIdx.x == 0) { flags[0] = okE; flags[1] = okB; }
}

// ---------------------------------------------------------------------------
// CSR build (by dst)
// ---------------------------------------------------------------------------
__global__ void csr_hist(const void* ei, const int* __restrict__ flags,
                         int* __restrict__ indeg, int E)
{
    int i = blockIdx.x * blockDim.x + threadIdx.x;
    if (i >= E) return;
    int d = clampi(ld_idx(ei, (long)E + i, flags[0]), N_NODES - 1);
    atomicAdd(&indeg[d], 1);
}

__global__ __launch_bounds__(1024) void csr_scan(const int* __restrict__ indeg,
                                                 int* __restrict__ off,
                                                 int* __restrict__ cursor)
{
    __shared__ int ps[1024];
    const int t = threadIdx.x;
    const int CH = (N_NODES + 1023) / 1024;
    const int base = t * CH;
    int s = 0;
    for (int i = 0; i < CH; ++i) { int idx = base + i; if (idx < N_NODES) s += indeg[idx]; }
    ps[t] = s;
    __syncthreads();
    for (int d = 1; d < 1024; d <<= 1) {
        int v = (t >= d) ? ps[t - d] : 0;
        __syncthreads();
        ps[t] += v;
        __syncthreads();
    }
    int excl = (t == 0) ? 0 : ps[t - 1];
    for (int i = 0; i < CH; ++i) {
        int idx = base + i;
        if (idx < N_NODES) { off[idx] = excl; cursor[idx] = excl; excl += indeg[idx]; }
    }
    if (t == 1023) off[N_NODES] = ps[1023];
}

__global__ void csr_fill(const void* ei, const int* __restrict__ flags,
                         int* __restrict__ cursor, int* __restrict__ slots, int E)
{
    int i = blockIdx.x * blockDim.x + threadIdx.x;
    if (i >= E) return;
    int d = clampi(ld_idx(ei, (long)E + i, flags[0]), N_NODES - 1);
    int p = atomicAdd(&cursor[d], 1);
    slots[p] = i;
}

// ---------------------------------------------------------------------------
// conversions
// ---------------------------------------------------------------------------
__global__ void conv_pad_bf16(const float* __restrict__ src, ushort_t* __restrict__ dst,
                              int K, int Kp, long M)
{
    long total = M * Kp;
    long stride = (long)gridDim.x * blockDim.x;
    for (long i = (long)blockIdx.x * blockDim.x + threadIdx.x; i < total; i += stride) {
        long n = i / Kp;
        int k = (int)(i - n * Kp);
        dst[i] = (k < K) ? f2bf(src[n * K + k]) : (ushort_t)0;
    }
}

// WT[n][kp] = bf16(W[k][n]), zero-padded k>=K
__global__ void wt_bf16(const float* __restrict__ W, ushort_t* __restrict__ WT,
                        int K, int Kp, int HC)
{
    int nch = Kp >> 3;
    int i = blockIdx.x * blockDim.x + threadIdx.x;
    if (i >= HC * nch) return;
    int n = i / nch, c8 = i - n * nch;
#pragma unroll
    for (int e = 0; e < 8; ++e) {
        int k = c8 * 8 + e;
        WT[(long)n * Kp + k] = (k < K) ? f2bf(W[(long)k * HC + n]) : (ushort_t)0;
    }
}

// ---------------------------------------------------------------------------
// Wd[k,h], Ws[k,h] = per-head att projections of W (f32, exact)
// ---------------------------------------------------------------------------
__global__ void make_watt(const float* __restrict__ W, const float* __restrict__ att,
                          float* __restrict__ Wd, float* __restrict__ Wsv,
                          int K, int C, int HC)
{
    int i = blockIdx.x * blockDim.x + threadIdx.x;
    if (i >= K * HEADS) return;
    int k = i >> 2, h = i & 3;
    const float* wrow = W + (long)k * HC + h * C;
    const float* ad = att + h * 2 * C;
    const float* as = ad + C;
    float s1 = 0.f, s2 = 0.f;
    for (int c = 0; c < C; ++c) { float w = wrow[c]; s1 += w * ad[c]; s2 += w * as[c]; }
    Wd[k * HEADS + h] = s1;
    Wsv[k * HEADS + h] = s2;
}

// ---------------------------------------------------------------------------
// adst/asrc per node. A may be f32 (lda,K) or bf16 padded (lda=Kp).
// ---------------------------------------------------------------------------
__global__ __launch_bounds__(256) void node_proj_any(const void* __restrict__ A,
                                                     int lda, int K, int isbf,
                                                     const float* __restrict__ Wd,
                                                     const float* __restrict__ Wsv,
                                                     float* __restrict__ adst,
                                                     float* __restrict__ asrc, int N)
{
    const int wv = threadIdx.x >> 6, lane = threadIdx.x & 63;
    const int n = blockIdx.x * 4 + wv;
    if (n >= N) return;
    float sd[HEADS] = {}, ss[HEADS] = {};
    for (int k = lane; k < K; k += 64) {
        float v = isbf ? bf2f(((const ushort_t*)A)[(long)n * lda + k])
                       : ((const float*)A)[(long)n * lda + k];
#pragma unroll
        for (int h = 0; h < HEADS; ++h) {
            sd[h] += v * Wd[k * HEADS + h];
            ss[h] += v * Wsv[k * HEADS + h];
        }
    }
#pragma unroll
    for (int off = 32; off; off >>= 1) {
#pragma unroll
        for (int h = 0; h < HEADS; ++h) {
            sd[h] += __shfl_down(sd[h], off);
            ss[h] += __shfl_down(ss[h], off);
        }
    }
    if (lane == 0) {
#pragma unroll
        for (int h = 0; h < HEADS; ++h) {
            adst[n * HEADS + h] = sd[h];
            asrc[n * HEADS + h] = ss[h];
        }
    }
}

// ---------------------------------------------------------------------------
__global__ void edge_alpha(const void* __restrict__ ei, const int* __restrict__ flags,
                           const float* __restrict__ adst, const float* __restrict__ asrc,
                           float* __restrict__ alpha, int E)
{
    int e = blockIdx.x * blockDim.x + threadIdx.x;
    if (e >= E) return;
    int is64 = flags[0];
    int s = clampi(ld_idx(ei, e, is64), N_NODES - 1);
    int d = clampi(ld_idx(ei, (long)E + e, is64), N_NODES - 1);
    float a[HEADS], m = -1e30f;
#pragma unroll
    for (int h = 0; h < HEADS; ++h) {
        float v = adst[d * HEADS + h] + asrc[s * HEADS + h];
        v = (v > 0.f) ? v : 0.2f * v;
        a[h] = v;
        m = fmaxf(m, v);
    }
    float sum = 0.f;
#pragma unroll
    for (int h = 0; h < HEADS; ++h) { a[h] = __expf(a[h] - m); sum += a[h]; }
    float inv = 1.f / sum;
#pragma unroll
    for (int h = 0; h < HEADS; ++h) alpha[(long)e * HEADS + h] = a[h] * inv;
}

// ---------------------------------------------------------------------------
// bf16 MFMA GEMM: C[M][FC] (bf16) = A[M][Kp] @ WT[n][Kp]^T  (all heads at once)
// BM=128 BN=64 BK=64, 4 waves (2x2), XOR-swizzled LDS, reg-staged.
// ---------------------------------------------------------------------------
#define BM 128
#define BN 64
#define BK 64
__global__ __launch_bounds__(256) void gemm_bf16(const ushort_t* __restrict__ A,
                                                 const ushort_t* __restrict__ WT,
                                                 ushort_t* __restrict__ C,
                                                 int M, int FC, int Kp)
{
    __shared__ ushort_t As[BM * BK];
    __shared__ ushort_t Bs[BN * BK];
    const int tid = threadIdx.x;
    const int lane = tid & 63;
    const int wid = tid >> 6;
    const int wm = wid >> 1, wn = wid & 1;
    const int row0 = blockIdx.y * BM;
    const int colb = blockIdx.x * BN;

    f32x4 acc[4][2];
#pragma unroll
    for (int i = 0; i < 4; ++i)
#pragma unroll
        for (int j = 0; j < 2; ++j) { f32x4 z = {0.f, 0.f, 0.f, 0.f}; acc[i][j] = z; }

    short8 ra[4], rb[2];

    auto loadG = [&](int k0) {
#pragma unroll
        for (int r = 0; r < 4; ++r) {
            int id = r * 256 + tid;
            int row = id >> 3, j = id & 7;
            long grow = min(row0 + row, M - 1);
            ra[r] = *(const short8*)&A[grow * Kp + k0 + j * 8];
        }
#pragma unroll
        for (int r = 0; r < 2; ++r) {
            int id = r * 256 + tid;
            int row = id >> 3, j = id & 7;
            long gcol = min(colb + row, FC - 1);
            rb[r] = *(const short8*)&WT[gcol * Kp + k0 + j * 8];
        }
    };

    loadG(0);
    for (int k0 = 0; k0 < Kp; k0 += BK) {
        __syncthreads();
#pragma unroll
        for (int r = 0; r < 4; ++r) {
            int id = r * 256 + tid;
            int row = id >> 3, j = id & 7;
            *(short8*)&As[row * BK + ((j ^ (row & 7)) << 3)] = ra[r];
        }
#pragma unroll
        for (int r = 0; r < 2; ++r) {
            int id = r * 256 + tid;
            int row = id >> 3, j = id & 7;
            *(short8*)&Bs[row * BK + ((j ^ (row & 7)) << 3)] = rb[r];
        }
        __syncthreads();
        if (k0 + BK < Kp) loadG(k0 + BK);
#pragma unroll
        for (int ks = 0; ks < 2; ++ks) {
            short8 af[4], bfr[2];
            const int jr = ks * 4 + (lane >> 4);
#pragma unroll
            for (int fm = 0; fm < 4; ++fm) {
                int row = wm * 64 + fm * 16 + (lane & 15);
                af[fm] = *(const short8*)&As[row * BK + ((jr ^ (row & 7)) << 3)];
            }
#pragma unroll
            for (int fn = 0; fn < 2; ++fn) {
                int row = wn * 32 + fn * 16 + (lane & 15);
                bfr[fn] = *(const short8*)&Bs[row * BK + ((jr ^ (row & 7)) << 3)];
            }
#pragma unroll
            for (int fm = 0; fm < 4; ++fm)
#pragma unroll
                for (int fn = 0; fn < 2; ++fn)
                    acc[fm][fn] = __builtin_amdgcn_mfma_f32_16x16x32_bf16(
                        af[fm], bfr[fn], acc[fm][fn], 0, 0, 0);
        }
    }

#pragma unroll
    for (int fm = 0; fm < 4; ++fm) {
        int rbase = row0 + wm * 64 + fm * 16 + (lane >> 4) * 4;
#pragma unroll
        for (int fn = 0; fn < 2; ++fn) {
            int col = colb + wn * 32 + fn * 16 + (lane & 15);
            if (col >= FC) continue;
#pragma unroll
            for (int r = 0; r < 4; ++r) {
                int gr = rbase + r;
                if (gr < M) C[(long)gr * FC + col] = f2bf(acc[fm][fn][r]);
            }
        }
    }
}

// ---------------------------------------------------------------------------
// CSR gather, ALL heads at once:
// acc[n, c] = sum_e alpha[e, c/FC] * xh[src_e, c],  c in [0, HC)
// layers 1/2: outb[n*ldo + c] = bf16(relu(acc + bias[c]))
// layer 3:    atomicMax(G[batch[n]*1248 + c], relu(acc + bias[c]))
// One wave per node; row processed in chunks of 256 (lane*4 + j).
// ---------------------------------------------------------------------------
__global__ __launch_bounds__(256) void gat_gather_all(const int* __restrict__ off,
                                                      const int* __restrict__ slots,
                                                      const void* __restrict__ ei,
                                                      const int* __restrict__ flags,
                                                      const float* __restrict__ alpha,
                                                      const ushort_t* __restrict__ xh,
                                                      const float* __restrict__ bias,
                                                      ushort_t* __restrict__ outb, int ldo,
                                                      float* __restrict__ G,
                                                      const void* __restrict__ batch,
                                                      int HC, int FC)
{
    const int wv = threadIdx.x >> 6, lane = threadIdx.x & 63;
    const int n = blockIdx.x * 4 + wv;
    if (n >= N_NODES) return;
    const int is64 = flags[0];
    const int nch = (HC + 255) >> 8;          // <= 5
    float acc[5][4];
#pragma unroll
    for (int i = 0; i < 5; ++i)
#pragma unroll
        for (int j = 0; j < 4; ++j) acc[i][j] = 0.f;

    const int s0 = off[n], s1 = off[n + 1];
    for (int i = s0; i < s1; ++i) {
        int e = slots[i];
        f32x4 al = *(const f32x4*)&alpha[(long)e * HEADS];
        int s = clampi(ld_idx(ei, e, is64), N_NODES - 1);
        const ushort_t* xs = xh + (long)s * HC;
        for (int ch = 0; ch < nch; ++ch) {
            int base = (ch << 8) + lane * 4;
            if (base >= HC) break;
            ushort4_t v = *(const ushort4_t*)&xs[base];
#pragma unroll
            for (int j = 0; j < 4; ++j) {
                int c = base + j;
                float w = (c < FC) ? al[0] : (c < 2 * FC) ? al[1]
                         : (c < 3 * FC) ? al[2] : al[3];
                acc[ch][j] += w * bf2f(v[j]);
            }
        }
    }

    if (G) {
        int g = clampi(ld_idx(batch, n, flags[1]), N_GRAPHS - 1);
        for (int ch = 0; ch < nch; ++ch) {
            int base = (ch << 8) + lane * 4;
            if (base >= HC) break;
#pragma unroll
            for (int j = 0; j < 4; ++j) {
                float v = fmaxf(acc[ch][j] + bias[base + j], 0.f);
                atomicMax((unsigned int*)&G[(long)g * 1248 + base + j], __float_as_uint(v));
            }
        }
    } else {
        for (int ch = 0; ch < nch; ++ch) {
            int base = (ch << 8) + lane * 4;
            if (base >= HC) break;
            ushort4_t o;
#pragma unroll
            for (int j = 0; j < 4; ++j)
                o[j] = f2bf(fmaxf(acc[ch][j] + bias[base + j], 0.f));
            *(ushort4_t*)&outb[(long)n * ldo + base] = o;
        }
    }
}

// ---------------------------------------------------------------------------
// MLP head. g1: [256,1248]@[1248,1024]+b, relu. 2 rows/block, float4/thread.
// ---------------------------------------------------------------------------
__global__ __launch_bounds__(256) void head_g1(const float* __restrict__ Gp,
                                               const float* __restrict__ W,
                                               const float* __restrict__ bias,
                                               float* __restrict__ out)
{
    __shared__ float a0[1248], a1[1248];
    const int m0 = blockIdx.x * 2;
    for (int i = threadIdx.x; i < 1248; i += 256) {
        a0[i] = Gp[(long)m0 * 1248 + i];
        a1[i] = Gp[(long)(m0 + 1) * 1248 + i];
    }
    __syncthreads();
    const int n4 = threadIdx.x * 4;
    float c0[4] = {}, c1[4] = {};
    for (int k = 0; k < 1248; ++k) {
        f32x4 b = *(const f32x4*)&W[(long)k * 1024 + n4];
        float av0 = a0[k], av1 = a1[k];
#pragma unroll
        for (int j = 0; j < 4; ++j) { c0[j] += av0 * b[j]; c1[j] += av1 * b[j]; }
    }
#pragma unroll
    for (int j = 0; j < 4; ++j) {
        float bj = bias[n4 + j];
        out[(long)m0 * 1024 + n4 + j]       = fmaxf(c0[j] + bj, 0.f);
        out[(long)(m0 + 1) * 1024 + n4 + j] = fmaxf(c1[j] + bj, 0.f);
    }
}

// g2: [256,1024]@[1024,128]+b (no relu). 2 rows/block, thread-per-output.
__global__ __launch_bounds__(256) void head_g2(const float* __restrict__ G1,
                                               const float* __restrict__ W,
                                               const float* __restrict__ bias,
                                               float* __restrict__ out)
{
    __shared__ float a0[1024], a1[1024];
    const int m0 = blockIdx.x * 2;
    for (int i = threadIdx.x; i < 1024; i += 256) {
        a0[i] = G1[(long)m0 * 1024 + i];
        a1[i] = G1[(long)(m0 + 1) * 1024 + i];
    }
    __syncthreads();
    const int nn = threadIdx.x & 127;
    const int r = threadIdx.x >> 7;
    const float* a = r ? a1 : a0;
    float acc = 0.f;
    for (int k = 0; k < 1024; k += 4) {
#pragma unroll
        for (int u = 0; u < 4; ++u)
            acc += a[k + u] * W[(long)(k + u) * 128 + nn];
    }
    out[(long)(m0 + r) * 128 + nn] = acc + bias[nn];
}

// g3: out[m] = dot(G2[m,:128], Wo) + bo. One wave per row.
__global__ __launch_bounds__(256) void head_g3(const float* __restrict__ G2,
                                               const float* __restrict__ Wo,
                                               const float* __restrict__ bo,
                                               float* __restrict__ out)
{
    const int wv = threadIdx.x >> 6, lane = threadIdx.x & 63;
    const int m = blockIdx.x * 4 + wv;
    if (m >= N_GRAPHS) return;
    float s = G2[(long)m * 128 + lane] * Wo[lane]
            + G2[(long)m * 128 + 64 + lane] * Wo[64 + lane];
#pragma unroll
    for (int o = 32; o; o >>= 1) s += __shfl_down(s, o);
    if (lane == 0) out[m] = s + bo[0];
}

// ---------------------------------------------------------------------------
extern "C" void kernel_launch(void* const* d_in, const int* in_sizes, int n_in,
                              void* d_out, int out_size, void* d_ws, size_t ws_size,
                              hipStream_t stream)
{
    const float* x    = (const float*)d_in[0];
    const void*  ei   = d_in[1];
    const void*  batch= d_in[2];
    const float* W1   = (const float*)d_in[3];
    const float* att1 = (const float*)d_in[4];
    const float* b1   = (const float*)d_in[5];
    const float* W2   = (const float*)d_in[6];
    const float* att2 = (const float*)d_in[7];
    const float* b2   = (const float*)d_in[8];
    const float* W3   = (const float*)d_in[9];
    const float* att3 = (const float*)d_in[10];
    const float* b3   = (const float*)d_in[11];
    const float* Wg1  = (const float*)d_in[12];
    const float* bg1  = (const float*)d_in[13];
    const float* Wg2  = (const float*)d_in[14];
    const float* bg2  = (const float*)d_in[15];
    const float* Wo   = (const float*)d_in[16];
    const float* bo   = (const float*)d_in[17];

    const int N = N_NODES;
    const int E = in_sizes[1] / 2;

    // ---- workspace layout (float units), total ~148 MB (155 MB proven OK) --
    float* ws = (float*)d_ws;
    ushort_t* H1b  = (ushort_t*)ws;                        // 30000*320 sh
    ushort_t* H2b  = (ushort_t*)(ws + 4800000);            // 30000*640 sh
    ushort_t* ABF1 = (ushort_t*)(ws + 14400000);           // 30000*128 sh
    ushort_t* XHb  = (ushort_t*)(ws + 16320000);           // 30000*1248 sh
    ushort_t* WT   = (ushort_t*)(ws + 35040000);           // 1248*640 sh
    float* ADST  = ws + 35440000;                          // 120000
    float* ASRC  = ws + 35560000;                          // 120000
    float* ALPHA = ws + 35680000;                          // 400000
    float* WD    = ws + 36080000;                          // 4096
    float* WSV   = ws + 36084096;                          // 4096
    float* G     = ws + 36088192;                          // 319488
    float* G1    = ws + 36407680;                          // 262144
    float* G2    = ws + 36669824;                          // 32768
    int*   INDEG = (int*)(ws + 36702592);                  // 30000
    int*   OFF   = (int*)(ws + 36732592);                  // 30001
    int*   CURS  = (int*)(ws + 36762593);                  // 30000
    int*   SLOTS = (int*)(ws + 36792593);                  // E (<=100000)
    int*   FLAGS = (int*)(ws + 36892593);                  // 2

    dim3 blk(256);

    detect_fmt<<<dim3(1), blk, 0, stream>>>(ei, batch, E, FLAGS);

    hipMemsetAsync(H1b, 0, (size_t)N * 320 * sizeof(ushort_t), stream);
    hipMemsetAsync(H2b, 0, (size_t)N * 640 * sizeof(ushort_t), stream);
    hipMemsetAsync(G, 0, (size_t)N_GRAPHS * 1248 * sizeof(float), stream);
    hipMemsetAsync(INDEG, 0, (size_t)N * sizeof(int), stream);

    csr_hist<<<dim3((E + 255) / 256), blk, 0, stream>>>(ei, FLAGS, INDEG, E);
    csr_scan<<<dim3(1), dim3(1024), 0, stream>>>(INDEG, OFF, CURS);
    csr_fill<<<dim3((E + 255) / 256), blk, 0, stream>>>(ei, FLAGS, CURS, SLOTS, E);

    conv_pad_bf16<<<dim3(8192), blk, 0, stream>>>(x, ABF1, 78, 128, (long)N);

    struct Layer {
        const void* A; int lda; int K; int isbf;   // node_proj input
        const ushort_t* Abf; int Kp;               // gemm A (padded bf16)
        const float *W, *att, *b;
        int C, HC;
        ushort_t* outb; int ldo;                   // layers 1,2
        int pool;                                  // layer 3
    };
    Layer L[3] = {
        { x,   78,  78,  0, ABF1, 128, W1, att1, b1,  78,  312, H1b, 320, 0 },
        { H1b, 320, 312, 1, H1b,  320, W2, att2, b2, 156,  624, H2b, 640, 0 },
        { H2b, 640, 624, 1, H2b,  640, W3, att3, b3, 312, 1248, nullptr, 0, 1 },
    };

    for (int li = 0; li < 3; ++li) {
        const Layer& l = L[li];
        int nch = l.Kp >> 3;
        wt_bf16<<<dim3((l.HC * nch + 255) / 256), blk, 0, stream>>>(l.W, WT, l.K, l.Kp, l.HC);
        make_watt<<<dim3((l.K * HEADS + 255) / 256), blk, 0, stream>>>(l.W, l.att, WD, WSV, l.K, l.C, l.HC);
        node_proj_any<<<dim3((N + 3) / 4), blk, 0, stream>>>(l.A, l.lda, l.K, l.isbf, WD, WSV, ADST, ASRC, N);
        edge_alpha<<<dim3((E + 255) / 256), blk, 0, stream>>>(ei, FLAGS, ADST, ASRC, ALPHA, E);

        // one GEMM over all heads: XHb[N][HC] = A @ WT^T
        dim3 gg((l.HC + BN - 1) / BN, (N + BM - 1) / BM);
        gemm_bf16<<<gg, blk, 0, stream>>>(l.Abf, WT, XHb, N, l.HC, l.Kp);

        // one gather over all heads
        gat_gather_all<<<dim3((N + 3) / 4), blk, 0, stream>>>(
            OFF, SLOTS, ei, FLAGS, ALPHA, XHb, l.b,
            l.pool ? nullptr : l.outb, l.ldo,
            l.pool ? G : nullptr, batch, l.HC, l.C);
    }

    // ---- MLP head (f32 exact) ----
    head_g1<<<dim3(N_GRAPHS / 2), blk, 0, stream>>>(G, Wg1, bg1, G1);
    head_g2<<<dim3(N_GRAPHS / 2), blk, 0, stream>>>(G1, Wg2, bg2, G2);
    head_g3<<<dim3(N_GRAPHS / 4), blk, 0, stream>>>(G2, Wo, bo, (float*)d_out);
}

// Round 5
// 873.174 us; speedup vs baseline: 4.7311x; 1.1548x over previous
//
#include <hip/hip_runtime.h>
#include <hip/hip_bf16.h>

#define N_NODES 30000
#define N_GRAPHS 256
#define HEADS 4

typedef __attribute__((ext_vector_type(8))) short short8;
typedef __attribute__((ext_vector_type(4))) float f32x4;
typedef __attribute__((ext_vector_type(4))) unsigned short ushort4_t;
typedef unsigned short ushort_t;

__device__ __forceinline__ ushort_t f2bf(float v) {
    __hip_bfloat16 h = __float2bfloat16(v);
    return *reinterpret_cast<ushort_t*>(&h);
}
__device__ __forceinline__ float bf2f(ushort_t u) {
    __hip_bfloat16 h;
    *reinterpret_cast<ushort_t*>(&h) = u;
    return __bfloat162float(h);
}
__device__ __forceinline__ int ld_idx(const void* p, long i, int is64) {
    return is64 ? (int)((const long long*)p)[i] : ((const int*)p)[i];
}
__device__ __forceinline__ int clampi(int v, int hi) {
    return v < 0 ? 0 : (v > hi ? hi : v);
}

// ---------------------------------------------------------------------------
__global__ void detect_fmt(const void* ei, const void* batch, int E, int* flags)
{
    __shared__ int okE, okB;
    if (threadIdx.x == 0) { okE = 1; okB = 1; }
    __syncthreads();
    const long long* e64 = (const long long*)ei;
    const long long* b64 = (const long long*)batch;
    const int nbslot = N_NODES / 2;
    for (int i = threadIdx.x; i < 2048; i += 256) {
        long ei_idx = (long)i * E / 2048;
        long long v = e64[ei_idx];
        if (v < 0 || v >= N_NODES) okE = 0;
        long b_idx = (long)i * nbslot / 2048;
        long long b = b64[b_idx];
        if (b < 0 || b >= N_GRAPHS) okB = 0;
    }
    __syncthreads();
    if (threadIdx.x == 0) { flags[0] = okE; flags[1] = okB; }
}

// ---------------------------------------------------------------------------
// CSR build (by dst)
// ---------------------------------------------------------------------------
__global__ void csr_hist(const void* ei, const int* __restrict__ flags,
                         int* __restrict__ indeg, int E)
{
    int i = blockIdx.x * blockDim.x + threadIdx.x;
    if (i >= E) return;
    int d = clampi(ld_idx(ei, (long)E + i, flags[0]), N_NODES - 1);
    atomicAdd(&indeg[d], 1);
}

__global__ __launch_bounds__(1024) void csr_scan(const int* __restrict__ indeg,
                                                 int* __restrict__ off,
                                                 int* __restrict__ cursor)
{
    __shared__ int ps[1024];
    const int t = threadIdx.x;
    const int CH = (N_NODES + 1023) / 1024;
    const int base = t * CH;
    int s = 0;
    for (int i = 0; i < CH; ++i) { int idx = base + i; if (idx < N_NODES) s += indeg[idx]; }
    ps[t] = s;
    __syncthreads();
    for (int d = 1; d < 1024; d <<= 1) {
        int v = (t >= d) ? ps[t - d] : 0;
        __syncthreads();
        ps[t] += v;
        __syncthreads();
    }
    int excl = (t == 0) ? 0 : ps[t - 1];
    for (int i = 0; i < CH; ++i) {
        int idx = base + i;
        if (idx < N_NODES) { off[idx] = excl; cursor[idx] = excl; excl += indeg[idx]; }
    }
    if (t == 1023) off[N_NODES] = ps[1023];
}

__global__ void csr_fill(const void* ei, const int* __restrict__ flags,
                         int* __restrict__ cursor, int* __restrict__ slots, int E)
{
    int i = blockIdx.x * blockDim.x + threadIdx.x;
    if (i >= E) return;
    int d = clampi(ld_idx(ei, (long)E + i, flags[0]), N_NODES - 1);
    int p = atomicAdd(&cursor[d], 1);
    slots[p] = i;
}

// ---------------------------------------------------------------------------
// graph segment boundaries (batch is sorted): GSTART[g]..GSTART[g+1]
// ---------------------------------------------------------------------------
__global__ void ghist(const void* batch, const int* __restrict__ flags,
                      int* __restrict__ gcnt)
{
    int n = blockIdx.x * blockDim.x + threadIdx.x;
    if (n >= N_NODES) return;
    int g = clampi(ld_idx(batch, n, flags[1]), N_GRAPHS - 1);
    atomicAdd(&gcnt[g], 1);
}

__global__ __launch_bounds__(256) void gscan(const int* __restrict__ gcnt,
                                             int* __restrict__ gstart)
{
    __shared__ int ps[256];
    const int t = threadIdx.x;
    ps[t] = gcnt[t];
    __syncthreads();
    for (int d = 1; d < 256; d <<= 1) {
        int v = (t >= d) ? ps[t - d] : 0;
        __syncthreads();
        ps[t] += v;
        __syncthreads();
    }
    gstart[t + 1] = ps[t];
    if (t == 0) gstart[0] = 0;
}

// ---------------------------------------------------------------------------
// conversions
// ---------------------------------------------------------------------------
__global__ void conv_pad_bf16(const float* __restrict__ src, ushort_t* __restrict__ dst,
                              int K, int Kp, long M)
{
    long total = M * Kp;
    long stride = (long)gridDim.x * blockDim.x;
    for (long i = (long)blockIdx.x * blockDim.x + threadIdx.x; i < total; i += stride) {
        long n = i / Kp;
        int k = (int)(i - n * Kp);
        dst[i] = (k < K) ? f2bf(src[n * K + k]) : (ushort_t)0;
    }
}

// WT[n][kp] = bf16(W[k][n]), zero-padded k>=K
__global__ void wt_bf16(const float* __restrict__ W, ushort_t* __restrict__ WT,
                        int K, int Kp, int HC)
{
    int nch = Kp >> 3;
    int i = blockIdx.x * blockDim.x + threadIdx.x;
    if (i >= HC * nch) return;
    int n = i / nch, c8 = i - n * nch;
#pragma unroll
    for (int e = 0; e < 8; ++e) {
        int k = c8 * 8 + e;
        WT[(long)n * Kp + k] = (k < K) ? f2bf(W[(long)k * HC + n]) : (ushort_t)0;
    }
}

// ---------------------------------------------------------------------------
// Wd[k,h], Ws[k,h] = per-head att projections of W (f32, exact)
// ---------------------------------------------------------------------------
__global__ void make_watt(const float* __restrict__ W, const float* __restrict__ att,
                          float* __restrict__ Wd, float* __restrict__ Wsv,
                          int K, int C, int HC)
{
    int i = blockIdx.x * blockDim.x + threadIdx.x;
    if (i >= K * HEADS) return;
    int k = i >> 2, h = i & 3;
    const float* wrow = W + (long)k * HC + h * C;
    const float* ad = att + h * 2 * C;
    const float* as = ad + C;
    float s1 = 0.f, s2 = 0.f;
    for (int c = 0; c < C; ++c) { float w = wrow[c]; s1 += w * ad[c]; s2 += w * as[c]; }
    Wd[k * HEADS + h] = s1;
    Wsv[k * HEADS + h] = s2;
}

// ---------------------------------------------------------------------------
// adst/asrc per node. A may be f32 (lda,K) or bf16 padded (lda=Kp).
// ---------------------------------------------------------------------------
__global__ __launch_bounds__(256) void node_proj_any(const void* __restrict__ A,
                                                     int lda, int K, int isbf,
                                                     const float* __restrict__ Wd,
                                                     const float* __restrict__ Wsv,
                                                     float* __restrict__ adst,
                                                     float* __restrict__ asrc, int N)
{
    const int wv = threadIdx.x >> 6, lane = threadIdx.x & 63;
    const int n = blockIdx.x * 4 + wv;
    if (n >= N) return;
    float sd[HEADS] = {}, ss[HEADS] = {};
    for (int k = lane; k < K; k += 64) {
        float v = isbf ? bf2f(((const ushort_t*)A)[(long)n * lda + k])
                       : ((const float*)A)[(long)n * lda + k];
#pragma unroll
        for (int h = 0; h < HEADS; ++h) {
            sd[h] += v * Wd[k * HEADS + h];
            ss[h] += v * Wsv[k * HEADS + h];
        }
    }
#pragma unroll
    for (int off = 32; off; off >>= 1) {
#pragma unroll
        for (int h = 0; h < HEADS; ++h) {
            sd[h] += __shfl_down(sd[h], off);
            ss[h] += __shfl_down(ss[h], off);
        }
    }
    if (lane == 0) {
#pragma unroll
        for (int h = 0; h < HEADS; ++h) {
            adst[n * HEADS + h] = sd[h];
            asrc[n * HEADS + h] = ss[h];
        }
    }
}

// ---------------------------------------------------------------------------
__global__ void edge_alpha(const void* __restrict__ ei, const int* __restrict__ flags,
                           const float* __restrict__ adst, const float* __restrict__ asrc,
                           float* __restrict__ alpha, int E)
{
    int e = blockIdx.x * blockDim.x + threadIdx.x;
    if (e >= E) return;
    int is64 = flags[0];
    int s = clampi(ld_idx(ei, e, is64), N_NODES - 1);
    int d = clampi(ld_idx(ei, (long)E + e, is64), N_NODES - 1);
    float a[HEADS], m = -1e30f;
#pragma unroll
    for (int h = 0; h < HEADS; ++h) {
        float v = adst[d * HEADS + h] + asrc[s * HEADS + h];
        v = (v > 0.f) ? v : 0.2f * v;
        a[h] = v;
        m = fmaxf(m, v);
    }
    float sum = 0.f;
#pragma unroll
    for (int h = 0; h < HEADS; ++h) { a[h] = __expf(a[h] - m); sum += a[h]; }
    float inv = 1.f / sum;
#pragma unroll
    for (int h = 0; h < HEADS; ++h) alpha[(long)e * HEADS + h] = a[h] * inv;
}

// ---------------------------------------------------------------------------
// bf16 MFMA GEMM: C[M][FC] (bf16) = A[M][Kp] @ WT[n][Kp]^T  (all heads)
// BM=128 BN=64 BK=64, 4 waves (2x2), XOR-swizzled LDS, reg-staged.
// ---------------------------------------------------------------------------
#define BM 128
#define BN 64
#define BK 64
__global__ __launch_bounds__(256) void gemm_bf16(const ushort_t* __restrict__ A,
                                                 const ushort_t* __restrict__ WT,
                                                 ushort_t* __restrict__ C,
                                                 int M, int FC, int Kp)
{
    __shared__ ushort_t As[BM * BK];
    __shared__ ushort_t Bs[BN * BK];
    const int tid = threadIdx.x;
    const int lane = tid & 63;
    const int wid = tid >> 6;
    const int wm = wid >> 1, wn = wid & 1;
    const int row0 = blockIdx.y * BM;
    const int colb = blockIdx.x * BN;

    f32x4 acc[4][2];
#pragma unroll
    for (int i = 0; i < 4; ++i)
#pragma unroll
        for (int j = 0; j < 2; ++j) { f32x4 z = {0.f, 0.f, 0.f, 0.f}; acc[i][j] = z; }

    short8 ra[4], rb[2];

    auto loadG = [&](int k0) {
#pragma unroll
        for (int r = 0; r < 4; ++r) {
            int id = r * 256 + tid;
            int row = id >> 3, j = id & 7;
            long grow = min(row0 + row, M - 1);
            ra[r] = *(const short8*)&A[grow * Kp + k0 + j * 8];
        }
#pragma unroll
        for (int r = 0; r < 2; ++r) {
            int id = r * 256 + tid;
            int row = id >> 3, j = id & 7;
            long gcol = min(colb + row, FC - 1);
            rb[r] = *(const short8*)&WT[gcol * Kp + k0 + j * 8];
        }
    };

    loadG(0);
    for (int k0 = 0; k0 < Kp; k0 += BK) {
        __syncthreads();
#pragma unroll
        for (int r = 0; r < 4; ++r) {
            int id = r * 256 + tid;
            int row = id >> 3, j = id & 7;
            *(short8*)&As[row * BK + ((j ^ (row & 7)) << 3)] = ra[r];
        }
#pragma unroll
        for (int r = 0; r < 2; ++r) {
            int id = r * 256 + tid;
            int row = id >> 3, j = id & 7;
            *(short8*)&Bs[row * BK + ((j ^ (row & 7)) << 3)] = rb[r];
        }
        __syncthreads();
        if (k0 + BK < Kp) loadG(k0 + BK);
#pragma unroll
        for (int ks = 0; ks < 2; ++ks) {
            short8 af[4], bfr[2];
            const int jr = ks * 4 + (lane >> 4);
#pragma unroll
            for (int fm = 0; fm < 4; ++fm) {
                int row = wm * 64 + fm * 16 + (lane & 15);
                af[fm] = *(const short8*)&As[row * BK + ((jr ^ (row & 7)) << 3)];
            }
#pragma unroll
            for (int fn = 0; fn < 2; ++fn) {
                int row = wn * 32 + fn * 16 + (lane & 15);
                bfr[fn] = *(const short8*)&Bs[row * BK + ((jr ^ (row & 7)) << 3)];
            }
#pragma unroll
            for (int fm = 0; fm < 4; ++fm)
#pragma unroll
                for (int fn = 0; fn < 2; ++fn)
                    acc[fm][fn] = __builtin_amdgcn_mfma_f32_16x16x32_bf16(
                        af[fm], bfr[fn], acc[fm][fn], 0, 0, 0);
        }
    }

#pragma unroll
    for (int fm = 0; fm < 4; ++fm) {
        int rbase = row0 + wm * 64 + fm * 16 + (lane >> 4) * 4;
#pragma unroll
        for (int fn = 0; fn < 2; ++fn) {
            int col = colb + wn * 32 + fn * 16 + (lane & 15);
            if (col >= FC) continue;
#pragma unroll
            for (int r = 0; r < 4; ++r) {
                int gr = rbase + r;
                if (gr < M) C[(long)gr * FC + col] = f2bf(acc[fm][fn][r]);
            }
        }
    }
}

// ---------------------------------------------------------------------------
// CSR gather, all heads, layers 1/2 (plain coalesced bf16 stores):
// outb[n*ldo + c] = bf16(relu(bias[c] + sum_e alpha[e, c/FC] * xh[src_e, c]))
// ---------------------------------------------------------------------------
__global__ __launch_bounds__(256) void gat_gather_all(const int* __restrict__ off,
                                                      const int* __restrict__ slots,
                                                      const void* __restrict__ ei,
                                                      const int* __restrict__ flags,
                                                      const float* __restrict__ alpha,
                                                      const ushort_t* __restrict__ xh,
                                                      const float* __restrict__ bias,
                                                      ushort_t* __restrict__ outb, int ldo,
                                                      int HC, int FC)
{
    const int wv = threadIdx.x >> 6, lane = threadIdx.x & 63;
    const int n = blockIdx.x * 4 + wv;
    if (n >= N_NODES) return;
    const int is64 = flags[0];
    const int nch = (HC + 255) >> 8;          // <= 3 for layers 1/2
    float acc[3][4];
#pragma unroll
    for (int i = 0; i < 3; ++i)
#pragma unroll
        for (int j = 0; j < 4; ++j) acc[i][j] = 0.f;

    const int s0 = off[n], s1 = off[n + 1];
    for (int i = s0; i < s1; ++i) {
        int e = slots[i];
        f32x4 al = *(const f32x4*)&alpha[(long)e * HEADS];
        int s = clampi(ld_idx(ei, e, is64), N_NODES - 1);
        const ushort_t* xs = xh + (long)s * HC;
        for (int ch = 0; ch < nch; ++ch) {
            int base = (ch << 8) + lane * 4;
            if (base >= HC) break;
            ushort4_t v = *(const ushort4_t*)&xs[base];
#pragma unroll
            for (int j = 0; j < 4; ++j) {
                int c = base + j;
                float w = (c < FC) ? al[0] : (c < 2 * FC) ? al[1]
                         : (c < 3 * FC) ? al[2] : al[3];
                acc[ch][j] += w * bf2f(v[j]);
            }
        }
    }

    for (int ch = 0; ch < nch; ++ch) {
        int base = (ch << 8) + lane * 4;
        if (base >= HC) break;
        ushort4_t o;
#pragma unroll
        for (int j = 0; j < 4; ++j)
            o[j] = f2bf(fmaxf(acc[ch][j] + bias[base + j], 0.f));
        *(ushort4_t*)&outb[(long)n * ldo + base] = o;
    }
}

// ---------------------------------------------------------------------------
// Layer 3 fused: gather + bias + relu + segment-max (sorted batch), no atomics.
// block = (graph g, column chunk ch); thread = one column.
// G[g*1248 + col] = max_{n in seg(g)} relu(bias[col] + sum_e alpha*xh[src,col])
// ---------------------------------------------------------------------------
__global__ __launch_bounds__(256) void pool_gather(const int* __restrict__ off,
                                                   const int* __restrict__ slots,
                                                   const void* __restrict__ ei,
                                                   const int* __restrict__ flags,
                                                   const float* __restrict__ alpha,
                                                   const ushort_t* __restrict__ xh,
                                                   const float* __restrict__ bias,
                                                   const int* __restrict__ gstart,
                                                   float* __restrict__ G,
                                                   int HC, int FC)
{
    const int g = blockIdx.x;
    const int col = blockIdx.y * 256 + threadIdx.x;
    if (col >= HC) return;
    const int h = col / FC;
    const int is64 = flags[0];
    const float bcol = bias[col];
    const ushort_t* xcol = xh + col;
    float gmax = 0.f;                        // relu floor; every segment non-empty
    const int n0 = gstart[g], n1 = gstart[g + 1];
    for (int n = n0; n < n1; ++n) {
        float acc = 0.f;
        const int s0 = off[n], s1 = off[n + 1];
        for (int i = s0; i < s1; ++i) {
            int e = slots[i];
            float w = alpha[(long)e * HEADS + h];
            int s = clampi(ld_idx(ei, e, is64), N_NODES - 1);
            acc += w * bf2f(xcol[(long)s * HC]);
        }
        gmax = fmaxf(gmax, fmaxf(acc + bcol, 0.f));
    }
    G[(long)g * 1248 + col] = gmax;
}

// ---------------------------------------------------------------------------
// MLP head. g1: [256,1248]@[1248,1024]+b, relu. 2 rows/block, float4/thread.
// ---------------------------------------------------------------------------
__global__ __launch_bounds__(256) void head_g1(const float* __restrict__ Gp,
                                               const float* __restrict__ W,
                                               const float* __restrict__ bias,
                                               float* __restrict__ out)
{
    __shared__ float a0[1248], a1[1248];
    const int m0 = blockIdx.x * 2;
    for (int i = threadIdx.x; i < 1248; i += 256) {
        a0[i] = Gp[(long)m0 * 1248 + i];
        a1[i] = Gp[(long)(m0 + 1) * 1248 + i];
    }
    __syncthreads();
    const int n4 = threadIdx.x * 4;
    float c0[4] = {}, c1[4] = {};
    for (int k = 0; k < 1248; ++k) {
        f32x4 b = *(const f32x4*)&W[(long)k * 1024 + n4];
        float av0 = a0[k], av1 = a1[k];
#pragma unroll
        for (int j = 0; j < 4; ++j) { c0[j] += av0 * b[j]; c1[j] += av1 * b[j]; }
    }
#pragma unroll
    for (int j = 0; j < 4; ++j) {
        float bj = bias[n4 + j];
        out[(long)m0 * 1024 + n4 + j]       = fmaxf(c0[j] + bj, 0.f);
        out[(long)(m0 + 1) * 1024 + n4 + j] = fmaxf(c1[j] + bj, 0.f);
    }
}

// g2: [256,1024]@[1024,128]+b (no relu). 2 rows/block, thread-per-output.
__global__ __launch_bounds__(256) void head_g2(const float* __restrict__ G1,
                                               const float* __restrict__ W,
                                               const float* __restrict__ bias,
                                               float* __restrict__ out)
{
    __shared__ float a0[1024], a1[1024];
    const int m0 = blockIdx.x * 2;
    for (int i = threadIdx.x; i < 1024; i += 256) {
        a0[i] = G1[(long)m0 * 1024 + i];
        a1[i] = G1[(long)(m0 + 1) * 1024 + i];
    }
    __syncthreads();
    const int nn = threadIdx.x & 127;
    const int r = threadIdx.x >> 7;
    const float* a = r ? a1 : a0;
    float acc = 0.f;
    for (int k = 0; k < 1024; k += 4) {
#pragma unroll
        for (int u = 0; u < 4; ++u)
            acc += a[k + u] * W[(long)(k + u) * 128 + nn];
    }
    out[(long)(m0 + r) * 128 + nn] = acc + bias[nn];
}

// g3: out[m] = dot(G2[m,:128], Wo) + bo. One wave per row.
__global__ __launch_bounds__(256) void head_g3(const float* __restrict__ G2,
                                               const float* __restrict__ Wo,
                                               const float* __restrict__ bo,
                                               float* __restrict__ out)
{
    const int wv = threadIdx.x >> 6, lane = threadIdx.x & 63;
    const int m = blockIdx.x * 4 + wv;
    if (m >= N_GRAPHS) return;
    float s = G2[(long)m * 128 + lane] * Wo[lane]
            + G2[(long)m * 128 + 64 + lane] * Wo[64 + lane];
#pragma unroll
    for (int o = 32; o; o >>= 1) s += __shfl_down(s, o);
    if (lane == 0) out[m] = s + bo[0];
}

// ---------------------------------------------------------------------------
extern "C" void kernel_launch(void* const* d_in, const int* in_sizes, int n_in,
                              void* d_out, int out_size, void* d_ws, size_t ws_size,
                              hipStream_t stream)
{
    const float* x    = (const float*)d_in[0];
    const void*  ei   = d_in[1];
    const void*  batch= d_in[2];
    const float* W1   = (const float*)d_in[3];
    const float* att1 = (const float*)d_in[4];
    const float* b1   = (const float*)d_in[5];
    const float* W2   = (const float*)d_in[6];
    const float* att2 = (const float*)d_in[7];
    const float* b2   = (const float*)d_in[8];
    const float* W3   = (const float*)d_in[9];
    const float* att3 = (const float*)d_in[10];
    const float* b3   = (const float*)d_in[11];
    const float* Wg1  = (const float*)d_in[12];
    const float* bg1  = (const float*)d_in[13];
    const float* Wg2  = (const float*)d_in[14];
    const float* bg2  = (const float*)d_in[15];
    const float* Wo   = (const float*)d_in[16];
    const float* bo   = (const float*)d_in[17];

    const int N = N_NODES;
    const int E = in_sizes[1] / 2;

    // ---- workspace layout (float units), ~148 MB ----
    float* ws = (float*)d_ws;
    ushort_t* H1b  = (ushort_t*)ws;                        // 30000*320 sh
    ushort_t* H2b  = (ushort_t*)(ws + 4800000);            // 30000*640 sh
    ushort_t* ABF1 = (ushort_t*)(ws + 14400000);           // 30000*128 sh
    ushort_t* XHb  = (ushort_t*)(ws + 16320000);           // 30000*1248 sh
    ushort_t* WT   = (ushort_t*)(ws + 35040000);           // 1248*640 sh
    float* ADST  = ws + 35440000;                          // 120000
    float* ASRC  = ws + 35560000;                          // 120000
    float* ALPHA = ws + 35680000;                          // 400000
    float* WD    = ws + 36080000;                          // 4096
    float* WSV   = ws + 36084096;                          // 4096
    float* G     = ws + 36088192;                          // 319488
    float* G1    = ws + 36407680;                          // 262144
    float* G2    = ws + 36669824;                          // 32768
    int*   INDEG = (int*)(ws + 36702592);                  // 30000
    int*   OFF   = (int*)(ws + 36732592);                  // 30001
    int*   CURS  = (int*)(ws + 36762593);                  // 30000
    int*   SLOTS = (int*)(ws + 36792593);                  // E (<=100000)
    int*   FLAGS = (int*)(ws + 36892593);                  // 2
    int*   GCNT  = (int*)(ws + 36892595);                  // 256
    int*   GSTART= (int*)(ws + 36892851);                  // 257

    dim3 blk(256);

    detect_fmt<<<dim3(1), blk, 0, stream>>>(ei, batch, E, FLAGS);

    hipMemsetAsync(H1b, 0, (size_t)N * 320 * sizeof(ushort_t), stream);
    hipMemsetAsync(H2b, 0, (size_t)N * 640 * sizeof(ushort_t), stream);
    hipMemsetAsync(INDEG, 0, (size_t)N * sizeof(int), stream);
    hipMemsetAsync(GCNT, 0, N_GRAPHS * sizeof(int), stream);

    csr_hist<<<dim3((E + 255) / 256), blk, 0, stream>>>(ei, FLAGS, INDEG, E);
    csr_scan<<<dim3(1), dim3(1024), 0, stream>>>(INDEG, OFF, CURS);
    csr_fill<<<dim3((E + 255) / 256), blk, 0, stream>>>(ei, FLAGS, CURS, SLOTS, E);

    ghist<<<dim3((N + 255) / 256), blk, 0, stream>>>(batch, FLAGS, GCNT);
    gscan<<<dim3(1), blk, 0, stream>>>(GCNT, GSTART);

    conv_pad_bf16<<<dim3(8192), blk, 0, stream>>>(x, ABF1, 78, 128, (long)N);

    struct Layer {
        const void* A; int lda; int K; int isbf;   // node_proj input
        const ushort_t* Abf; int Kp;               // gemm A (padded bf16)
        const float *W, *att, *b;
        int C, HC;
        ushort_t* outb; int ldo;                   // layers 1,2
        int pool;                                  // layer 3
    };
    Layer L[3] = {
        { x,   78,  78,  0, ABF1, 128, W1, att1, b1,  78,  312, H1b, 320, 0 },
        { H1b, 320, 312, 1, H1b,  320, W2, att2, b2, 156,  624, H2b, 640, 0 },
        { H2b, 640, 624, 1, H2b,  640, W3, att3, b3, 312, 1248, nullptr, 0, 1 },
    };

    for (int li = 0; li < 3; ++li) {
        const Layer& l = L[li];
        int nch = l.Kp >> 3;
        wt_bf16<<<dim3((l.HC * nch + 255) / 256), blk, 0, stream>>>(l.W, WT, l.K, l.Kp, l.HC);
        make_watt<<<dim3((l.K * HEADS + 255) / 256), blk, 0, stream>>>(l.W, l.att, WD, WSV, l.K, l.C, l.HC);
        node_proj_any<<<dim3((N + 3) / 4), blk, 0, stream>>>(l.A, l.lda, l.K, l.isbf, WD, WSV, ADST, ASRC, N);
        edge_alpha<<<dim3((E + 255) / 256), blk, 0, stream>>>(ei, FLAGS, ADST, ASRC, ALPHA, E);

        // one GEMM over all heads: XHb[N][HC] = A @ WT^T
        dim3 gg((l.HC + BN - 1) / BN, (N + BM - 1) / BM);
        gemm_bf16<<<gg, blk, 0, stream>>>(l.Abf, WT, XHb, N, l.HC, l.Kp);

        if (l.pool) {
            // fused gather + bias + relu + segment-max (no atomics)
            dim3 pg(N_GRAPHS, (l.HC + 255) / 256);
            pool_gather<<<pg, blk, 0, stream>>>(OFF, SLOTS, ei, FLAGS, ALPHA,
                                                XHb, l.b, GSTART, G, l.HC, l.C);
        } else {
            gat_gather_all<<<dim3((N + 3) / 4), blk, 0, stream>>>(
                OFF, SLOTS, ei, FLAGS, ALPHA, XHb, l.b, l.outb, l.ldo, l.HC, l.C);
        }
    }

    // ---- MLP head (f32 exact) ----
    head_g1<<<dim3(N_GRAPHS / 2), blk, 0, stream>>>(G, Wg1, bg1, G1);
    head_g2<<<dim3(N_GRAPHS / 2), blk, 0, stream>>>(G1, Wg2, bg2, G2);
    head_g3<<<dim3(N_GRAPHS / 4), blk, 0, stream>>>(G2, Wo, bo, (float*)d_out);
}

// Round 6
// 750.457 us; speedup vs baseline: 5.5047x; 1.1635x over previous
//
#include <hip/hip_runtime.h>
#include <hip/hip_bf16.h>

#define N_NODES 30000
#define N_GRAPHS 256
#define HEADS 4

typedef __attribute__((ext_vector_type(8))) short short8;
typedef __attribute__((ext_vector_type(4))) float f32x4;
typedef __attribute__((ext_vector_type(4))) unsigned short ushort4_t;
typedef unsigned short ushort_t;

__device__ __forceinline__ ushort_t f2bf(float v) {
    __hip_bfloat16 h = __float2bfloat16(v);
    return *reinterpret_cast<ushort_t*>(&h);
}
__device__ __forceinline__ float bf2f(ushort_t u) {
    __hip_bfloat16 h;
    *reinterpret_cast<ushort_t*>(&h) = u;
    return __bfloat162float(h);
}
__device__ __forceinline__ int ld_idx(const void* p, long i, int is64) {
    return is64 ? (int)((const long long*)p)[i] : ((const int*)p)[i];
}
__device__ __forceinline__ int clampi(int v, int hi) {
    return v < 0 ? 0 : (v > hi ? hi : v);
}

// ---------------------------------------------------------------------------
__global__ void detect_fmt(const void* ei, const void* batch, int E, int* flags)
{
    __shared__ int okE, okB;
    if (threadIdx.x == 0) { okE = 1; okB = 1; }
    __syncthreads();
    const long long* e64 = (const long long*)ei;
    const long long* b64 = (const long long*)batch;
    const int nbslot = N_NODES / 2;
    for (int i = threadIdx.x; i < 2048; i += 256) {
        long ei_idx = (long)i * E / 2048;
        long long v = e64[ei_idx];
        if (v < 0 || v >= N_NODES) okE = 0;
        long b_idx = (long)i * nbslot / 2048;
        long long b = b64[b_idx];
        if (b < 0 || b >= N_GRAPHS) okB = 0;
    }
    __syncthreads();
    if (threadIdx.x == 0) { flags[0] = okE; flags[1] = okB; }
}

// ---------------------------------------------------------------------------
// CSR build (by dst). csr_fill also records the CSR-ordered src list.
// ---------------------------------------------------------------------------
__global__ void csr_hist(const void* ei, const int* __restrict__ flags,
                         int* __restrict__ indeg, int E)
{
    int i = blockIdx.x * blockDim.x + threadIdx.x;
    if (i >= E) return;
    int d = clampi(ld_idx(ei, (long)E + i, flags[0]), N_NODES - 1);
    atomicAdd(&indeg[d], 1);
}

__global__ __launch_bounds__(1024) void csr_scan(const int* __restrict__ indeg,
                                                 int* __restrict__ off,
                                                 int* __restrict__ cursor)
{
    __shared__ int ps[1024];
    const int t = threadIdx.x;
    const int CH = (N_NODES + 1023) / 1024;
    const int base = t * CH;
    int s = 0;
    for (int i = 0; i < CH; ++i) { int idx = base + i; if (idx < N_NODES) s += indeg[idx]; }
    ps[t] = s;
    __syncthreads();
    for (int d = 1; d < 1024; d <<= 1) {
        int v = (t >= d) ? ps[t - d] : 0;
        __syncthreads();
        ps[t] += v;
        __syncthreads();
    }
    int excl = (t == 0) ? 0 : ps[t - 1];
    for (int i = 0; i < CH; ++i) {
        int idx = base + i;
        if (idx < N_NODES) { off[idx] = excl; cursor[idx] = excl; excl += indeg[idx]; }
    }
    if (t == 1023) off[N_NODES] = ps[1023];
}

__global__ void csr_fill(const void* ei, const int* __restrict__ flags,
                         int* __restrict__ cursor, int* __restrict__ slots,
                         int* __restrict__ srcs, int E)
{
    int i = blockIdx.x * blockDim.x + threadIdx.x;
    if (i >= E) return;
    int is64 = flags[0];
    int d = clampi(ld_idx(ei, (long)E + i, is64), N_NODES - 1);
    int s = clampi(ld_idx(ei, i, is64), N_NODES - 1);
    int p = atomicAdd(&cursor[d], 1);
    slots[p] = i;
    srcs[p] = s;
}

// ---------------------------------------------------------------------------
// graph segment boundaries (batch is sorted): GSTART[g]..GSTART[g+1]
// ---------------------------------------------------------------------------
__global__ void ghist(const void* batch, const int* __restrict__ flags,
                      int* __restrict__ gcnt)
{
    int n = blockIdx.x * blockDim.x + threadIdx.x;
    if (n >= N_NODES) return;
    int g = clampi(ld_idx(batch, n, flags[1]), N_GRAPHS - 1);
    atomicAdd(&gcnt[g], 1);
}

__global__ __launch_bounds__(256) void gscan(const int* __restrict__ gcnt,
                                             int* __restrict__ gstart)
{
    __shared__ int ps[256];
    const int t = threadIdx.x;
    ps[t] = gcnt[t];
    __syncthreads();
    for (int d = 1; d < 256; d <<= 1) {
        int v = (t >= d) ? ps[t - d] : 0;
        __syncthreads();
        ps[t] += v;
        __syncthreads();
    }
    gstart[t + 1] = ps[t];
    if (t == 0) gstart[0] = 0;
}

// ---------------------------------------------------------------------------
// conversions
// ---------------------------------------------------------------------------
__global__ void conv_pad_bf16(const float* __restrict__ src, ushort_t* __restrict__ dst,
                              int K, int Kp, long M)
{
    long total = M * Kp;
    long stride = (long)gridDim.x * blockDim.x;
    for (long i = (long)blockIdx.x * blockDim.x + threadIdx.x; i < total; i += stride) {
        long n = i / Kp;
        int k = (int)(i - n * Kp);
        dst[i] = (k < K) ? f2bf(src[n * K + k]) : (ushort_t)0;
    }
}

// WT[n][kp] = bf16(W[k][n]), zero-padded k>=K
__global__ void wt_bf16(const float* __restrict__ W, ushort_t* __restrict__ WT,
                        int K, int Kp, int HC)
{
    int nch = Kp >> 3;
    int i = blockIdx.x * blockDim.x + threadIdx.x;
    if (i >= HC * nch) return;
    int n = i / nch, c8 = i - n * nch;
#pragma unroll
    for (int e = 0; e < 8; ++e) {
        int k = c8 * 8 + e;
        WT[(long)n * Kp + k] = (k < K) ? f2bf(W[(long)k * HC + n]) : (ushort_t)0;
    }
}

// ---------------------------------------------------------------------------
// Wd[k,h], Ws[k,h] = per-head att projections of W (f32, exact)
// ---------------------------------------------------------------------------
__global__ void make_watt(const float* __restrict__ W, const float* __restrict__ att,
                          float* __restrict__ Wd, float* __restrict__ Wsv,
                          int K, int C, int HC)
{
    int i = blockIdx.x * blockDim.x + threadIdx.x;
    if (i >= K * HEADS) return;
    int k = i >> 2, h = i & 3;
    const float* wrow = W + (long)k * HC + h * C;
    const float* ad = att + h * 2 * C;
    const float* as = ad + C;
    float s1 = 0.f, s2 = 0.f;
    for (int c = 0; c < C; ++c) { float w = wrow[c]; s1 += w * ad[c]; s2 += w * as[c]; }
    Wd[k * HEADS + h] = s1;
    Wsv[k * HEADS + h] = s2;
}

// ---------------------------------------------------------------------------
// adst/asrc per node. A may be f32 (lda,K) or bf16 padded (lda=Kp).
// ---------------------------------------------------------------------------
__global__ __launch_bounds__(256) void node_proj_any(const void* __restrict__ A,
                                                     int lda, int K, int isbf,
                                                     const float* __restrict__ Wd,
                                                     const float* __restrict__ Wsv,
                                                     float* __restrict__ adst,
                                                     float* __restrict__ asrc, int N)
{
    const int wv = threadIdx.x >> 6, lane = threadIdx.x & 63;
    const int n = blockIdx.x * 4 + wv;
    if (n >= N) return;
    float sd[HEADS] = {}, ss[HEADS] = {};
    for (int k = lane; k < K; k += 64) {
        float v = isbf ? bf2f(((const ushort_t*)A)[(long)n * lda + k])
                       : ((const float*)A)[(long)n * lda + k];
#pragma unroll
        for (int h = 0; h < HEADS; ++h) {
            sd[h] += v * Wd[k * HEADS + h];
            ss[h] += v * Wsv[k * HEADS + h];
        }
    }
#pragma unroll
    for (int off = 32; off; off >>= 1) {
#pragma unroll
        for (int h = 0; h < HEADS; ++h) {
            sd[h] += __shfl_down(sd[h], off);
            ss[h] += __shfl_down(ss[h], off);
        }
    }
    if (lane == 0) {
#pragma unroll
        for (int h = 0; h < HEADS; ++h) {
            adst[n * HEADS + h] = sd[h];
            asrc[n * HEADS + h] = ss[h];
        }
    }
}

// ---------------------------------------------------------------------------
// Per-CSR-slot softmax over heads -> ALPHAC[p][4] (CSR order, f32x4)
// ---------------------------------------------------------------------------
__global__ void edge_alpha_csr(const int* __restrict__ slots,
                               const void* __restrict__ ei, const int* __restrict__ flags,
                               const float* __restrict__ adst, const float* __restrict__ asrc,
                               float* __restrict__ alphac, int E)
{
    int p = blockIdx.x * blockDim.x + threadIdx.x;
    if (p >= E) return;
    int is64 = flags[0];
    int e = slots[p];
    int s = clampi(ld_idx(ei, e, is64), N_NODES - 1);
    int d = clampi(ld_idx(ei, (long)E + e, is64), N_NODES - 1);
    float a[HEADS], m = -1e30f;
#pragma unroll
    for (int h = 0; h < HEADS; ++h) {
        float v = adst[d * HEADS + h] + asrc[s * HEADS + h];
        v = (v > 0.f) ? v : 0.2f * v;
        a[h] = v;
        m = fmaxf(m, v);
    }
    float sum = 0.f;
#pragma unroll
    for (int h = 0; h < HEADS; ++h) { a[h] = __expf(a[h] - m); sum += a[h]; }
    float inv = 1.f / sum;
    f32x4 o;
#pragma unroll
    for (int h = 0; h < HEADS; ++h) o[h] = a[h] * inv;
    *(f32x4*)&alphac[(long)p * HEADS] = o;
}

// ---------------------------------------------------------------------------
// bf16 MFMA GEMM: C[M][FC] (bf16) = A[M][Kp] @ WT[n][Kp]^T  (all heads)
// BM=128 BN=64 BK=64, 4 waves (2x2), XOR-swizzled LDS, reg-staged.
// ---------------------------------------------------------------------------
#define BM 128
#define BN 64
#define BK 64
__global__ __launch_bounds__(256) void gemm_bf16(const ushort_t* __restrict__ A,
                                                 const ushort_t* __restrict__ WT,
                                                 ushort_t* __restrict__ C,
                                                 int M, int FC, int Kp)
{
    __shared__ ushort_t As[BM * BK];
    __shared__ ushort_t Bs[BN * BK];
    const int tid = threadIdx.x;
    const int lane = tid & 63;
    const int wid = tid >> 6;
    const int wm = wid >> 1, wn = wid & 1;
    const int row0 = blockIdx.y * BM;
    const int colb = blockIdx.x * BN;

    f32x4 acc[4][2];
#pragma unroll
    for (int i = 0; i < 4; ++i)
#pragma unroll
        for (int j = 0; j < 2; ++j) { f32x4 z = {0.f, 0.f, 0.f, 0.f}; acc[i][j] = z; }

    short8 ra[4], rb[2];

    auto loadG = [&](int k0) {
#pragma unroll
        for (int r = 0; r < 4; ++r) {
            int id = r * 256 + tid;
            int row = id >> 3, j = id & 7;
            long grow = min(row0 + row, M - 1);
            ra[r] = *(const short8*)&A[grow * Kp + k0 + j * 8];
        }
#pragma unroll
        for (int r = 0; r < 2; ++r) {
            int id = r * 256 + tid;
            int row = id >> 3, j = id & 7;
            long gcol = min(colb + row, FC - 1);
            rb[r] = *(const short8*)&WT[gcol * Kp + k0 + j * 8];
        }
    };

    loadG(0);
    for (int k0 = 0; k0 < Kp; k0 += BK) {
        __syncthreads();
#pragma unroll
        for (int r = 0; r < 4; ++r) {
            int id = r * 256 + tid;
            int row = id >> 3, j = id & 7;
            *(short8*)&As[row * BK + ((j ^ (row & 7)) << 3)] = ra[r];
        }
#pragma unroll
        for (int r = 0; r < 2; ++r) {
            int id = r * 256 + tid;
            int row = id >> 3, j = id & 7;
            *(short8*)&Bs[row * BK + ((j ^ (row & 7)) << 3)] = rb[r];
        }
        __syncthreads();
        if (k0 + BK < Kp) loadG(k0 + BK);
#pragma unroll
        for (int ks = 0; ks < 2; ++ks) {
            short8 af[4], bfr[2];
            const int jr = ks * 4 + (lane >> 4);
#pragma unroll
            for (int fm = 0; fm < 4; ++fm) {
                int row = wm * 64 + fm * 16 + (lane & 15);
                af[fm] = *(const short8*)&As[row * BK + ((jr ^ (row & 7)) << 3)];
            }
#pragma unroll
            for (int fn = 0; fn < 2; ++fn) {
                int row = wn * 32 + fn * 16 + (lane & 15);
                bfr[fn] = *(const short8*)&Bs[row * BK + ((jr ^ (row & 7)) << 3)];
            }
#pragma unroll
            for (int fm = 0; fm < 4; ++fm)
#pragma unroll
                for (int fn = 0; fn < 2; ++fn)
                    acc[fm][fn] = __builtin_amdgcn_mfma_f32_16x16x32_bf16(
                        af[fm], bfr[fn], acc[fm][fn], 0, 0, 0);
        }
    }

#pragma unroll
    for (int fm = 0; fm < 4; ++fm) {
        int rbase = row0 + wm * 64 + fm * 16 + (lane >> 4) * 4;
#pragma unroll
        for (int fn = 0; fn < 2; ++fn) {
            int col = colb + wn * 32 + fn * 16 + (lane & 15);
            if (col >= FC) continue;
#pragma unroll
            for (int r = 0; r < 4; ++r) {
                int gr = rbase + r;
                if (gr < M) C[(long)gr * FC + col] = f2bf(acc[fm][fn][r]);
            }
        }
    }
}

// ---------------------------------------------------------------------------
// CSR gather, all heads, layers 1/2 (plain coalesced bf16 stores):
// outb[n*ldo + c] = bf16(relu(bias[c] + sum_p alphac[p, c/FC] * xh[srcs[p], c]))
// ---------------------------------------------------------------------------
__global__ __launch_bounds__(256) void gat_gather_all(const int* __restrict__ off,
                                                      const int* __restrict__ srcs,
                                                      const float* __restrict__ alphac,
                                                      const ushort_t* __restrict__ xh,
                                                      const float* __restrict__ bias,
                                                      ushort_t* __restrict__ outb, int ldo,
                                                      int HC, int FC)
{
    const int wv = threadIdx.x >> 6, lane = threadIdx.x & 63;
    const int n = blockIdx.x * 4 + wv;
    if (n >= N_NODES) return;
    const int nch = (HC + 255) >> 8;          // <= 3 for layers 1/2
    float acc[3][4];
#pragma unroll
    for (int i = 0; i < 3; ++i)
#pragma unroll
        for (int j = 0; j < 4; ++j) acc[i][j] = 0.f;

    const int s0 = off[n], s1 = off[n + 1];
    for (int i = s0; i < s1; ++i) {
        f32x4 al = *(const f32x4*)&alphac[(long)i * HEADS];
        int s = srcs[i];
        const ushort_t* xs = xh + (long)s * HC;
        for (int ch = 0; ch < nch; ++ch) {
            int base = (ch << 8) + lane * 4;
            if (base >= HC) break;
            ushort4_t v = *(const ushort4_t*)&xs[base];
#pragma unroll
            for (int j = 0; j < 4; ++j) {
                int c = base + j;
                float w = (c < FC) ? al[0] : (c < 2 * FC) ? al[1]
                         : (c < 3 * FC) ? al[2] : al[3];
                acc[ch][j] += w * bf2f(v[j]);
            }
        }
    }

    for (int ch = 0; ch < nch; ++ch) {
        int base = (ch << 8) + lane * 4;
        if (base >= HC) break;
        ushort4_t o;
#pragma unroll
        for (int j = 0; j < 4; ++j)
            o[j] = f2bf(fmaxf(acc[ch][j] + bias[base + j], 0.f));
        *(ushort4_t*)&outb[(long)n * ldo + base] = o;
    }
}

// ---------------------------------------------------------------------------
// Layer 3 fused: gather + bias + relu + segment-max, node-split for occupancy.
// block = (graph g * NSPLIT + split, column chunk); thread = one column.
// Partial max over the node sub-range, then one atomicMax per (block,col).
// G pre-zeroed; values >= 0 so uint-bits atomicMax is exact & deterministic.
// ---------------------------------------------------------------------------
#define NSPLIT 8
__global__ __launch_bounds__(256) void pool_gather(const int* __restrict__ off,
                                                   const int* __restrict__ srcs,
                                                   const float* __restrict__ alphac,
                                                   const ushort_t* __restrict__ xh,
                                                   const float* __restrict__ bias,
                                                   const int* __restrict__ gstart,
                                                   float* __restrict__ G,
                                                   int HC, int FC)
{
    const int g = blockIdx.x / NSPLIT;
    const int sp = blockIdx.x - g * NSPLIT;
    const int col = blockIdx.y * 256 + threadIdx.x;
    if (col >= HC) return;
    const int h = col / FC;
    const float bcol = bias[col];
    const ushort_t* xcol = xh + col;

    const int n0 = gstart[g], n1 = gstart[g + 1];
    const int len = n1 - n0;
    const int ch = (len + NSPLIT - 1) / NSPLIT;
    const int na = n0 + sp * ch;
    const int nb = min(na + ch, n1);
    if (na >= nb) return;

    float gmax = 0.f;                        // relu floor
    for (int n = na; n < nb; ++n) {
        float acc = 0.f;
        const int s0 = off[n], s1 = off[n + 1];
        for (int i = s0; i < s1; ++i) {
            float w = alphac[(long)i * HEADS + h];
            int s = srcs[i];
            acc += w * bf2f(xcol[(long)s * HC]);
        }
        gmax = fmaxf(gmax, fmaxf(acc + bcol, 0.f));
    }
    atomicMax((unsigned int*)&G[(long)g * 1248 + col], __float_as_uint(gmax));
}

// ---------------------------------------------------------------------------
// MLP head. g1: [256,1248]@[1248,1024]+b, relu. 2 rows/block, float4/thread.
// ---------------------------------------------------------------------------
__global__ __launch_bounds__(256) void head_g1(const float* __restrict__ Gp,
                                               const float* __restrict__ W,
                                               const float* __restrict__ bias,
                                               float* __restrict__ out)
{
    __shared__ float a0[1248], a1[1248];
    const int m0 = blockIdx.x * 2;
    for (int i = threadIdx.x; i < 1248; i += 256) {
        a0[i] = Gp[(long)m0 * 1248 + i];
        a1[i] = Gp[(long)(m0 + 1) * 1248 + i];
    }
    __syncthreads();
    const int n4 = threadIdx.x * 4;
    float c0[4] = {}, c1[4] = {};
    for (int k = 0; k < 1248; ++k) {
        f32x4 b = *(const f32x4*)&W[(long)k * 1024 + n4];
        float av0 = a0[k], av1 = a1[k];
#pragma unroll
        for (int j = 0; j < 4; ++j) { c0[j] += av0 * b[j]; c1[j] += av1 * b[j]; }
    }
#pragma unroll
    for (int j = 0; j < 4; ++j) {
        float bj = bias[n4 + j];
        out[(long)m0 * 1024 + n4 + j]       = fmaxf(c0[j] + bj, 0.f);
        out[(long)(m0 + 1) * 1024 + n4 + j] = fmaxf(c1[j] + bj, 0.f);
    }
}

// g2: [256,1024]@[1024,128]+b (no relu). 2 rows/block, thread-per-output.
__global__ __launch_bounds__(256) void head_g2(const float* __restrict__ G1,
                                               const float* __restrict__ W,
                                               const float* __restrict__ bias,
                                               float* __restrict__ out)
{
    __shared__ float a0[1024], a1[1024];
    const int m0 = blockIdx.x * 2;
    for (int i = threadIdx.x; i < 1024; i += 256) {
        a0[i] = G1[(long)m0 * 1024 + i];
        a1[i] = G1[(long)(m0 + 1) * 1024 + i];
    }
    __syncthreads();
    const int nn = threadIdx.x & 127;
    const int r = threadIdx.x >> 7;
    const float* a = r ? a1 : a0;
    float acc = 0.f;
    for (int k = 0; k < 1024; k += 4) {
#pragma unroll
        for (int u = 0; u < 4; ++u)
            acc += a[k + u] * W[(long)(k + u) * 128 + nn];
    }
    out[(long)(m0 + r) * 128 + nn] = acc + bias[nn];
}

// g3: out[m] = dot(G2[m,:128], Wo) + bo. One wave per row.
__global__ __launch_bounds__(256) void head_g3(const float* __restrict__ G2,
                                               const float* __restrict__ Wo,
                                               const float* __restrict__ bo,
                                               float* __restrict__ out)
{
    const int wv = threadIdx.x >> 6, lane = threadIdx.x & 63;
    const int m = blockIdx.x * 4 + wv;
    if (m >= N_GRAPHS) return;
    float s = G2[(long)m * 128 + lane] * Wo[lane]
            + G2[(long)m * 128 + 64 + lane] * Wo[64 + lane];
#pragma unroll
    for (int o = 32; o; o >>= 1) s += __shfl_down(s, o);
    if (lane == 0) out[m] = s + bo[0];
}

// ---------------------------------------------------------------------------
extern "C" void kernel_launch(void* const* d_in, const int* in_sizes, int n_in,
                              void* d_out, int out_size, void* d_ws, size_t ws_size,
                              hipStream_t stream)
{
    const float* x    = (const float*)d_in[0];
    const void*  ei   = d_in[1];
    const void*  batch= d_in[2];
    const float* W1   = (const float*)d_in[3];
    const float* att1 = (const float*)d_in[4];
    const float* b1   = (const float*)d_in[5];
    const float* W2   = (const float*)d_in[6];
    const float* att2 = (const float*)d_in[7];
    const float* b2   = (const float*)d_in[8];
    const float* W3   = (const float*)d_in[9];
    const float* att3 = (const float*)d_in[10];
    const float* b3   = (const float*)d_in[11];
    const float* Wg1  = (const float*)d_in[12];
    const float* bg1  = (const float*)d_in[13];
    const float* Wg2  = (const float*)d_in[14];
    const float* bg2  = (const float*)d_in[15];
    const float* Wo   = (const float*)d_in[16];
    const float* bo   = (const float*)d_in[17];

    const int N = N_NODES;
    const int E = in_sizes[1] / 2;

    // ---- workspace layout (float units), ~149 MB ----
    float* ws = (float*)d_ws;
    ushort_t* H1b  = (ushort_t*)ws;                        // 30000*320 sh
    ushort_t* H2b  = (ushort_t*)(ws + 4800000);            // 30000*640 sh
    ushort_t* ABF1 = (ushort_t*)(ws + 14400000);           // 30000*128 sh
    ushort_t* XHb  = (ushort_t*)(ws + 16320000);           // 30000*1248 sh
    ushort_t* WT   = (ushort_t*)(ws + 35040000);           // 1248*640 sh
    float* ADST  = ws + 35440000;                          // 120000
    float* ASRC  = ws + 35560000;                          // 120000
    float* ALPHAC= ws + 35680000;                          // 400000 (CSR order)
    float* WD    = ws + 36080000;                          // 4096
    float* WSV   = ws + 36084096;                          // 4096
    float* G     = ws + 36088192;                          // 319488
    float* G1    = ws + 36407680;                          // 262144
    float* G2    = ws + 36669824;                          // 32768
    int*   INDEG = (int*)(ws + 36702592);                  // 30000
    int*   OFF   = (int*)(ws + 36732592);                  // 30001
    int*   CURS  = (int*)(ws + 36762593);                  // 30000
    int*   SLOTS = (int*)(ws + 36792593);                  // E (<=100000)
    int*   SRCS  = (int*)(ws + 36892593);                  // E (<=100000)
    int*   FLAGS = (int*)(ws + 36992593);                  // 2
    int*   GCNT  = (int*)(ws + 36992595);                  // 256
    int*   GSTART= (int*)(ws + 36992851);                  // 257

    dim3 blk(256);

    detect_fmt<<<dim3(1), blk, 0, stream>>>(ei, batch, E, FLAGS);

    hipMemsetAsync(H1b, 0, (size_t)N * 320 * sizeof(ushort_t), stream);
    hipMemsetAsync(H2b, 0, (size_t)N * 640 * sizeof(ushort_t), stream);
    hipMemsetAsync(G, 0, (size_t)N_GRAPHS * 1248 * sizeof(float), stream);
    hipMemsetAsync(INDEG, 0, (size_t)N * sizeof(int), stream);
    hipMemsetAsync(GCNT, 0, N_GRAPHS * sizeof(int), stream);

    csr_hist<<<dim3((E + 255) / 256), blk, 0, stream>>>(ei, FLAGS, INDEG, E);
    csr_scan<<<dim3(1), dim3(1024), 0, stream>>>(INDEG, OFF, CURS);
    csr_fill<<<dim3((E + 255) / 256), blk, 0, stream>>>(ei, FLAGS, CURS, SLOTS, SRCS, E);

    ghist<<<dim3((N + 255) / 256), blk, 0, stream>>>(batch, FLAGS, GCNT);
    gscan<<<dim3(1), blk, 0, stream>>>(GCNT, GSTART);

    conv_pad_bf16<<<dim3(8192), blk, 0, stream>>>(x, ABF1, 78, 128, (long)N);

    struct Layer {
        const void* A; int lda; int K; int isbf;   // node_proj input
        const ushort_t* Abf; int Kp;               // gemm A (padded bf16)
        const float *W, *att, *b;
        int C, HC;
        ushort_t* outb; int ldo;                   // layers 1,2
        int pool;                                  // layer 3
    };
    Layer L[3] = {
        { x,   78,  78,  0, ABF1, 128, W1, att1, b1,  78,  312, H1b, 320, 0 },
        { H1b, 320, 312, 1, H1b,  320, W2, att2, b2, 156,  624, H2b, 640, 0 },
        { H2b, 640, 624, 1, H2b,  640, W3, att3, b3, 312, 1248, nullptr, 0, 1 },
    };

    for (int li = 0; li < 3; ++li) {
        const Layer& l = L[li];
        int nch = l.Kp >> 3;
        wt_bf16<<<dim3((l.HC * nch + 255) / 256), blk, 0, stream>>>(l.W, WT, l.K, l.Kp, l.HC);
        make_watt<<<dim3((l.K * HEADS + 255) / 256), blk, 0, stream>>>(l.W, l.att, WD, WSV, l.K, l.C, l.HC);
        node_proj_any<<<dim3((N + 3) / 4), blk, 0, stream>>>(l.A, l.lda, l.K, l.isbf, WD, WSV, ADST, ASRC, N);
        edge_alpha_csr<<<dim3((E + 255) / 256), blk, 0, stream>>>(SLOTS, ei, FLAGS, ADST, ASRC, ALPHAC, E);

        // one GEMM over all heads: XHb[N][HC] = A @ WT^T
        dim3 gg((l.HC + BN - 1) / BN, (N + BM - 1) / BM);
        gemm_bf16<<<gg, blk, 0, stream>>>(l.Abf, WT, XHb, N, l.HC, l.Kp);

        if (l.pool) {
            dim3 pg(N_GRAPHS * NSPLIT, (l.HC + 255) / 256);
            pool_gather<<<pg, blk, 0, stream>>>(OFF, SRCS, ALPHAC, XHb, l.b,
                                                GSTART, G, l.HC, l.C);
        } else {
            gat_gather_all<<<dim3((N + 3) / 4), blk, 0, stream>>>(
                OFF, SRCS, ALPHAC, XHb, l.b, l.outb, l.ldo, l.HC, l.C);
        }
    }

    // ---- MLP head (f32 exact) ----
    head_g1<<<dim3(N_GRAPHS / 2), blk, 0, stream>>>(G, Wg1, bg1, G1);
    head_g2<<<dim3(N_GRAPHS / 2), blk, 0, stream>>>(G1, Wg2, bg2, G2);
    head_g3<<<dim3(N_GRAPHS / 4), blk, 0, stream>>>(G2, Wo, bo, (float*)d_out);
}

// Round 7
// 701.787 us; speedup vs baseline: 5.8865x; 1.0694x over previous
//
#include <hip/hip_runtime.h>
#include <hip/hip_bf16.h>

#define N_NODES 30000
#define N_GRAPHS 256
#define HEADS 4

typedef __attribute__((ext_vector_type(8))) short short8;
typedef __attribute__((ext_vector_type(4))) float f32x4;
typedef __attribute__((ext_vector_type(4))) unsigned short ushort4_t;
typedef unsigned short ushort_t;

__device__ __forceinline__ ushort_t f2bf(float v) {
    __hip_bfloat16 h = __float2bfloat16(v);
    return *reinterpret_cast<ushort_t*>(&h);
}
__device__ __forceinline__ float bf2f(ushort_t u) {
    __hip_bfloat16 h;
    *reinterpret_cast<ushort_t*>(&h) = u;
    return __bfloat162float(h);
}
__device__ __forceinline__ int ld_idx(const void* p, long i, int is64) {
    return is64 ? (int)((const long long*)p)[i] : ((const int*)p)[i];
}
__device__ __forceinline__ int clampi(int v, int hi) {
    return v < 0 ? 0 : (v > hi ? hi : v);
}

// ---------------------------------------------------------------------------
__global__ void detect_fmt(const void* ei, const void* batch, int E, int* flags)
{
    __shared__ int okE, okB;
    if (threadIdx.x == 0) { okE = 1; okB = 1; }
    __syncthreads();
    const long long* e64 = (const long long*)ei;
    const long long* b64 = (const long long*)batch;
    const int nbslot = N_NODES / 2;
    for (int i = threadIdx.x; i < 2048; i += 256) {
        long ei_idx = (long)i * E / 2048;
        long long v = e64[ei_idx];
        if (v < 0 || v >= N_NODES) okE = 0;
        long b_idx = (long)i * nbslot / 2048;
        long long b = b64[b_idx];
        if (b < 0 || b >= N_GRAPHS) okB = 0;
    }
    __syncthreads();
    if (threadIdx.x == 0) { flags[0] = okE; flags[1] = okB; }
}

// ---------------------------------------------------------------------------
// CSR build (by dst). csr_fill also records the CSR-ordered src list.
// ---------------------------------------------------------------------------
__global__ void csr_hist(const void* ei, const int* __restrict__ flags,
                         int* __restrict__ indeg, int E)
{
    int i = blockIdx.x * blockDim.x + threadIdx.x;
    if (i >= E) return;
    int d = clampi(ld_idx(ei, (long)E + i, flags[0]), N_NODES - 1);
    atomicAdd(&indeg[d], 1);
}

__global__ __launch_bounds__(1024) void csr_scan(const int* __restrict__ indeg,
                                                 int* __restrict__ off,
                                                 int* __restrict__ cursor)
{
    __shared__ int ps[1024];
    const int t = threadIdx.x;
    const int CH = (N_NODES + 1023) / 1024;
    const int base = t * CH;
    int s = 0;
    for (int i = 0; i < CH; ++i) { int idx = base + i; if (idx < N_NODES) s += indeg[idx]; }
    ps[t] = s;
    __syncthreads();
    for (int d = 1; d < 1024; d <<= 1) {
        int v = (t >= d) ? ps[t - d] : 0;
        __syncthreads();
        ps[t] += v;
        __syncthreads();
    }
    int excl = (t == 0) ? 0 : ps[t - 1];
    for (int i = 0; i < CH; ++i) {
        int idx = base + i;
        if (idx < N_NODES) { off[idx] = excl; cursor[idx] = excl; excl += indeg[idx]; }
    }
    if (t == 1023) off[N_NODES] = ps[1023];
}

__global__ void csr_fill(const void* ei, const int* __restrict__ flags,
                         int* __restrict__ cursor, int* __restrict__ slots,
                         int* __restrict__ srcs, int E)
{
    int i = blockIdx.x * blockDim.x + threadIdx.x;
    if (i >= E) return;
    int is64 = flags[0];
    int d = clampi(ld_idx(ei, (long)E + i, is64), N_NODES - 1);
    int s = clampi(ld_idx(ei, i, is64), N_NODES - 1);
    int p = atomicAdd(&cursor[d], 1);
    slots[p] = i;
    srcs[p] = s;
}

// ---------------------------------------------------------------------------
// graph segment boundaries (batch is sorted): GSTART[g]..GSTART[g+1]
// ---------------------------------------------------------------------------
__global__ void ghist(const void* batch, const int* __restrict__ flags,
                      int* __restrict__ gcnt)
{
    int n = blockIdx.x * blockDim.x + threadIdx.x;
    if (n >= N_NODES) return;
    int g = clampi(ld_idx(batch, n, flags[1]), N_GRAPHS - 1);
    atomicAdd(&gcnt[g], 1);
}

__global__ __launch_bounds__(256) void gscan(const int* __restrict__ gcnt,
                                             int* __restrict__ gstart)
{
    __shared__ int ps[256];
    const int t = threadIdx.x;
    ps[t] = gcnt[t];
    __syncthreads();
    for (int d = 1; d < 256; d <<= 1) {
        int v = (t >= d) ? ps[t - d] : 0;
        __syncthreads();
        ps[t] += v;
        __syncthreads();
    }
    gstart[t + 1] = ps[t];
    if (t == 0) gstart[0] = 0;
}

// ---------------------------------------------------------------------------
// conversions
// ---------------------------------------------------------------------------
__global__ void conv_pad_bf16(const float* __restrict__ src, ushort_t* __restrict__ dst,
                              int K, int Kp, long M)
{
    long total = M * Kp;
    long stride = (long)gridDim.x * blockDim.x;
    for (long i = (long)blockIdx.x * blockDim.x + threadIdx.x; i < total; i += stride) {
        long n = i / Kp;
        int k = (int)(i - n * Kp);
        dst[i] = (k < K) ? f2bf(src[n * K + k]) : (ushort_t)0;
    }
}

// WT[n][kp] = bf16(W[k][n]), zero-padded k>=K
__global__ void wt_bf16(const float* __restrict__ W, ushort_t* __restrict__ WT,
                        int K, int Kp, int HC)
{
    int nch = Kp >> 3;
    int i = blockIdx.x * blockDim.x + threadIdx.x;
    if (i >= HC * nch) return;
    int n = i / nch, c8 = i - n * nch;
#pragma unroll
    for (int e = 0; e < 8; ++e) {
        int k = c8 * 8 + e;
        WT[(long)n * Kp + k] = (k < K) ? f2bf(W[(long)k * HC + n]) : (ushort_t)0;
    }
}

// ---------------------------------------------------------------------------
// Wd[k,h], Ws[k,h] = per-head att projections of W (f32, exact)
// ---------------------------------------------------------------------------
__global__ void make_watt(const float* __restrict__ W, const float* __restrict__ att,
                          float* __restrict__ Wd, float* __restrict__ Wsv,
                          int K, int C, int HC)
{
    int i = blockIdx.x * blockDim.x + threadIdx.x;
    if (i >= K * HEADS) return;
    int k = i >> 2, h = i & 3;
    const float* wrow = W + (long)k * HC + h * C;
    const float* ad = att + h * 2 * C;
    const float* as = ad + C;
    float s1 = 0.f, s2 = 0.f;
    for (int c = 0; c < C; ++c) { float w = wrow[c]; s1 += w * ad[c]; s2 += w * as[c]; }
    Wd[k * HEADS + h] = s1;
    Wsv[k * HEADS + h] = s2;
}

// ---------------------------------------------------------------------------
// adst/asrc per node. A may be f32 (lda,K) or bf16 padded (lda=Kp).
// ---------------------------------------------------------------------------
__global__ __launch_bounds__(256) void node_proj_any(const void* __restrict__ A,
                                                     int lda, int K, int isbf,
                                                     const float* __restrict__ Wd,
                                                     const float* __restrict__ Wsv,
                                                     float* __restrict__ adst,
                                                     float* __restrict__ asrc, int N)
{
    const int wv = threadIdx.x >> 6, lane = threadIdx.x & 63;
    const int n = blockIdx.x * 4 + wv;
    if (n >= N) return;
    float sd[HEADS] = {}, ss[HEADS] = {};
    for (int k = lane; k < K; k += 64) {
        float v = isbf ? bf2f(((const ushort_t*)A)[(long)n * lda + k])
                       : ((const float*)A)[(long)n * lda + k];
#pragma unroll
        for (int h = 0; h < HEADS; ++h) {
            sd[h] += v * Wd[k * HEADS + h];
            ss[h] += v * Wsv[k * HEADS + h];
        }
    }
#pragma unroll
    for (int off = 32; off; off >>= 1) {
#pragma unroll
        for (int h = 0; h < HEADS; ++h) {
            sd[h] += __shfl_down(sd[h], off);
            ss[h] += __shfl_down(ss[h], off);
        }
    }
    if (lane == 0) {
#pragma unroll
        for (int h = 0; h < HEADS; ++h) {
            adst[n * HEADS + h] = sd[h];
            asrc[n * HEADS + h] = ss[h];
        }
    }
}

// ---------------------------------------------------------------------------
// Per-CSR-slot softmax over heads -> ALPHAC[p][4] (CSR order, f32x4)
// ---------------------------------------------------------------------------
__global__ void edge_alpha_csr(const int* __restrict__ slots,
                               const void* __restrict__ ei, const int* __restrict__ flags,
                               const float* __restrict__ adst, const float* __restrict__ asrc,
                               float* __restrict__ alphac, int E)
{
    int p = blockIdx.x * blockDim.x + threadIdx.x;
    if (p >= E) return;
    int is64 = flags[0];
    int e = slots[p];
    int s = clampi(ld_idx(ei, e, is64), N_NODES - 1);
    int d = clampi(ld_idx(ei, (long)E + e, is64), N_NODES - 1);
    float a[HEADS], m = -1e30f;
#pragma unroll
    for (int h = 0; h < HEADS; ++h) {
        float v = adst[d * HEADS + h] + asrc[s * HEADS + h];
        v = (v > 0.f) ? v : 0.2f * v;
        a[h] = v;
        m = fmaxf(m, v);
    }
    float sum = 0.f;
#pragma unroll
    for (int h = 0; h < HEADS; ++h) { a[h] = __expf(a[h] - m); sum += a[h]; }
    float inv = 1.f / sum;
    f32x4 o;
#pragma unroll
    for (int h = 0; h < HEADS; ++h) o[h] = a[h] * inv;
    *(f32x4*)&alphac[(long)p * HEADS] = o;
}

// ---------------------------------------------------------------------------
// bf16 MFMA GEMM: C[M][FC] (bf16) = A[M][Kp] @ WT[n][Kp]^T  (all heads)
// BM=128 BN=128 BK=64, 4 waves (2x2), wave tile 64x64.
// XOR-swizzled LDS, reg-staged global loads.
// ---------------------------------------------------------------------------
#define BM 128
#define BN 128
#define BK 64
__global__ __launch_bounds__(256) void gemm_bf16(const ushort_t* __restrict__ A,
                                                 const ushort_t* __restrict__ WT,
                                                 ushort_t* __restrict__ C,
                                                 int M, int FC, int Kp)
{
    __shared__ ushort_t As[BM * BK];
    __shared__ ushort_t Bs[BN * BK];
    const int tid = threadIdx.x;
    const int lane = tid & 63;
    const int wid = tid >> 6;
    const int wm = wid >> 1, wn = wid & 1;
    const int row0 = blockIdx.y * BM;
    const int colb = blockIdx.x * BN;

    f32x4 acc[4][4];
#pragma unroll
    for (int i = 0; i < 4; ++i)
#pragma unroll
        for (int j = 0; j < 4; ++j) { f32x4 z = {0.f, 0.f, 0.f, 0.f}; acc[i][j] = z; }

    short8 ra[4], rb[4];

    auto loadG = [&](int k0) {
#pragma unroll
        for (int r = 0; r < 4; ++r) {
            int id = r * 256 + tid;
            int row = id >> 3, j = id & 7;
            long grow = min(row0 + row, M - 1);
            ra[r] = *(const short8*)&A[grow * Kp + k0 + j * 8];
        }
#pragma unroll
        for (int r = 0; r < 4; ++r) {
            int id = r * 256 + tid;
            int row = id >> 3, j = id & 7;
            long gcol = min(colb + row, FC - 1);
            rb[r] = *(const short8*)&WT[gcol * Kp + k0 + j * 8];
        }
    };

    loadG(0);
    for (int k0 = 0; k0 < Kp; k0 += BK) {
        __syncthreads();
#pragma unroll
        for (int r = 0; r < 4; ++r) {
            int id = r * 256 + tid;
            int row = id >> 3, j = id & 7;
            *(short8*)&As[row * BK + ((j ^ (row & 7)) << 3)] = ra[r];
        }
#pragma unroll
        for (int r = 0; r < 4; ++r) {
            int id = r * 256 + tid;
            int row = id >> 3, j = id & 7;
            *(short8*)&Bs[row * BK + ((j ^ (row & 7)) << 3)] = rb[r];
        }
        __syncthreads();
        if (k0 + BK < Kp) loadG(k0 + BK);
#pragma unroll
        for (int ks = 0; ks < 2; ++ks) {
            short8 af[4], bfr[4];
            const int jr = ks * 4 + (lane >> 4);
#pragma unroll
            for (int fm = 0; fm < 4; ++fm) {
                int row = wm * 64 + fm * 16 + (lane & 15);
                af[fm] = *(const short8*)&As[row * BK + ((jr ^ (row & 7)) << 3)];
            }
#pragma unroll
            for (int fn = 0; fn < 4; ++fn) {
                int row = wn * 64 + fn * 16 + (lane & 15);
                bfr[fn] = *(const short8*)&Bs[row * BK + ((jr ^ (row & 7)) << 3)];
            }
#pragma unroll
            for (int fm = 0; fm < 4; ++fm)
#pragma unroll
                for (int fn = 0; fn < 4; ++fn)
                    acc[fm][fn] = __builtin_amdgcn_mfma_f32_16x16x32_bf16(
                        af[fm], bfr[fn], acc[fm][fn], 0, 0, 0);
        }
    }

#pragma unroll
    for (int fm = 0; fm < 4; ++fm) {
        int rbase = row0 + wm * 64 + fm * 16 + (lane >> 4) * 4;
#pragma unroll
        for (int fn = 0; fn < 4; ++fn) {
            int col = colb + wn * 64 + fn * 16 + (lane & 15);
            if (col >= FC) continue;
#pragma unroll
            for (int r = 0; r < 4; ++r) {
                int gr = rbase + r;
                if (gr < M) C[(long)gr * FC + col] = f2bf(acc[fm][fn][r]);
            }
        }
    }
}

// ---------------------------------------------------------------------------
// CSR gather, all heads, layers 1/2 (plain coalesced bf16 stores):
// outb[n*ldo + c] = bf16(relu(bias[c] + sum_p alphac[p, c/FC] * xh[srcs[p], c]))
// ---------------------------------------------------------------------------
__global__ __launch_bounds__(256) void gat_gather_all(const int* __restrict__ off,
                                                      const int* __restrict__ srcs,
                                                      const float* __restrict__ alphac,
                                                      const ushort_t* __restrict__ xh,
                                                      const float* __restrict__ bias,
                                                      ushort_t* __restrict__ outb, int ldo,
                                                      int HC, int FC)
{
    const int wv = threadIdx.x >> 6, lane = threadIdx.x & 63;
    const int n = blockIdx.x * 4 + wv;
    if (n >= N_NODES) return;
    const int nch = (HC + 255) >> 8;          // <= 3 for layers 1/2
    float acc[3][4];
#pragma unroll
    for (int i = 0; i < 3; ++i)
#pragma unroll
        for (int j = 0; j < 4; ++j) acc[i][j] = 0.f;

    const int s0 = off[n], s1 = off[n + 1];
    for (int i = s0; i < s1; ++i) {
        f32x4 al = *(const f32x4*)&alphac[(long)i * HEADS];
        int s = srcs[i];
        const ushort_t* xs = xh + (long)s * HC;
        for (int ch = 0; ch < nch; ++ch) {
            int base = (ch << 8) + lane * 4;
            if (base >= HC) break;
            ushort4_t v = *(const ushort4_t*)&xs[base];
#pragma unroll
            for (int j = 0; j < 4; ++j) {
                int c = base + j;
                float w = (c < FC) ? al[0] : (c < 2 * FC) ? al[1]
                         : (c < 3 * FC) ? al[2] : al[3];
                acc[ch][j] += w * bf2f(v[j]);
            }
        }
    }

    for (int ch = 0; ch < nch; ++ch) {
        int base = (ch << 8) + lane * 4;
        if (base >= HC) break;
        ushort4_t o;
#pragma unroll
        for (int j = 0; j < 4; ++j)
            o[j] = f2bf(fmaxf(acc[ch][j] + bias[base + j], 0.f));
        *(ushort4_t*)&outb[(long)n * ldo + base] = o;
    }
}

// ---------------------------------------------------------------------------
// Layer 3 fused: gather + bias + relu + segment-max, node-split, vectorized.
// block = (g*NSPLIT+split, 1024-col chunk); thread = 4 consecutive cols.
// Head index is uniform within a 4-col group (312 % 4 == 0).
// Partial max over node sub-range, one atomicMax per (block,col).
// ---------------------------------------------------------------------------
#define NSPLIT 8
__global__ __launch_bounds__(256) void pool_gather(const int* __restrict__ off,
                                                   const int* __restrict__ srcs,
                                                   const float* __restrict__ alphac,
                                                   const ushort_t* __restrict__ xh,
                                                   const float* __restrict__ bias,
                                                   const int* __restrict__ gstart,
                                                   float* __restrict__ G,
                                                   int HC, int FC)
{
    const int g = blockIdx.x / NSPLIT;
    const int sp = blockIdx.x - g * NSPLIT;
    const int col = blockIdx.y * 1024 + threadIdx.x * 4;
    if (col >= HC) return;
    const int h = col / FC;                  // uniform over the 4-col group
    const ushort_t* xcol = xh + col;

    const int n0 = gstart[g], n1 = gstart[g + 1];
    const int len = n1 - n0;
    const int ch = (len + NSPLIT - 1) / NSPLIT;
    const int na = n0 + sp * ch;
    const int nb = min(na + ch, n1);
    if (na >= nb) return;

    f32x4 bc = *(const f32x4*)&bias[col];
    float gmax[4] = {0.f, 0.f, 0.f, 0.f};    // relu floor
    for (int n = na; n < nb; ++n) {
        f32x4 acc = {0.f, 0.f, 0.f, 0.f};
        const int s0 = off[n], s1 = off[n + 1];
        for (int i = s0; i < s1; ++i) {
            float w = alphac[(long)i * HEADS + h];
            int s = srcs[i];
            ushort4_t v = *(const ushort4_t*)&xcol[(long)s * HC];
#pragma unroll
            for (int j = 0; j < 4; ++j) acc[j] += w * bf2f(v[j]);
        }
#pragma unroll
        for (int j = 0; j < 4; ++j)
            gmax[j] = fmaxf(gmax[j], fmaxf(acc[j] + bc[j], 0.f));
    }
#pragma unroll
    for (int j = 0; j < 4; ++j)
        atomicMax((unsigned int*)&G[(long)g * 1248 + col + j], __float_as_uint(gmax[j]));
}

// ---------------------------------------------------------------------------
// MLP head. g1: [256,1248]@[1248,1024]+b, relu. 2 rows/block, float4/thread.
// ---------------------------------------------------------------------------
__global__ __launch_bounds__(256) void head_g1(const float* __restrict__ Gp,
                                               const float* __restrict__ W,
                                               const float* __restrict__ bias,
                                               float* __restrict__ out)
{
    __shared__ float a0[1248], a1[1248];
    const int m0 = blockIdx.x * 2;
    for (int i = threadIdx.x; i < 1248; i += 256) {
        a0[i] = Gp[(long)m0 * 1248 + i];
        a1[i] = Gp[(long)(m0 + 1) * 1248 + i];
    }
    __syncthreads();
    const int n4 = threadIdx.x * 4;
    float c0[4] = {}, c1[4] = {};
    for (int k = 0; k < 1248; ++k) {
        f32x4 b = *(const f32x4*)&W[(long)k * 1024 + n4];
        float av0 = a0[k], av1 = a1[k];
#pragma unroll
        for (int j = 0; j < 4; ++j) { c0[j] += av0 * b[j]; c1[j] += av1 * b[j]; }
    }
#pragma unroll
    for (int j = 0; j < 4; ++j) {
        float bj = bias[n4 + j];
        out[(long)m0 * 1024 + n4 + j]       = fmaxf(c0[j] + bj, 0.f);
        out[(long)(m0 + 1) * 1024 + n4 + j] = fmaxf(c1[j] + bj, 0.f);
    }
}

// g2: [256,1024]@[1024,128]+b (no relu). 2 rows/block, thread-per-output.
__global__ __launch_bounds__(256) void head_g2(const float* __restrict__ G1,
                                               const float* __restrict__ W,
                                               const float* __restrict__ bias,
                                               float* __restrict__ out)
{
    __shared__ float a0[1024], a1[1024];
    const int m0 = blockIdx.x * 2;
    for (int i = threadIdx.x; i < 1024; i += 256) {
        a0[i] = G1[(long)m0 * 1024 + i];
        a1[i] = G1[(long)(m0 + 1) * 1024 + i];
    }
    __syncthreads();
    const int nn = threadIdx.x & 127;
    const int r = threadIdx.x >> 7;
    const float* a = r ? a1 : a0;
    float acc = 0.f;
    for (int k = 0; k < 1024; k += 4) {
#pragma unroll
        for (int u = 0; u < 4; ++u)
            acc += a[k + u] * W[(long)(k + u) * 128 + nn];
    }
    out[(long)(m0 + r) * 128 + nn] = acc + bias[nn];
}

// g3: out[m] = dot(G2[m,:128], Wo) + bo. One wave per row.
__global__ __launch_bounds__(256) void head_g3(const float* __restrict__ G2,
                                               const float* __restrict__ Wo,
                                               const float* __restrict__ bo,
                                               float* __restrict__ out)
{
    const int wv = threadIdx.x >> 6, lane = threadIdx.x & 63;
    const int m = blockIdx.x * 4 + wv;
    if (m >= N_GRAPHS) return;
    float s = G2[(long)m * 128 + lane] * Wo[lane]
            + G2[(long)m * 128 + 64 + lane] * Wo[64 + lane];
#pragma unroll
    for (int o = 32; o; o >>= 1) s += __shfl_down(s, o);
    if (lane == 0) out[m] = s + bo[0];
}

// ---------------------------------------------------------------------------
extern "C" void kernel_launch(void* const* d_in, const int* in_sizes, int n_in,
                              void* d_out, int out_size, void* d_ws, size_t ws_size,
                              hipStream_t stream)
{
    const float* x    = (const float*)d_in[0];
    const void*  ei   = d_in[1];
    const void*  batch= d_in[2];
    const float* W1   = (const float*)d_in[3];
    const float* att1 = (const float*)d_in[4];
    const float* b1   = (const float*)d_in[5];
    const float* W2   = (const float*)d_in[6];
    const float* att2 = (const float*)d_in[7];
    const float* b2   = (const float*)d_in[8];
    const float* W3   = (const float*)d_in[9];
    const float* att3 = (const float*)d_in[10];
    const float* b3   = (const float*)d_in[11];
    const float* Wg1  = (const float*)d_in[12];
    const float* bg1  = (const float*)d_in[13];
    const float* Wg2  = (const float*)d_in[14];
    const float* bg2  = (const float*)d_in[15];
    const float* Wo   = (const float*)d_in[16];
    const float* bo   = (const float*)d_in[17];

    const int N = N_NODES;
    const int E = in_sizes[1] / 2;

    // ---- workspace layout (float units), ~149 MB ----
    float* ws = (float*)d_ws;
    ushort_t* H1b  = (ushort_t*)ws;                        // 30000*320 sh
    ushort_t* H2b  = (ushort_t*)(ws + 4800000);            // 30000*640 sh
    ushort_t* ABF1 = (ushort_t*)(ws + 14400000);           // 30000*128 sh
    ushort_t* XHb  = (ushort_t*)(ws + 16320000);           // 30000*1248 sh
    ushort_t* WT   = (ushort_t*)(ws + 35040000);           // 1248*640 sh
    float* ADST  = ws + 35440000;                          // 120000
    float* ASRC  = ws + 35560000;                          // 120000
    float* ALPHAC= ws + 35680000;                          // 400000 (CSR order)
    float* WD    = ws + 36080000;                          // 4096
    float* WSV   = ws + 36084096;                          // 4096
    float* G     = ws + 36088192;                          // 319488
    float* G1    = ws + 36407680;                          // 262144
    float* G2    = ws + 36669824;                          // 32768
    int*   INDEG = (int*)(ws + 36702592);                  // 30000
    int*   OFF   = (int*)(ws + 36732592);                  // 30001
    int*   CURS  = (int*)(ws + 36762593);                  // 30000
    int*   SLOTS = (int*)(ws + 36792593);                  // E (<=100000)
    int*   SRCS  = (int*)(ws + 36892593);                  // E (<=100000)
    int*   FLAGS = (int*)(ws + 36992593);                  // 2
    int*   GCNT  = (int*)(ws + 36992595);                  // 256
    int*   GSTART= (int*)(ws + 36992851);                  // 257

    dim3 blk(256);

    detect_fmt<<<dim3(1), blk, 0, stream>>>(ei, batch, E, FLAGS);

    hipMemsetAsync(H1b, 0, (size_t)N * 320 * sizeof(ushort_t), stream);
    hipMemsetAsync(H2b, 0, (size_t)N * 640 * sizeof(ushort_t), stream);
    hipMemsetAsync(G, 0, (size_t)N_GRAPHS * 1248 * sizeof(float), stream);
    hipMemsetAsync(INDEG, 0, (size_t)N * sizeof(int), stream);
    hipMemsetAsync(GCNT, 0, N_GRAPHS * sizeof(int), stream);

    csr_hist<<<dim3((E + 255) / 256), blk, 0, stream>>>(ei, FLAGS, INDEG, E);
    csr_scan<<<dim3(1), dim3(1024), 0, stream>>>(INDEG, OFF, CURS);
    csr_fill<<<dim3((E + 255) / 256), blk, 0, stream>>>(ei, FLAGS, CURS, SLOTS, SRCS, E);

    ghist<<<dim3((N + 255) / 256), blk, 0, stream>>>(batch, FLAGS, GCNT);
    gscan<<<dim3(1), blk, 0, stream>>>(GCNT, GSTART);

    conv_pad_bf16<<<dim3(8192), blk, 0, stream>>>(x, ABF1, 78, 128, (long)N);

    struct Layer {
        const void* A; int lda; int K; int isbf;   // node_proj input
        const ushort_t* Abf; int Kp;               // gemm A (padded bf16)
        const float *W, *att, *b;
        int C, HC;
        ushort_t* outb; int ldo;                   // layers 1,2
        int pool;                                  // layer 3
    };
    Layer L[3] = {
        { x,   78,  78,  0, ABF1, 128, W1, att1, b1,  78,  312, H1b, 320, 0 },
        { H1b, 320, 312, 1, H1b,  320, W2, att2, b2, 156,  624, H2b, 640, 0 },
        { H2b, 640, 624, 1, H2b,  640, W3, att3, b3, 312, 1248, nullptr, 0, 1 },
    };

    for (int li = 0; li < 3; ++li) {
        const Layer& l = L[li];
        int nch = l.Kp >> 3;
        wt_bf16<<<dim3((l.HC * nch + 255) / 256), blk, 0, stream>>>(l.W, WT, l.K, l.Kp, l.HC);
        make_watt<<<dim3((l.K * HEADS + 255) / 256), blk, 0, stream>>>(l.W, l.att, WD, WSV, l.K, l.C, l.HC);
        node_proj_any<<<dim3((N + 3) / 4), blk, 0, stream>>>(l.A, l.lda, l.K, l.isbf, WD, WSV, ADST, ASRC, N);
        edge_alpha_csr<<<dim3((E + 255) / 256), blk, 0, stream>>>(SLOTS, ei, FLAGS, ADST, ASRC, ALPHAC, E);

        // one GEMM over all heads: XHb[N][HC] = A @ WT^T
        dim3 gg((l.HC + BN - 1) / BN, (N + BM - 1) / BM);
        gemm_bf16<<<gg, blk, 0, stream>>>(l.Abf, WT, XHb, N, l.HC, l.Kp);

        if (l.pool) {
            dim3 pg(N_GRAPHS * NSPLIT, (l.HC + 1023) / 1024);
            pool_gather<<<pg, blk, 0, stream>>>(OFF, SRCS, ALPHAC, XHb, l.b,
                                                GSTART, G, l.HC, l.C);
        } else {
            gat_gather_all<<<dim3((N + 3) / 4), blk, 0, stream>>>(
                OFF, SRCS, ALPHAC, XHb, l.b, l.outb, l.ldo, l.HC, l.C);
        }
    }

    // ---- MLP head (f32 exact) ----
    head_g1<<<dim3(N_GRAPHS / 2), blk, 0, stream>>>(G, Wg1, bg1, G1);
    head_g2<<<dim3(N_GRAPHS / 2), blk, 0, stream>>>(G1, Wg2, bg2, G2);
    head_g3<<<dim3(N_GRAPHS / 4), blk, 0, stream>>>(G2, Wo, bo, (float*)d_out);
}

// Round 8
// 653.283 us; speedup vs baseline: 6.3236x; 1.0742x over previous
//
#include <hip/hip_runtime.h>
#include <hip/hip_bf16.h>

#define N_NODES 30000
#define N_GRAPHS 256
#define HEADS 4

typedef __attribute__((ext_vector_type(8))) short short8;
typedef __attribute__((ext_vector_type(4))) float f32x4;
typedef __attribute__((ext_vector_type(4))) unsigned short ushort4_t;
typedef unsigned short ushort_t;

__device__ __forceinline__ ushort_t f2bf(float v) {
    __hip_bfloat16 h = __float2bfloat16(v);
    return *reinterpret_cast<ushort_t*>(&h);
}
__device__ __forceinline__ float bf2f(ushort_t u) {
    __hip_bfloat16 h;
    *reinterpret_cast<ushort_t*>(&h) = u;
    return __bfloat162float(h);
}
__device__ __forceinline__ int ld_idx(const void* p, long i, int is64) {
    return is64 ? (int)((const long long*)p)[i] : ((const int*)p)[i];
}
__device__ __forceinline__ int clampi(int v, int hi) {
    return v < 0 ? 0 : (v > hi ? hi : v);
}

// ---------------------------------------------------------------------------
__global__ void detect_fmt(const void* ei, const void* batch, int E, int* flags)
{
    __shared__ int okE, okB;
    if (threadIdx.x == 0) { okE = 1; okB = 1; }
    __syncthreads();
    const long long* e64 = (const long long*)ei;
    const long long* b64 = (const long long*)batch;
    const int nbslot = N_NODES / 2;
    for (int i = threadIdx.x; i < 2048; i += 256) {
        long ei_idx = (long)i * E / 2048;
        long long v = e64[ei_idx];
        if (v < 0 || v >= N_NODES) okE = 0;
        long b_idx = (long)i * nbslot / 2048;
        long long b = b64[b_idx];
        if (b < 0 || b >= N_GRAPHS) okB = 0;
    }
    __syncthreads();
    if (threadIdx.x == 0) { flags[0] = okE; flags[1] = okB; }
}

// ---------------------------------------------------------------------------
// CSR build (by dst). csr_fill also records the CSR-ordered src list.
// ---------------------------------------------------------------------------
__global__ void csr_hist(const void* ei, const int* __restrict__ flags,
                         int* __restrict__ indeg, int E)
{
    int i = blockIdx.x * blockDim.x + threadIdx.x;
    if (i >= E) return;
    int d = clampi(ld_idx(ei, (long)E + i, flags[0]), N_NODES - 1);
    atomicAdd(&indeg[d], 1);
}

__global__ __launch_bounds__(1024) void csr_scan(const int* __restrict__ indeg,
                                                 int* __restrict__ off,
                                                 int* __restrict__ cursor)
{
    __shared__ int ps[1024];
    const int t = threadIdx.x;
    const int CH = (N_NODES + 1023) / 1024;
    const int base = t * CH;
    int s = 0;
    for (int i = 0; i < CH; ++i) { int idx = base + i; if (idx < N_NODES) s += indeg[idx]; }
    ps[t] = s;
    __syncthreads();
    for (int d = 1; d < 1024; d <<= 1) {
        int v = (t >= d) ? ps[t - d] : 0;
        __syncthreads();
        ps[t] += v;
        __syncthreads();
    }
    int excl = (t == 0) ? 0 : ps[t - 1];
    for (int i = 0; i < CH; ++i) {
        int idx = base + i;
        if (idx < N_NODES) { off[idx] = excl; cursor[idx] = excl; excl += indeg[idx]; }
    }
    if (t == 1023) off[N_NODES] = ps[1023];
}

__global__ void csr_fill(const void* ei, const int* __restrict__ flags,
                         int* __restrict__ cursor, int* __restrict__ slots,
                         int* __restrict__ srcs, int E)
{
    int i = blockIdx.x * blockDim.x + threadIdx.x;
    if (i >= E) return;
    int is64 = flags[0];
    int d = clampi(ld_idx(ei, (long)E + i, is64), N_NODES - 1);
    int s = clampi(ld_idx(ei, i, is64), N_NODES - 1);
    int p = atomicAdd(&cursor[d], 1);
    slots[p] = i;
    srcs[p] = s;
}

// ---------------------------------------------------------------------------
// graph segment boundaries (batch is sorted): GSTART[g]..GSTART[g+1]
// ---------------------------------------------------------------------------
__global__ void ghist(const void* batch, const int* __restrict__ flags,
                      int* __restrict__ gcnt)
{
    int n = blockIdx.x * blockDim.x + threadIdx.x;
    if (n >= N_NODES) return;
    int g = clampi(ld_idx(batch, n, flags[1]), N_GRAPHS - 1);
    atomicAdd(&gcnt[g], 1);
}

__global__ __launch_bounds__(256) void gscan(const int* __restrict__ gcnt,
                                             int* __restrict__ gstart)
{
    __shared__ int ps[256];
    const int t = threadIdx.x;
    ps[t] = gcnt[t];
    __syncthreads();
    for (int d = 1; d < 256; d <<= 1) {
        int v = (t >= d) ? ps[t - d] : 0;
        __syncthreads();
        ps[t] += v;
        __syncthreads();
    }
    gstart[t + 1] = ps[t];
    if (t == 0) gstart[0] = 0;
}

// ---------------------------------------------------------------------------
// conversions
// ---------------------------------------------------------------------------
__global__ void conv_pad_bf16(const float* __restrict__ src, ushort_t* __restrict__ dst,
                              int K, int Kp, long M)
{
    long total = M * Kp;
    long stride = (long)gridDim.x * blockDim.x;
    for (long i = (long)blockIdx.x * blockDim.x + threadIdx.x; i < total; i += stride) {
        long n = i / Kp;
        int k = (int)(i - n * Kp);
        dst[i] = (k < K) ? f2bf(src[n * K + k]) : (ushort_t)0;
    }
}

// WT[n][kp] = bf16(W[k][n]), zero-padded k>=K
__global__ void wt_bf16(const float* __restrict__ W, ushort_t* __restrict__ WT,
                        int K, int Kp, int HC)
{
    int nch = Kp >> 3;
    int i = blockIdx.x * blockDim.x + threadIdx.x;
    if (i >= HC * nch) return;
    int n = i / nch, c8 = i - n * nch;
#pragma unroll
    for (int e = 0; e < 8; ++e) {
        int k = c8 * 8 + e;
        WT[(long)n * Kp + k] = (k < K) ? f2bf(W[(long)k * HC + n]) : (ushort_t)0;
    }
}

// ---------------------------------------------------------------------------
// Wd[k,h], Ws[k,h] = per-head att projections of W (f32, exact)
// ---------------------------------------------------------------------------
__global__ void make_watt(const float* __restrict__ W, const float* __restrict__ att,
                          float* __restrict__ Wd, float* __restrict__ Wsv,
                          int K, int C, int HC)
{
    int i = blockIdx.x * blockDim.x + threadIdx.x;
    if (i >= K * HEADS) return;
    int k = i >> 2, h = i & 3;
    const float* wrow = W + (long)k * HC + h * C;
    const float* ad = att + h * 2 * C;
    const float* as = ad + C;
    float s1 = 0.f, s2 = 0.f;
    for (int c = 0; c < C; ++c) { float w = wrow[c]; s1 += w * ad[c]; s2 += w * as[c]; }
    Wd[k * HEADS + h] = s1;
    Wsv[k * HEADS + h] = s2;
}

// ---------------------------------------------------------------------------
// adst/asrc per node. A may be f32 (lda,K) or bf16 padded (lda=Kp).
// ---------------------------------------------------------------------------
__global__ __launch_bounds__(256) void node_proj_any(const void* __restrict__ A,
                                                     int lda, int K, int isbf,
                                                     const float* __restrict__ Wd,
                                                     const float* __restrict__ Wsv,
                                                     float* __restrict__ adst,
                                                     float* __restrict__ asrc, int N)
{
    const int wv = threadIdx.x >> 6, lane = threadIdx.x & 63;
    const int n = blockIdx.x * 4 + wv;
    if (n >= N) return;
    float sd[HEADS] = {}, ss[HEADS] = {};
    for (int k = lane; k < K; k += 64) {
        float v = isbf ? bf2f(((const ushort_t*)A)[(long)n * lda + k])
                       : ((const float*)A)[(long)n * lda + k];
#pragma unroll
        for (int h = 0; h < HEADS; ++h) {
            sd[h] += v * Wd[k * HEADS + h];
            ss[h] += v * Wsv[k * HEADS + h];
        }
    }
#pragma unroll
    for (int off = 32; off; off >>= 1) {
#pragma unroll
        for (int h = 0; h < HEADS; ++h) {
            sd[h] += __shfl_down(sd[h], off);
            ss[h] += __shfl_down(ss[h], off);
        }
    }
    if (lane == 0) {
#pragma unroll
        for (int h = 0; h < HEADS; ++h) {
            adst[n * HEADS + h] = sd[h];
            asrc[n * HEADS + h] = ss[h];
        }
    }
}

// ---------------------------------------------------------------------------
// Per-CSR-slot softmax over heads -> ALPHAC[p][4] (CSR order, f32x4)
// ---------------------------------------------------------------------------
__global__ void edge_alpha_csr(const int* __restrict__ slots,
                               const void* __restrict__ ei, const int* __restrict__ flags,
                               const float* __restrict__ adst, const float* __restrict__ asrc,
                               float* __restrict__ alphac, int E)
{
    int p = blockIdx.x * blockDim.x + threadIdx.x;
    if (p >= E) return;
    int is64 = flags[0];
    int e = slots[p];
    int s = clampi(ld_idx(ei, e, is64), N_NODES - 1);
    int d = clampi(ld_idx(ei, (long)E + e, is64), N_NODES - 1);
    float a[HEADS], m = -1e30f;
#pragma unroll
    for (int h = 0; h < HEADS; ++h) {
        float v = adst[d * HEADS + h] + asrc[s * HEADS + h];
        v = (v > 0.f) ? v : 0.2f * v;
        a[h] = v;
        m = fmaxf(m, v);
    }
    float sum = 0.f;
#pragma unroll
    for (int h = 0; h < HEADS; ++h) { a[h] = __expf(a[h] - m); sum += a[h]; }
    float inv = 1.f / sum;
    f32x4 o;
#pragma unroll
    for (int h = 0; h < HEADS; ++h) o[h] = a[h] * inv;
    *(f32x4*)&alphac[(long)p * HEADS] = o;
}

// ---------------------------------------------------------------------------
// bf16 MFMA GEMM: C[M][FC] (bf16) = A[M][Kp] @ WT[n][Kp]^T  (all heads)
// BM=128 BN=128 BK=64, 4 waves (2x2), wave tile 64x64.
// XOR-swizzled LDS, reg-staged global loads.
// ---------------------------------------------------------------------------
#define BM 128
#define BN 128
#define BK 64
__global__ __launch_bounds__(256) void gemm_bf16(const ushort_t* __restrict__ A,
                                                 const ushort_t* __restrict__ WT,
                                                 ushort_t* __restrict__ C,
                                                 int M, int FC, int Kp)
{
    __shared__ ushort_t As[BM * BK];
    __shared__ ushort_t Bs[BN * BK];
    const int tid = threadIdx.x;
    const int lane = tid & 63;
    const int wid = tid >> 6;
    const int wm = wid >> 1, wn = wid & 1;
    const int row0 = blockIdx.y * BM;
    const int colb = blockIdx.x * BN;

    f32x4 acc[4][4];
#pragma unroll
    for (int i = 0; i < 4; ++i)
#pragma unroll
        for (int j = 0; j < 4; ++j) { f32x4 z = {0.f, 0.f, 0.f, 0.f}; acc[i][j] = z; }

    short8 ra[4], rb[4];

    auto loadG = [&](int k0) {
#pragma unroll
        for (int r = 0; r < 4; ++r) {
            int id = r * 256 + tid;
            int row = id >> 3, j = id & 7;
            long grow = min(row0 + row, M - 1);
            ra[r] = *(const short8*)&A[grow * Kp + k0 + j * 8];
        }
#pragma unroll
        for (int r = 0; r < 4; ++r) {
            int id = r * 256 + tid;
            int row = id >> 3, j = id & 7;
            long gcol = min(colb + row, FC - 1);
            rb[r] = *(const short8*)&WT[gcol * Kp + k0 + j * 8];
        }
    };

    loadG(0);
    for (int k0 = 0; k0 < Kp; k0 += BK) {
        __syncthreads();
#pragma unroll
        for (int r = 0; r < 4; ++r) {
            int id = r * 256 + tid;
            int row = id >> 3, j = id & 7;
            *(short8*)&As[row * BK + ((j ^ (row & 7)) << 3)] = ra[r];
        }
#pragma unroll
        for (int r = 0; r < 4; ++r) {
            int id = r * 256 + tid;
            int row = id >> 3, j = id & 7;
            *(short8*)&Bs[row * BK + ((j ^ (row & 7)) << 3)] = rb[r];
        }
        __syncthreads();
        if (k0 + BK < Kp) loadG(k0 + BK);
#pragma unroll
        for (int ks = 0; ks < 2; ++ks) {
            short8 af[4], bfr[4];
            const int jr = ks * 4 + (lane >> 4);
#pragma unroll
            for (int fm = 0; fm < 4; ++fm) {
                int row = wm * 64 + fm * 16 + (lane & 15);
                af[fm] = *(const short8*)&As[row * BK + ((jr ^ (row & 7)) << 3)];
            }
#pragma unroll
            for (int fn = 0; fn < 4; ++fn) {
                int row = wn * 64 + fn * 16 + (lane & 15);
                bfr[fn] = *(const short8*)&Bs[row * BK + ((jr ^ (row & 7)) << 3)];
            }
#pragma unroll
            for (int fm = 0; fm < 4; ++fm)
#pragma unroll
                for (int fn = 0; fn < 4; ++fn)
                    acc[fm][fn] = __builtin_amdgcn_mfma_f32_16x16x32_bf16(
                        af[fm], bfr[fn], acc[fm][fn], 0, 0, 0);
        }
    }

#pragma unroll
    for (int fm = 0; fm < 4; ++fm) {
        int rbase = row0 + wm * 64 + fm * 16 + (lane >> 4) * 4;
#pragma unroll
        for (int fn = 0; fn < 4; ++fn) {
            int col = colb + wn * 64 + fn * 16 + (lane & 15);
            if (col >= FC) continue;
#pragma unroll
            for (int r = 0; r < 4; ++r) {
                int gr = rbase + r;
                if (gr < M) C[(long)gr * FC + col] = f2bf(acc[fm][fn][r]);
            }
        }
    }
}

// ---------------------------------------------------------------------------
// CSR gather, all heads, layers 1/2 (plain coalesced bf16 stores):
// outb[n*ldo + c] = bf16(relu(bias[c] + sum_p alphac[p, c/FC] * xh[srcs[p], c]))
// ---------------------------------------------------------------------------
__global__ __launch_bounds__(256) void gat_gather_all(const int* __restrict__ off,
                                                      const int* __restrict__ srcs,
                                                      const float* __restrict__ alphac,
                                                      const ushort_t* __restrict__ xh,
                                                      const float* __restrict__ bias,
                                                      ushort_t* __restrict__ outb, int ldo,
                                                      int HC, int FC)
{
    const int wv = threadIdx.x >> 6, lane = threadIdx.x & 63;
    const int n = blockIdx.x * 4 + wv;
    if (n >= N_NODES) return;
    const int nch = (HC + 255) >> 8;          // <= 3 for layers 1/2
    float acc[3][4];
#pragma unroll
    for (int i = 0; i < 3; ++i)
#pragma unroll
        for (int j = 0; j < 4; ++j) acc[i][j] = 0.f;

    const int s0 = off[n], s1 = off[n + 1];
    for (int i = s0; i < s1; ++i) {
        f32x4 al = *(const f32x4*)&alphac[(long)i * HEADS];
        int s = srcs[i];
        const ushort_t* xs = xh + (long)s * HC;
        for (int ch = 0; ch < nch; ++ch) {
            int base = (ch << 8) + lane * 4;
            if (base >= HC) break;
            ushort4_t v = *(const ushort4_t*)&xs[base];
#pragma unroll
            for (int j = 0; j < 4; ++j) {
                int c = base + j;
                float w = (c < FC) ? al[0] : (c < 2 * FC) ? al[1]
                         : (c < 3 * FC) ? al[2] : al[3];
                acc[ch][j] += w * bf2f(v[j]);
            }
        }
    }

    for (int ch = 0; ch < nch; ++ch) {
        int base = (ch << 8) + lane * 4;
        if (base >= HC) break;
        ushort4_t o;
#pragma unroll
        for (int j = 0; j < 4; ++j)
            o[j] = f2bf(fmaxf(acc[ch][j] + bias[base + j], 0.f));
        *(ushort4_t*)&outb[(long)n * ldo + base] = o;
    }
}

// ---------------------------------------------------------------------------
// Layer 3 fused: gather + bias + relu + segment-max, node-split, vectorized.
// ---------------------------------------------------------------------------
#define NSPLIT 8
__global__ __launch_bounds__(256) void pool_gather(const int* __restrict__ off,
                                                   const int* __restrict__ srcs,
                                                   const float* __restrict__ alphac,
                                                   const ushort_t* __restrict__ xh,
                                                   const float* __restrict__ bias,
                                                   const int* __restrict__ gstart,
                                                   float* __restrict__ G,
                                                   int HC, int FC)
{
    const int g = blockIdx.x / NSPLIT;
    const int sp = blockIdx.x - g * NSPLIT;
    const int col = blockIdx.y * 1024 + threadIdx.x * 4;
    if (col >= HC) return;
    const int h = col / FC;                  // uniform over the 4-col group
    const ushort_t* xcol = xh + col;

    const int n0 = gstart[g], n1 = gstart[g + 1];
    const int len = n1 - n0;
    const int ch = (len + NSPLIT - 1) / NSPLIT;
    const int na = n0 + sp * ch;
    const int nb = min(na + ch, n1);
    if (na >= nb) return;

    f32x4 bc = *(const f32x4*)&bias[col];
    float gmax[4] = {0.f, 0.f, 0.f, 0.f};    // relu floor
    for (int n = na; n < nb; ++n) {
        f32x4 acc = {0.f, 0.f, 0.f, 0.f};
        const int s0 = off[n], s1 = off[n + 1];
        for (int i = s0; i < s1; ++i) {
            float w = alphac[(long)i * HEADS + h];
            int s = srcs[i];
            ushort4_t v = *(const ushort4_t*)&xcol[(long)s * HC];
#pragma unroll
            for (int j = 0; j < 4; ++j) acc[j] += w * bf2f(v[j]);
        }
#pragma unroll
        for (int j = 0; j < 4; ++j)
            gmax[j] = fmaxf(gmax[j], fmaxf(acc[j] + bc[j], 0.f));
    }
#pragma unroll
    for (int j = 0; j < 4; ++j)
        atomicMax((unsigned int*)&G[(long)g * 1248 + col + j], __float_as_uint(gmax[j]));
}

// ---------------------------------------------------------------------------
// MLP head, split-K (deterministic fixed-order reduce).
// g1: [256,1248]@[1248,1024]. grid (128 row-pairs, 8 k-chunks of 156).
// Partials HP1[ks][256][1024]; reduce sums ks in fixed order + bias + relu.
// ---------------------------------------------------------------------------
__global__ __launch_bounds__(256) void head_g1_sk(const float* __restrict__ Gp,
                                                  const float* __restrict__ W,
                                                  float* __restrict__ HP)
{
    __shared__ float a0[156], a1[156];
    const int m0 = blockIdx.x * 2;
    const int ks = blockIdx.y;
    const int k0 = ks * 156;
    if (threadIdx.x < 156) {
        a0[threadIdx.x] = Gp[(long)m0 * 1248 + k0 + threadIdx.x];
        a1[threadIdx.x] = Gp[(long)(m0 + 1) * 1248 + k0 + threadIdx.x];
    }
    __syncthreads();
    const int n4 = threadIdx.x * 4;
    float c0[4] = {}, c1[4] = {};
    for (int k = 0; k < 156; ++k) {
        f32x4 b = *(const f32x4*)&W[(long)(k0 + k) * 1024 + n4];
        float av0 = a0[k], av1 = a1[k];
#pragma unroll
        for (int j = 0; j < 4; ++j) { c0[j] += av0 * b[j]; c1[j] += av1 * b[j]; }
    }
    float* hp = HP + ((long)ks * 256 + m0) * 1024;
#pragma unroll
    for (int j = 0; j < 4; ++j) {
        hp[n4 + j]        = c0[j];
        hp[1024 + n4 + j] = c1[j];
    }
}

__global__ void head_g1_red(const float* __restrict__ HP,
                            const float* __restrict__ bias,
                            float* __restrict__ out)
{
    int i = blockIdx.x * 256 + threadIdx.x;      // 262144 total
    float s = 0.f;
#pragma unroll
    for (int ks = 0; ks < 8; ++ks) s += HP[(long)ks * 262144 + i];
    out[i] = fmaxf(s + bias[i & 1023], 0.f);
}

// g2: [256,1024]@[1024,128]. grid (128 row-pairs, 8 k-chunks of 128).
__global__ __launch_bounds__(256) void head_g2_sk(const float* __restrict__ G1,
                                                  const float* __restrict__ W,
                                                  float* __restrict__ HP)
{
    __shared__ float a[2][128];
    const int m0 = blockIdx.x * 2;
    const int ks = blockIdx.y;
    const int k0 = ks * 128;
    if (threadIdx.x < 128)
        a[0][threadIdx.x] = G1[(long)m0 * 1024 + k0 + threadIdx.x];
    else
        a[1][threadIdx.x - 128] = G1[(long)(m0 + 1) * 1024 + k0 + threadIdx.x - 128];
    __syncthreads();
    const int nn = threadIdx.x & 127;
    const int r = threadIdx.x >> 7;
    float acc = 0.f;
    for (int k = 0; k < 128; ++k)
        acc += a[r][k] * W[(long)(k0 + k) * 128 + nn];
    HP[((long)ks * 256 + m0 + r) * 128 + nn] = acc;
}

__global__ void head_g2_red(const float* __restrict__ HP,
                            const float* __restrict__ bias,
                            float* __restrict__ out)
{
    int i = blockIdx.x * 256 + threadIdx.x;      // 32768 total
    float s = 0.f;
#pragma unroll
    for (int ks = 0; ks < 8; ++ks) s += HP[(long)ks * 32768 + i];
    out[i] = s + bias[i & 127];
}

// g3: out[m] = dot(G2[m,:128], Wo) + bo. One wave per row.
__global__ __launch_bounds__(256) void head_g3(const float* __restrict__ G2,
                                               const float* __restrict__ Wo,
                                               const float* __restrict__ bo,
                                               float* __restrict__ out)
{
    const int wv = threadIdx.x >> 6, lane = threadIdx.x & 63;
    const int m = blockIdx.x * 4 + wv;
    if (m >= N_GRAPHS) return;
    float s = G2[(long)m * 128 + lane] * Wo[lane]
            + G2[(long)m * 128 + 64 + lane] * Wo[64 + lane];
#pragma unroll
    for (int o = 32; o; o >>= 1) s += __shfl_down(s, o);
    if (lane == 0) out[m] = s + bo[0];
}

// ---------------------------------------------------------------------------
extern "C" void kernel_launch(void* const* d_in, const int* in_sizes, int n_in,
                              void* d_out, int out_size, void* d_ws, size_t ws_size,
                              hipStream_t stream)
{
    const float* x    = (const float*)d_in[0];
    const void*  ei   = d_in[1];
    const void*  batch= d_in[2];
    const float* W1   = (const float*)d_in[3];
    const float* att1 = (const float*)d_in[4];
    const float* b1   = (const float*)d_in[5];
    const float* W2   = (const float*)d_in[6];
    const float* att2 = (const float*)d_in[7];
    const float* b2   = (const float*)d_in[8];
    const float* W3   = (const float*)d_in[9];
    const float* att3 = (const float*)d_in[10];
    const float* b3   = (const float*)d_in[11];
    const float* Wg1  = (const float*)d_in[12];
    const float* bg1  = (const float*)d_in[13];
    const float* Wg2  = (const float*)d_in[14];
    const float* bg2  = (const float*)d_in[15];
    const float* Wo   = (const float*)d_in[16];
    const float* bo   = (const float*)d_in[17];

    const int N = N_NODES;
    const int E = in_sizes[1] / 2;

    // ---- workspace layout (float units), ~149 MB ----
    float* ws = (float*)d_ws;
    ushort_t* H1b  = (ushort_t*)ws;                        // 30000*320 sh
    ushort_t* H2b  = (ushort_t*)(ws + 4800000);            // 30000*640 sh
    ushort_t* ABF1 = (ushort_t*)(ws + 14400000);           // 30000*128 sh
    ushort_t* XHb  = (ushort_t*)(ws + 16320000);           // 30000*1248 sh
    ushort_t* WT   = (ushort_t*)(ws + 35040000);           // 1248*640 sh
    float* ADST  = ws + 35440000;                          // 120000
    float* ASRC  = ws + 35560000;                          // 120000
    float* ALPHAC= ws + 35680000;                          // 400000 (CSR order)
    float* WD    = ws + 36080000;                          // 4096
    float* WSV   = ws + 36084096;                          // 4096
    float* G     = ws + 36088192;                          // 319488
    float* G1    = ws + 36407680;                          // 262144
    float* G2    = ws + 36669824;                          // 32768
    int*   INDEG = (int*)(ws + 36702592);                  // 30000
    int*   OFF   = (int*)(ws + 36732592);                  // 30001
    int*   CURS  = (int*)(ws + 36762593);                  // 30000
    int*   SLOTS = (int*)(ws + 36792593);                  // E (<=100000)
    int*   SRCS  = (int*)(ws + 36892593);                  // E (<=100000)
    int*   FLAGS = (int*)(ws + 36992593);                  // 2
    int*   GCNT  = (int*)(ws + 36992595);                  // 256
    int*   GSTART= (int*)(ws + 36992851);                  // 257
    // head split-K partials alias the retired H1b region (free after layer 2)
    float* HP1   = ws;                                     // 2,097,152 fl
    float* HP2   = ws + 2100000;                           // 262,144 fl

    dim3 blk(256);

    detect_fmt<<<dim3(1), blk, 0, stream>>>(ei, batch, E, FLAGS);

    hipMemsetAsync(H1b, 0, (size_t)N * 320 * sizeof(ushort_t), stream);
    hipMemsetAsync(H2b, 0, (size_t)N * 640 * sizeof(ushort_t), stream);
    hipMemsetAsync(G, 0, (size_t)N_GRAPHS * 1248 * sizeof(float), stream);
    hipMemsetAsync(INDEG, 0, (size_t)N * sizeof(int), stream);
    hipMemsetAsync(GCNT, 0, N_GRAPHS * sizeof(int), stream);

    csr_hist<<<dim3((E + 255) / 256), blk, 0, stream>>>(ei, FLAGS, INDEG, E);
    csr_scan<<<dim3(1), dim3(1024), 0, stream>>>(INDEG, OFF, CURS);
    csr_fill<<<dim3((E + 255) / 256), blk, 0, stream>>>(ei, FLAGS, CURS, SLOTS, SRCS, E);

    ghist<<<dim3((N + 255) / 256), blk, 0, stream>>>(batch, FLAGS, GCNT);
    gscan<<<dim3(1), blk, 0, stream>>>(GCNT, GSTART);

    conv_pad_bf16<<<dim3(8192), blk, 0, stream>>>(x, ABF1, 78, 128, (long)N);

    struct Layer {
        const void* A; int lda; int K; int isbf;   // node_proj input
        const ushort_t* Abf; int Kp;               // gemm A (padded bf16)
        const float *W, *att, *b;
        int C, HC;
        ushort_t* outb; int ldo;                   // layers 1,2
        int pool;                                  // layer 3
    };
    Layer L[3] = {
        { x,   78,  78,  0, ABF1, 128, W1, att1, b1,  78,  312, H1b, 320, 0 },
        { H1b, 320, 312, 1, H1b,  320, W2, att2, b2, 156,  624, H2b, 640, 0 },
        { H2b, 640, 624, 1, H2b,  640, W3, att3, b3, 312, 1248, nullptr, 0, 1 },
    };

    for (int li = 0; li < 3; ++li) {
        const Layer& l = L[li];
        int nch = l.Kp >> 3;
        wt_bf16<<<dim3((l.HC * nch + 255) / 256), blk, 0, stream>>>(l.W, WT, l.K, l.Kp, l.HC);
        make_watt<<<dim3((l.K * HEADS + 255) / 256), blk, 0, stream>>>(l.W, l.att, WD, WSV, l.K, l.C, l.HC);
        node_proj_any<<<dim3((N + 3) / 4), blk, 0, stream>>>(l.A, l.lda, l.K, l.isbf, WD, WSV, ADST, ASRC, N);
        edge_alpha_csr<<<dim3((E + 255) / 256), blk, 0, stream>>>(SLOTS, ei, FLAGS, ADST, ASRC, ALPHAC, E);

        // one GEMM over all heads: XHb[N][HC] = A @ WT^T
        dim3 gg((l.HC + BN - 1) / BN, (N + BM - 1) / BM);
        gemm_bf16<<<gg, blk, 0, stream>>>(l.Abf, WT, XHb, N, l.HC, l.Kp);

        if (l.pool) {
            dim3 pg(N_GRAPHS * NSPLIT, (l.HC + 1023) / 1024);
            pool_gather<<<pg, blk, 0, stream>>>(OFF, SRCS, ALPHAC, XHb, l.b,
                                                GSTART, G, l.HC, l.C);
        } else {
            gat_gather_all<<<dim3((N + 3) / 4), blk, 0, stream>>>(
                OFF, SRCS, ALPHAC, XHb, l.b, l.outb, l.ldo, l.HC, l.C);
        }
    }

    // ---- MLP head (f32 exact, split-K with fixed-order reduce) ----
    head_g1_sk <<<dim3(N_GRAPHS / 2, 8), blk, 0, stream>>>(G, Wg1, HP1);
    head_g1_red<<<dim3(1024), blk, 0, stream>>>(HP1, bg1, G1);
    head_g2_sk <<<dim3(N_GRAPHS / 2, 8), blk, 0, stream>>>(G1, Wg2, HP2);
    head_g2_red<<<dim3(128), blk, 0, stream>>>(HP2, bg2, G2);
    head_g3    <<<dim3(N_GRAPHS / 4), blk, 0, stream>>>(G2, Wo, bo, (float*)d_out);
}

// Round 9
// 640.869 us; speedup vs baseline: 6.4460x; 1.0194x over previous
//
#include <hip/hip_runtime.h>
#include <hip/hip_bf16.h>

#define N_NODES 30000
#define N_GRAPHS 256
#define HEADS 4

typedef __attribute__((ext_vector_type(8))) short short8;
typedef __attribute__((ext_vector_type(4))) float f32x4;
typedef __attribute__((ext_vector_type(4))) unsigned short ushort4_t;
typedef unsigned short ushort_t;

__device__ __forceinline__ ushort_t f2bf(float v) {
    __hip_bfloat16 h = __float2bfloat16(v);
    return *reinterpret_cast<ushort_t*>(&h);
}
__device__ __forceinline__ float bf2f(ushort_t u) {
    __hip_bfloat16 h;
    *reinterpret_cast<ushort_t*>(&h) = u;
    return __bfloat162float(h);
}
__device__ __forceinline__ int ld_idx(const void* p, long i, int is64) {
    return is64 ? (int)((const long long*)p)[i] : ((const int*)p)[i];
}
__device__ __forceinline__ int clampi(int v, int hi) {
    return v < 0 ? 0 : (v > hi ? hi : v);
}

// ---------------------------------------------------------------------------
__global__ void detect_fmt(const void* ei, const void* batch, int E, int* flags)
{
    __shared__ int okE, okB;
    if (threadIdx.x == 0) { okE = 1; okB = 1; }
    __syncthreads();
    const long long* e64 = (const long long*)ei;
    const long long* b64 = (const long long*)batch;
    const int nbslot = N_NODES / 2;
    for (int i = threadIdx.x; i < 2048; i += 256) {
        long ei_idx = (long)i * E / 2048;
        long long v = e64[ei_idx];
        if (v < 0 || v >= N_NODES) okE = 0;
        long b_idx = (long)i * nbslot / 2048;
        long long b = b64[b_idx];
        if (b < 0 || b >= N_GRAPHS) okB = 0;
    }
    __syncthreads();
    if (threadIdx.x == 0) { flags[0] = okE; flags[1] = okB; }
}

// ---------------------------------------------------------------------------
// CSR build (by dst). csr_fill also records the CSR-ordered src list.
// ---------------------------------------------------------------------------
__global__ void csr_hist(const void* ei, const int* __restrict__ flags,
                         int* __restrict__ indeg, int E)
{
    int i = blockIdx.x * blockDim.x + threadIdx.x;
    if (i >= E) return;
    int d = clampi(ld_idx(ei, (long)E + i, flags[0]), N_NODES - 1);
    atomicAdd(&indeg[d], 1);
}

__global__ __launch_bounds__(1024) void csr_scan(const int* __restrict__ indeg,
                                                 int* __restrict__ off,
                                                 int* __restrict__ cursor)
{
    __shared__ int ps[1024];
    const int t = threadIdx.x;
    const int CH = (N_NODES + 1023) / 1024;
    const int base = t * CH;
    int s = 0;
    for (int i = 0; i < CH; ++i) { int idx = base + i; if (idx < N_NODES) s += indeg[idx]; }
    ps[t] = s;
    __syncthreads();
    for (int d = 1; d < 1024; d <<= 1) {
        int v = (t >= d) ? ps[t - d] : 0;
        __syncthreads();
        ps[t] += v;
        __syncthreads();
    }
    int excl = (t == 0) ? 0 : ps[t - 1];
    for (int i = 0; i < CH; ++i) {
        int idx = base + i;
        if (idx < N_NODES) { off[idx] = excl; cursor[idx] = excl; excl += indeg[idx]; }
    }
    if (t == 1023) off[N_NODES] = ps[1023];
}

__global__ void csr_fill(const void* ei, const int* __restrict__ flags,
                         int* __restrict__ cursor, int* __restrict__ slots,
                         int* __restrict__ srcs, int E)
{
    int i = blockIdx.x * blockDim.x + threadIdx.x;
    if (i >= E) return;
    int is64 = flags[0];
    int d = clampi(ld_idx(ei, (long)E + i, is64), N_NODES - 1);
    int s = clampi(ld_idx(ei, i, is64), N_NODES - 1);
    int p = atomicAdd(&cursor[d], 1);
    slots[p] = i;
    srcs[p] = s;
}

// ---------------------------------------------------------------------------
// graph segment boundaries (batch is sorted): GSTART[g]..GSTART[g+1]
// ---------------------------------------------------------------------------
__global__ void ghist(const void* batch, const int* __restrict__ flags,
                      int* __restrict__ gcnt)
{
    int n = blockIdx.x * blockDim.x + threadIdx.x;
    if (n >= N_NODES) return;
    int g = clampi(ld_idx(batch, n, flags[1]), N_GRAPHS - 1);
    atomicAdd(&gcnt[g], 1);
}

__global__ __launch_bounds__(256) void gscan(const int* __restrict__ gcnt,
                                             int* __restrict__ gstart)
{
    __shared__ int ps[256];
    const int t = threadIdx.x;
    ps[t] = gcnt[t];
    __syncthreads();
    for (int d = 1; d < 256; d <<= 1) {
        int v = (t >= d) ? ps[t - d] : 0;
        __syncthreads();
        ps[t] += v;
        __syncthreads();
    }
    gstart[t + 1] = ps[t];
    if (t == 0) gstart[0] = 0;
}

// ---------------------------------------------------------------------------
// conversions
// ---------------------------------------------------------------------------
__global__ void conv_pad_bf16(const float* __restrict__ src, ushort_t* __restrict__ dst,
                              int K, int Kp, long M)
{
    long total = M * Kp;
    long stride = (long)gridDim.x * blockDim.x;
    for (long i = (long)blockIdx.x * blockDim.x + threadIdx.x; i < total; i += stride) {
        long n = i / Kp;
        int k = (int)(i - n * Kp);
        dst[i] = (k < K) ? f2bf(src[n * K + k]) : (ushort_t)0;
    }
}

// WT[n][kp] = bf16(W[k][n]), zero-padded k>=K
__global__ void wt_bf16(const float* __restrict__ W, ushort_t* __restrict__ WT,
                        int K, int Kp, int HC)
{
    int nch = Kp >> 3;
    int i = blockIdx.x * blockDim.x + threadIdx.x;
    if (i >= HC * nch) return;
    int n = i / nch, c8 = i - n * nch;
#pragma unroll
    for (int e = 0; e < 8; ++e) {
        int k = c8 * 8 + e;
        WT[(long)n * Kp + k] = (k < K) ? f2bf(W[(long)k * HC + n]) : (ushort_t)0;
    }
}

// ---------------------------------------------------------------------------
// Wd[k,h], Ws[k,h] = per-head att projections of W (f32, exact)
// ---------------------------------------------------------------------------
__global__ void make_watt(const float* __restrict__ W, const float* __restrict__ att,
                          float* __restrict__ Wd, float* __restrict__ Wsv,
                          int K, int C, int HC)
{
    int i = blockIdx.x * blockDim.x + threadIdx.x;
    if (i >= K * HEADS) return;
    int k = i >> 2, h = i & 3;
    const float* wrow = W + (long)k * HC + h * C;
    const float* ad = att + h * 2 * C;
    const float* as = ad + C;
    float s1 = 0.f, s2 = 0.f;
    for (int c = 0; c < C; ++c) { float w = wrow[c]; s1 += w * ad[c]; s2 += w * as[c]; }
    Wd[k * HEADS + h] = s1;
    Wsv[k * HEADS + h] = s2;
}

// ---------------------------------------------------------------------------
// adst/asrc per node. A may be f32 (lda,K) or bf16 padded (lda=Kp).
// ---------------------------------------------------------------------------
__global__ __launch_bounds__(256) void node_proj_any(const void* __restrict__ A,
                                                     int lda, int K, int isbf,
                                                     const float* __restrict__ Wd,
                                                     const float* __restrict__ Wsv,
                                                     float* __restrict__ adst,
                                                     float* __restrict__ asrc, int N)
{
    const int wv = threadIdx.x >> 6, lane = threadIdx.x & 63;
    const int n = blockIdx.x * 4 + wv;
    if (n >= N) return;
    float sd[HEADS] = {}, ss[HEADS] = {};
    for (int k = lane; k < K; k += 64) {
        float v = isbf ? bf2f(((const ushort_t*)A)[(long)n * lda + k])
                       : ((const float*)A)[(long)n * lda + k];
#pragma unroll
        for (int h = 0; h < HEADS; ++h) {
            sd[h] += v * Wd[k * HEADS + h];
            ss[h] += v * Wsv[k * HEADS + h];
        }
    }
#pragma unroll
    for (int off = 32; off; off >>= 1) {
#pragma unroll
        for (int h = 0; h < HEADS; ++h) {
            sd[h] += __shfl_down(sd[h], off);
            ss[h] += __shfl_down(ss[h], off);
        }
    }
    if (lane == 0) {
#pragma unroll
        for (int h = 0; h < HEADS; ++h) {
            adst[n * HEADS + h] = sd[h];
            asrc[n * HEADS + h] = ss[h];
        }
    }
}

// ---------------------------------------------------------------------------
// Per-CSR-slot softmax over heads -> ALPHAC[p][4] (CSR order, f32x4)
// ---------------------------------------------------------------------------
__global__ void edge_alpha_csr(const int* __restrict__ slots,
                               const void* __restrict__ ei, const int* __restrict__ flags,
                               const float* __restrict__ adst, const float* __restrict__ asrc,
                               float* __restrict__ alphac, int E)
{
    int p = blockIdx.x * blockDim.x + threadIdx.x;
    if (p >= E) return;
    int is64 = flags[0];
    int e = slots[p];
    int s = clampi(ld_idx(ei, e, is64), N_NODES - 1);
    int d = clampi(ld_idx(ei, (long)E + e, is64), N_NODES - 1);
    float a[HEADS], m = -1e30f;
#pragma unroll
    for (int h = 0; h < HEADS; ++h) {
        float v = adst[d * HEADS + h] + asrc[s * HEADS + h];
        v = (v > 0.f) ? v : 0.2f * v;
        a[h] = v;
        m = fmaxf(m, v);
    }
    float sum = 0.f;
#pragma unroll
    for (int h = 0; h < HEADS; ++h) { a[h] = __expf(a[h] - m); sum += a[h]; }
    float inv = 1.f / sum;
    f32x4 o;
#pragma unroll
    for (int h = 0; h < HEADS; ++h) o[h] = a[h] * inv;
    *(f32x4*)&alphac[(long)p * HEADS] = o;
}

// ---------------------------------------------------------------------------
// bf16 MFMA GEMM: C[M][FC] (bf16) = A[M][Kp] @ WT[n][Kp]^T  (all heads)
// BM=128 BN=128 BK=64, 4 waves (2x2), wave tile 64x64.
// XOR-swizzled LDS, reg-staged global loads.
// 1D grid + bijective XCD-chunked swizzle (T1): each XCD owns contiguous
// row-tiles and ALL their col-blocks -> A-tile fetched once per XCD L2.
// ---------------------------------------------------------------------------
#define BM 128
#define BN 128
#define BK 64
#define NXCD 8
__global__ __launch_bounds__(256) void gemm_bf16(const ushort_t* __restrict__ A,
                                                 const ushort_t* __restrict__ WT,
                                                 ushort_t* __restrict__ C,
                                                 int M, int FC, int Kp, int ncols)
{
    // --- bijective chunked XCD swizzle (m204 formula) ---
    const int nwg = gridDim.x;
    const int bid = blockIdx.x;
    const int q = nwg >> 3, r = nwg & (NXCD - 1);
    const int k = bid & (NXCD - 1), i = bid >> 3;   // hw: xcd = bid % 8
    const int wu = (k < r) ? k * (q + 1) + i
                           : r * (q + 1) + (k - r) * q + i;
    const int rowb = wu / ncols;
    const int colb_i = wu - rowb * ncols;
    const int row0 = rowb * BM;
    const int colb = colb_i * BN;

    __shared__ ushort_t As[BM * BK];
    __shared__ ushort_t Bs[BN * BK];
    const int tid = threadIdx.x;
    const int lane = tid & 63;
    const int wid = tid >> 6;
    const int wm = wid >> 1, wn = wid & 1;

    f32x4 acc[4][4];
#pragma unroll
    for (int a = 0; a < 4; ++a)
#pragma unroll
        for (int b = 0; b < 4; ++b) { f32x4 z = {0.f, 0.f, 0.f, 0.f}; acc[a][b] = z; }

    short8 ra[4], rb[4];

    auto loadG = [&](int k0) {
#pragma unroll
        for (int u = 0; u < 4; ++u) {
            int id = u * 256 + tid;
            int row = id >> 3, j = id & 7;
            long grow = min(row0 + row, M - 1);
            ra[u] = *(const short8*)&A[grow * Kp + k0 + j * 8];
        }
#pragma unroll
        for (int u = 0; u < 4; ++u) {
            int id = u * 256 + tid;
            int row = id >> 3, j = id & 7;
            long gcol = min(colb + row, FC - 1);
            rb[u] = *(const short8*)&WT[gcol * Kp + k0 + j * 8];
        }
    };

    loadG(0);
    for (int k0 = 0; k0 < Kp; k0 += BK) {
        __syncthreads();
#pragma unroll
        for (int u = 0; u < 4; ++u) {
            int id = u * 256 + tid;
            int row = id >> 3, j = id & 7;
            *(short8*)&As[row * BK + ((j ^ (row & 7)) << 3)] = ra[u];
        }
#pragma unroll
        for (int u = 0; u < 4; ++u) {
            int id = u * 256 + tid;
            int row = id >> 3, j = id & 7;
            *(short8*)&Bs[row * BK + ((j ^ (row & 7)) << 3)] = rb[u];
        }
        __syncthreads();
        if (k0 + BK < Kp) loadG(k0 + BK);
#pragma unroll
        for (int ks = 0; ks < 2; ++ks) {
            short8 af[4], bfr[4];
            const int jr = ks * 4 + (lane >> 4);
#pragma unroll
            for (int fm = 0; fm < 4; ++fm) {
                int row = wm * 64 + fm * 16 + (lane & 15);
                af[fm] = *(const short8*)&As[row * BK + ((jr ^ (row & 7)) << 3)];
            }
#pragma unroll
            for (int fn = 0; fn < 4; ++fn) {
                int row = wn * 64 + fn * 16 + (lane & 15);
                bfr[fn] = *(const short8*)&Bs[row * BK + ((jr ^ (row & 7)) << 3)];
            }
#pragma unroll
            for (int fm = 0; fm < 4; ++fm)
#pragma unroll
                for (int fn = 0; fn < 4; ++fn)
                    acc[fm][fn] = __builtin_amdgcn_mfma_f32_16x16x32_bf16(
                        af[fm], bfr[fn], acc[fm][fn], 0, 0, 0);
        }
    }

#pragma unroll
    for (int fm = 0; fm < 4; ++fm) {
        int rbase = row0 + wm * 64 + fm * 16 + (lane >> 4) * 4;
#pragma unroll
        for (int fn = 0; fn < 4; ++fn) {
            int col = colb + wn * 64 + fn * 16 + (lane & 15);
            if (col >= FC) continue;
#pragma unroll
            for (int u = 0; u < 4; ++u) {
                int gr = rbase + u;
                if (gr < M) C[(long)gr * FC + col] = f2bf(acc[fm][fn][u]);
            }
        }
    }
}

// ---------------------------------------------------------------------------
// CSR gather, all heads, layers 1/2 (plain coalesced bf16 stores):
// outb[n*ldo + c] = bf16(relu(bias[c] + sum_p alphac[p, c/FC] * xh[srcs[p], c]))
// ---------------------------------------------------------------------------
__global__ __launch_bounds__(256) void gat_gather_all(const int* __restrict__ off,
                                                      const int* __restrict__ srcs,
                                                      const float* __restrict__ alphac,
                                                      const ushort_t* __restrict__ xh,
                                                      const float* __restrict__ bias,
                                                      ushort_t* __restrict__ outb, int ldo,
                                                      int HC, int FC)
{
    const int wv = threadIdx.x >> 6, lane = threadIdx.x & 63;
    const int n = blockIdx.x * 4 + wv;
    if (n >= N_NODES) return;
    const int nch = (HC + 255) >> 8;          // <= 3 for layers 1/2
    float acc[3][4];
#pragma unroll
    for (int a = 0; a < 3; ++a)
#pragma unroll
        for (int j = 0; j < 4; ++j) acc[a][j] = 0.f;

    const int s0 = off[n], s1 = off[n + 1];
    for (int i = s0; i < s1; ++i) {
        f32x4 al = *(const f32x4*)&alphac[(long)i * HEADS];
        int s = srcs[i];
        const ushort_t* xs = xh + (long)s * HC;
        for (int ch = 0; ch < nch; ++ch) {
            int base = (ch << 8) + lane * 4;
            if (base >= HC) break;
            ushort4_t v = *(const ushort4_t*)&xs[base];
#pragma unroll
            for (int j = 0; j < 4; ++j) {
                int c = base + j;
                float w = (c < FC) ? al[0] : (c < 2 * FC) ? al[1]
                         : (c < 3 * FC) ? al[2] : al[3];
                acc[ch][j] += w * bf2f(v[j]);
            }
        }
    }

    for (int ch = 0; ch < nch; ++ch) {
        int base = (ch << 8) + lane * 4;
        if (base >= HC) break;
        ushort4_t o;
#pragma unroll
        for (int j = 0; j < 4; ++j)
            o[j] = f2bf(fmaxf(acc[ch][j] + bias[base + j], 0.f));
        *(ushort4_t*)&outb[(long)n * ldo + base] = o;
    }
}

// ---------------------------------------------------------------------------
// Layer 3 fused: gather + bias + relu + segment-max, node-split, vectorized.
// ---------------------------------------------------------------------------
#define NSPLIT 8
__global__ __launch_bounds__(256) void pool_gather(const int* __restrict__ off,
                                                   const int* __restrict__ srcs,
                                                   const float* __restrict__ alphac,
                                                   const ushort_t* __restrict__ xh,
                                                   const float* __restrict__ bias,
                                                   const int* __restrict__ gstart,
                                                   float* __restrict__ G,
                                                   int HC, int FC)
{
    const int g = blockIdx.x / NSPLIT;
    const int sp = blockIdx.x - g * NSPLIT;
    const int col = blockIdx.y * 1024 + threadIdx.x * 4;
    if (col >= HC) return;
    const int h = col / FC;                  // uniform over the 4-col group
    const ushort_t* xcol = xh + col;

    const int n0 = gstart[g], n1 = gstart[g + 1];
    const int len = n1 - n0;
    const int ch = (len + NSPLIT - 1) / NSPLIT;
    const int na = n0 + sp * ch;
    const int nb = min(na + ch, n1);
    if (na >= nb) return;

    f32x4 bc = *(const f32x4*)&bias[col];
    float gmax[4] = {0.f, 0.f, 0.f, 0.f};    // relu floor
    for (int n = na; n < nb; ++n) {
        f32x4 acc = {0.f, 0.f, 0.f, 0.f};
        const int s0 = off[n], s1 = off[n + 1];
        for (int i = s0; i < s1; ++i) {
            float w = alphac[(long)i * HEADS + h];
            int s = srcs[i];
            ushort4_t v = *(const ushort4_t*)&xcol[(long)s * HC];
#pragma unroll
            for (int j = 0; j < 4; ++j) acc[j] += w * bf2f(v[j]);
        }
#pragma unroll
        for (int j = 0; j < 4; ++j)
            gmax[j] = fmaxf(gmax[j], fmaxf(acc[j] + bc[j], 0.f));
    }
#pragma unroll
    for (int j = 0; j < 4; ++j)
        atomicMax((unsigned int*)&G[(long)g * 1248 + col + j], __float_as_uint(gmax[j]));
}

// ---------------------------------------------------------------------------
// MLP head, split-K (deterministic fixed-order reduce).
// ---------------------------------------------------------------------------
__global__ __launch_bounds__(256) void head_g1_sk(const float* __restrict__ Gp,
                                                  const float* __restrict__ W,
                                                  float* __restrict__ HP)
{
    __shared__ float a0[156], a1[156];
    const int m0 = blockIdx.x * 2;
    const int ks = blockIdx.y;
    const int k0 = ks * 156;
    if (threadIdx.x < 156) {
        a0[threadIdx.x] = Gp[(long)m0 * 1248 + k0 + threadIdx.x];
        a1[threadIdx.x] = Gp[(long)(m0 + 1) * 1248 + k0 + threadIdx.x];
    }
    __syncthreads();
    const int n4 = threadIdx.x * 4;
    float c0[4] = {}, c1[4] = {};
    for (int k = 0; k < 156; ++k) {
        f32x4 b = *(const f32x4*)&W[(long)(k0 + k) * 1024 + n4];
        float av0 = a0[k], av1 = a1[k];
#pragma unroll
        for (int j = 0; j < 4; ++j) { c0[j] += av0 * b[j]; c1[j] += av1 * b[j]; }
    }
    float* hp = HP + ((long)ks * 256 + m0) * 1024;
#pragma unroll
    for (int j = 0; j < 4; ++j) {
        hp[n4 + j]        = c0[j];
        hp[1024 + n4 + j] = c1[j];
    }
}

__global__ void head_g1_red(const float* __restrict__ HP,
                            const float* __restrict__ bias,
                            float* __restrict__ out)
{
    int i = blockIdx.x * 256 + threadIdx.x;      // 262144 total
    float s = 0.f;
#pragma unroll
    for (int ks = 0; ks < 8; ++ks) s += HP[(long)ks * 262144 + i];
    out[i] = fmaxf(s + bias[i & 1023], 0.f);
}

// g2: [256,1024]@[1024,128]. grid (128 row-pairs, 8 k-chunks of 128).
__global__ __launch_bounds__(256) void head_g2_sk(const float* __restrict__ G1,
                                                  const float* __restrict__ W,
                                                  float* __restrict__ HP)
{
    __shared__ float a[2][128];
    const int m0 = blockIdx.x * 2;
    const int ks = blockIdx.y;
    const int k0 = ks * 128;
    if (threadIdx.x < 128)
        a[0][threadIdx.x] = G1[(long)m0 * 1024 + k0 + threadIdx.x];
    else
        a[1][threadIdx.x - 128] = G1[(long)(m0 + 1) * 1024 + k0 + threadIdx.x - 128];
    __syncthreads();
    const int nn = threadIdx.x & 127;
    const int r = threadIdx.x >> 7;
    float acc = 0.f;
    for (int k = 0; k < 128; ++k)
        acc += a[r][k] * W[(long)(k0 + k) * 128 + nn];
    HP[((long)ks * 256 + m0 + r) * 128 + nn] = acc;
}

__global__ void head_g2_red(const float* __restrict__ HP,
                            const float* __restrict__ bias,
                            float* __restrict__ out)
{
    int i = blockIdx.x * 256 + threadIdx.x;      // 32768 total
    float s = 0.f;
#pragma unroll
    for (int ks = 0; ks < 8; ++ks) s += HP[(long)ks * 32768 + i];
    out[i] = s + bias[i & 127];
}

// g3: out[m] = dot(G2[m,:128], Wo) + bo. One wave per row.
__global__ __launch_bounds__(256) void head_g3(const float* __restrict__ G2,
                                               const float* __restrict__ Wo,
                                               const float* __restrict__ bo,
                                               float* __restrict__ out)
{
    const int wv = threadIdx.x >> 6, lane = threadIdx.x & 63;
    const int m = blockIdx.x * 4 + wv;
    if (m >= N_GRAPHS) return;
    float s = G2[(long)m * 128 + lane] * Wo[lane]
            + G2[(long)m * 128 + 64 + lane] * Wo[64 + lane];
#pragma unroll
    for (int o = 32; o; o >>= 1) s += __shfl_down(s, o);
    if (lane == 0) out[m] = s + bo[0];
}

// ---------------------------------------------------------------------------
extern "C" void kernel_launch(void* const* d_in, const int* in_sizes, int n_in,
                              void* d_out, int out_size, void* d_ws, size_t ws_size,
                              hipStream_t stream)
{
    const float* x    = (const float*)d_in[0];
    const void*  ei   = d_in[1];
    const void*  batch= d_in[2];
    const float* W1   = (const float*)d_in[3];
    const float* att1 = (const float*)d_in[4];
    const float* b1   = (const float*)d_in[5];
    const float* W2   = (const float*)d_in[6];
    const float* att2 = (const float*)d_in[7];
    const float* b2   = (const float*)d_in[8];
    const float* W3   = (const float*)d_in[9];
    const float* att3 = (const float*)d_in[10];
    const float* b3   = (const float*)d_in[11];
    const float* Wg1  = (const float*)d_in[12];
    const float* bg1  = (const float*)d_in[13];
    const float* Wg2  = (const float*)d_in[14];
    const float* bg2  = (const float*)d_in[15];
    const float* Wo   = (const float*)d_in[16];
    const float* bo   = (const float*)d_in[17];

    const int N = N_NODES;
    const int E = in_sizes[1] / 2;

    // ---- workspace layout (float units), ~149 MB ----
    float* ws = (float*)d_ws;
    ushort_t* H1b  = (ushort_t*)ws;                        // 30000*320 sh
    ushort_t* H2b  = (ushort_t*)(ws + 4800000);            // 30000*640 sh
    ushort_t* ABF1 = (ushort_t*)(ws + 14400000);           // 30000*128 sh
    ushort_t* XHb  = (ushort_t*)(ws + 16320000);           // 30000*1248 sh
    ushort_t* WT   = (ushort_t*)(ws + 35040000);           // 1248*640 sh
    float* ADST  = ws + 35440000;                          // 120000
    float* ASRC  = ws + 35560000;                          // 120000
    float* ALPHAC= ws + 35680000;                          // 400000 (CSR order)
    float* WD    = ws + 36080000;                          // 4096
    float* WSV   = ws + 36084096;                          // 4096
    float* G     = ws + 36088192;                          // 319488
    float* G1    = ws + 36407680;                          // 262144
    float* G2    = ws + 36669824;                          // 32768
    int*   INDEG = (int*)(ws + 36702592);                  // 30000
    int*   OFF   = (int*)(ws + 36732592);                  // 30001
    int*   CURS  = (int*)(ws + 36762593);                  // 30000
    int*   SLOTS = (int*)(ws + 36792593);                  // E (<=100000)
    int*   SRCS  = (int*)(ws + 36892593);                  // E (<=100000)
    int*   FLAGS = (int*)(ws + 36992593);                  // 2
    int*   GCNT  = (int*)(ws + 36992595);                  // 256
    int*   GSTART= (int*)(ws + 36992851);                  // 257
    // head split-K partials alias the retired H1b region (free after layer 2)
    float* HP1   = ws;                                     // 2,097,152 fl
    float* HP2   = ws + 2100000;                           // 262,144 fl

    dim3 blk(256);

    detect_fmt<<<dim3(1), blk, 0, stream>>>(ei, batch, E, FLAGS);

    hipMemsetAsync(H1b, 0, (size_t)N * 320 * sizeof(ushort_t), stream);
    hipMemsetAsync(H2b, 0, (size_t)N * 640 * sizeof(ushort_t), stream);
    hipMemsetAsync(G, 0, (size_t)N_GRAPHS * 1248 * sizeof(float), stream);
    hipMemsetAsync(INDEG, 0, (size_t)N * sizeof(int), stream);
    hipMemsetAsync(GCNT, 0, N_GRAPHS * sizeof(int), stream);

    csr_hist<<<dim3((E + 255) / 256), blk, 0, stream>>>(ei, FLAGS, INDEG, E);
    csr_scan<<<dim3(1), dim3(1024), 0, stream>>>(INDEG, OFF, CURS);
    csr_fill<<<dim3((E + 255) / 256), blk, 0, stream>>>(ei, FLAGS, CURS, SLOTS, SRCS, E);

    ghist<<<dim3((N + 255) / 256), blk, 0, stream>>>(batch, FLAGS, GCNT);
    gscan<<<dim3(1), blk, 0, stream>>>(GCNT, GSTART);

    conv_pad_bf16<<<dim3(8192), blk, 0, stream>>>(x, ABF1, 78, 128, (long)N);

    struct Layer {
        const void* A; int lda; int K; int isbf;   // node_proj input
        const ushort_t* Abf; int Kp;               // gemm A (padded bf16)
        const float *W, *att, *b;
        int C, HC;
        ushort_t* outb; int ldo;                   // layers 1,2
        int pool;                                  // layer 3
    };
    Layer L[3] = {
        { x,   78,  78,  0, ABF1, 128, W1, att1, b1,  78,  312, H1b, 320, 0 },
        { H1b, 320, 312, 1, H1b,  320, W2, att2, b2, 156,  624, H2b, 640, 0 },
        { H2b, 640, 624, 1, H2b,  640, W3, att3, b3, 312, 1248, nullptr, 0, 1 },
    };

    for (int li = 0; li < 3; ++li) {
        const Layer& l = L[li];
        int nch = l.Kp >> 3;
        wt_bf16<<<dim3((l.HC * nch + 255) / 256), blk, 0, stream>>>(l.W, WT, l.K, l.Kp, l.HC);
        make_watt<<<dim3((l.K * HEADS + 255) / 256), blk, 0, stream>>>(l.W, l.att, WD, WSV, l.K, l.C, l.HC);
        node_proj_any<<<dim3((N + 3) / 4), blk, 0, stream>>>(l.A, l.lda, l.K, l.isbf, WD, WSV, ADST, ASRC, N);
        edge_alpha_csr<<<dim3((E + 255) / 256), blk, 0, stream>>>(SLOTS, ei, FLAGS, ADST, ASRC, ALPHAC, E);

        // one GEMM over all heads: XHb[N][HC] = A @ WT^T  (1D grid + XCD swizzle)
        int ncols = (l.HC + BN - 1) / BN;
        int nrows = (N + BM - 1) / BM;
        gemm_bf16<<<dim3(ncols * nrows), blk, 0, stream>>>(l.Abf, WT, XHb, N, l.HC, l.Kp, ncols);

        if (l.pool) {
            dim3 pg(N_GRAPHS * NSPLIT, (l.HC + 1023) / 1024);
            pool_gather<<<pg, blk, 0, stream>>>(OFF, SRCS, ALPHAC, XHb, l.b,
                                                GSTART, G, l.HC, l.C);
        } else {
            gat_gather_all<<<dim3((N + 3) / 4), blk, 0, stream>>>(
                OFF, SRCS, ALPHAC, XHb, l.b, l.outb, l.ldo, l.HC, l.C);
        }
    }

    // ---- MLP head (f32 exact, split-K with fixed-order reduce) ----
    head_g1_sk <<<dim3(N_GRAPHS / 2, 8), blk, 0, stream>>>(G, Wg1, HP1);
    head_g1_red<<<dim3(1024), blk, 0, stream>>>(HP1, bg1, G1);
    head_g2_sk <<<dim3(N_GRAPHS / 2, 8), blk, 0, stream>>>(G1, Wg2, HP2);
    head_g2_red<<<dim3(128), blk, 0, stream>>>(HP2, bg2, G2);
    head_g3    <<<dim3(N_GRAPHS / 4), blk, 0, stream>>>(G2, Wo, bo, (float*)d_out);
}

// Round 10
// 623.260 us; speedup vs baseline: 6.6282x; 1.0283x over previous
//
#include <hip/hip_runtime.h>
#include <hip/hip_bf16.h>

#define N_NODES 30000
#define N_GRAPHS 256
#define HEADS 4

typedef __attribute__((ext_vector_type(8))) short short8;
typedef __attribute__((ext_vector_type(4))) float f32x4;
typedef __attribute__((ext_vector_type(4))) unsigned short ushort4_t;
typedef unsigned short ushort_t;

__device__ __forceinline__ ushort_t f2bf(float v) {
    __hip_bfloat16 h = __float2bfloat16(v);
    return *reinterpret_cast<ushort_t*>(&h);
}
__device__ __forceinline__ float bf2f(ushort_t u) {
    __hip_bfloat16 h;
    *reinterpret_cast<ushort_t*>(&h) = u;
    return __bfloat162float(h);
}
__device__ __forceinline__ int ld_idx(const void* p, long i, int is64) {
    return is64 ? (int)((const long long*)p)[i] : ((const int*)p)[i];
}
__device__ __forceinline__ int clampi(int v, int hi) {
    return v < 0 ? 0 : (v > hi ? hi : v);
}

// ---------------------------------------------------------------------------
__global__ void detect_fmt(const void* ei, const void* batch, int E, int* flags)
{
    __shared__ int okE, okB;
    if (threadIdx.x == 0) { okE = 1; okB = 1; }
    __syncthreads();
    const long long* e64 = (const long long*)ei;
    const long long* b64 = (const long long*)batch;
    const int nbslot = N_NODES / 2;
    for (int i = threadIdx.x; i < 2048; i += 256) {
        long ei_idx = (long)i * E / 2048;
        long long v = e64[ei_idx];
        if (v < 0 || v >= N_NODES) okE = 0;
        long b_idx = (long)i * nbslot / 2048;
        long long b = b64[b_idx];
        if (b < 0 || b >= N_GRAPHS) okB = 0;
    }
    __syncthreads();
    if (threadIdx.x == 0) { flags[0] = okE; flags[1] = okB; }
}

// ---------------------------------------------------------------------------
// CSR build (by dst). csr_fill also records the CSR-ordered src list.
// ---------------------------------------------------------------------------
__global__ void csr_hist(const void* ei, const int* __restrict__ flags,
                         int* __restrict__ indeg, int E)
{
    int i = blockIdx.x * blockDim.x + threadIdx.x;
    if (i >= E) return;
    int d = clampi(ld_idx(ei, (long)E + i, flags[0]), N_NODES - 1);
    atomicAdd(&indeg[d], 1);
}

__global__ __launch_bounds__(1024) void csr_scan(const int* __restrict__ indeg,
                                                 int* __restrict__ off,
                                                 int* __restrict__ cursor)
{
    __shared__ int ps[1024];
    const int t = threadIdx.x;
    const int CH = (N_NODES + 1023) / 1024;
    const int base = t * CH;
    int s = 0;
    for (int i = 0; i < CH; ++i) { int idx = base + i; if (idx < N_NODES) s += indeg[idx]; }
    ps[t] = s;
    __syncthreads();
    for (int d = 1; d < 1024; d <<= 1) {
        int v = (t >= d) ? ps[t - d] : 0;
        __syncthreads();
        ps[t] += v;
        __syncthreads();
    }
    int excl = (t == 0) ? 0 : ps[t - 1];
    for (int i = 0; i < CH; ++i) {
        int idx = base + i;
        if (idx < N_NODES) { off[idx] = excl; cursor[idx] = excl; excl += indeg[idx]; }
    }
    if (t == 1023) off[N_NODES] = ps[1023];
}

__global__ void csr_fill(const void* ei, const int* __restrict__ flags,
                         int* __restrict__ cursor, int* __restrict__ slots,
                         int* __restrict__ srcs, int E)
{
    int i = blockIdx.x * blockDim.x + threadIdx.x;
    if (i >= E) return;
    int is64 = flags[0];
    int d = clampi(ld_idx(ei, (long)E + i, is64), N_NODES - 1);
    int s = clampi(ld_idx(ei, i, is64), N_NODES - 1);
    int p = atomicAdd(&cursor[d], 1);
    slots[p] = i;
    srcs[p] = s;
}

// ---------------------------------------------------------------------------
// graph segment boundaries (batch is sorted): GSTART[g]..GSTART[g+1]
// ---------------------------------------------------------------------------
__global__ void ghist(const void* batch, const int* __restrict__ flags,
                      int* __restrict__ gcnt)
{
    int n = blockIdx.x * blockDim.x + threadIdx.x;
    if (n >= N_NODES) return;
    int g = clampi(ld_idx(batch, n, flags[1]), N_GRAPHS - 1);
    atomicAdd(&gcnt[g], 1);
}

__global__ __launch_bounds__(256) void gscan(const int* __restrict__ gcnt,
                                             int* __restrict__ gstart)
{
    __shared__ int ps[256];
    const int t = threadIdx.x;
    ps[t] = gcnt[t];
    __syncthreads();
    for (int d = 1; d < 256; d <<= 1) {
        int v = (t >= d) ? ps[t - d] : 0;
        __syncthreads();
        ps[t] += v;
        __syncthreads();
    }
    gstart[t + 1] = ps[t];
    if (t == 0) gstart[0] = 0;
}

// ---------------------------------------------------------------------------
// conversions
// ---------------------------------------------------------------------------
__global__ void conv_pad_bf16(const float* __restrict__ src, ushort_t* __restrict__ dst,
                              int K, int Kp, long M)
{
    long total = M * Kp;
    long stride = (long)gridDim.x * blockDim.x;
    for (long i = (long)blockIdx.x * blockDim.x + threadIdx.x; i < total; i += stride) {
        long n = i / Kp;
        int k = (int)(i - n * Kp);
        dst[i] = (k < K) ? f2bf(src[n * K + k]) : (ushort_t)0;
    }
}

// WT[n][kp] = bf16(W[k][n]), zero-padded k>=K
__global__ void wt_bf16(const float* __restrict__ W, ushort_t* __restrict__ WT,
                        int K, int Kp, int HC)
{
    int nch = Kp >> 3;
    int i = blockIdx.x * blockDim.x + threadIdx.x;
    if (i >= HC * nch) return;
    int n = i / nch, c8 = i - n * nch;
#pragma unroll
    for (int e = 0; e < 8; ++e) {
        int k = c8 * 8 + e;
        WT[(long)n * Kp + k] = (k < K) ? f2bf(W[(long)k * HC + n]) : (ushort_t)0;
    }
}

// ---------------------------------------------------------------------------
// Wd[k,h], Ws[k,h] = per-head att projections of W (f32, exact)
// ---------------------------------------------------------------------------
__global__ void make_watt(const float* __restrict__ W, const float* __restrict__ att,
                          float* __restrict__ Wd, float* __restrict__ Wsv,
                          int K, int C, int HC)
{
    int i = blockIdx.x * blockDim.x + threadIdx.x;
    if (i >= K * HEADS) return;
    int k = i >> 2, h = i & 3;
    const float* wrow = W + (long)k * HC + h * C;
    const float* ad = att + h * 2 * C;
    const float* as = ad + C;
    float s1 = 0.f, s2 = 0.f;
    for (int c = 0; c < C; ++c) { float w = wrow[c]; s1 += w * ad[c]; s2 += w * as[c]; }
    Wd[k * HEADS + h] = s1;
    Wsv[k * HEADS + h] = s2;
}

// ---------------------------------------------------------------------------
// adst/asrc per node. A may be f32 (lda,K) or bf16 padded (lda=Kp).
// ---------------------------------------------------------------------------
__global__ __launch_bounds__(256) void node_proj_any(const void* __restrict__ A,
                                                     int lda, int K, int isbf,
                                                     const float* __restrict__ Wd,
                                                     const float* __restrict__ Wsv,
                                                     float* __restrict__ adst,
                                                     float* __restrict__ asrc, int N)
{
    const int wv = threadIdx.x >> 6, lane = threadIdx.x & 63;
    const int n = blockIdx.x * 4 + wv;
    if (n >= N) return;
    float sd[HEADS] = {}, ss[HEADS] = {};
    for (int k = lane; k < K; k += 64) {
        float v = isbf ? bf2f(((const ushort_t*)A)[(long)n * lda + k])
                       : ((const float*)A)[(long)n * lda + k];
#pragma unroll
        for (int h = 0; h < HEADS; ++h) {
            sd[h] += v * Wd[k * HEADS + h];
            ss[h] += v * Wsv[k * HEADS + h];
        }
    }
#pragma unroll
    for (int off = 32; off; off >>= 1) {
#pragma unroll
        for (int h = 0; h < HEADS; ++h) {
            sd[h] += __shfl_down(sd[h], off);
            ss[h] += __shfl_down(ss[h], off);
        }
    }
    if (lane == 0) {
#pragma unroll
        for (int h = 0; h < HEADS; ++h) {
            adst[n * HEADS + h] = sd[h];
            asrc[n * HEADS + h] = ss[h];
        }
    }
}

// ---------------------------------------------------------------------------
// Per-CSR-slot softmax over heads -> ALPHAC[p][4] (CSR order, f32x4)
// ---------------------------------------------------------------------------
__global__ void edge_alpha_csr(const int* __restrict__ slots,
                               const void* __restrict__ ei, const int* __restrict__ flags,
                               const float* __restrict__ adst, const float* __restrict__ asrc,
                               float* __restrict__ alphac, int E)
{
    int p = blockIdx.x * blockDim.x + threadIdx.x;
    if (p >= E) return;
    int is64 = flags[0];
    int e = slots[p];
    int s = clampi(ld_idx(ei, e, is64), N_NODES - 1);
    int d = clampi(ld_idx(ei, (long)E + e, is64), N_NODES - 1);
    float a[HEADS], m = -1e30f;
#pragma unroll
    for (int h = 0; h < HEADS; ++h) {
        float v = adst[d * HEADS + h] + asrc[s * HEADS + h];
        v = (v > 0.f) ? v : 0.2f * v;
        a[h] = v;
        m = fmaxf(m, v);
    }
    float sum = 0.f;
#pragma unroll
    for (int h = 0; h < HEADS; ++h) { a[h] = __expf(a[h] - m); sum += a[h]; }
    float inv = 1.f / sum;
    f32x4 o;
#pragma unroll
    for (int h = 0; h < HEADS; ++h) o[h] = a[h] * inv;
    *(f32x4*)&alphac[(long)p * HEADS] = o;
}

// ---------------------------------------------------------------------------
// bf16 MFMA GEMM: C[M][FC] (bf16) = A[M][Kp] @ WT[n][Kp]^T  (all heads)
// BM=128 BN=128 BK=64, 4 waves (2x2), wave tile 64x64.
// XOR-swizzled LDS, reg-staged global loads.
// 1D grid + bijective XCD-chunked swizzle (T1).
// ---------------------------------------------------------------------------
#define BM 128
#define BN 128
#define BK 64
#define NXCD 8
__global__ __launch_bounds__(256) void gemm_bf16(const ushort_t* __restrict__ A,
                                                 const ushort_t* __restrict__ WT,
                                                 ushort_t* __restrict__ C,
                                                 int M, int FC, int Kp, int ncols)
{
    // --- bijective chunked XCD swizzle (m204 formula) ---
    const int nwg = gridDim.x;
    const int bid = blockIdx.x;
    const int q = nwg >> 3, r = nwg & (NXCD - 1);
    const int k = bid & (NXCD - 1), i = bid >> 3;   // hw: xcd = bid % 8
    const int wu = (k < r) ? k * (q + 1) + i
                           : r * (q + 1) + (k - r) * q + i;
    const int rowb = wu / ncols;
    const int colb_i = wu - rowb * ncols;
    const int row0 = rowb * BM;
    const int colb = colb_i * BN;

    __shared__ ushort_t As[BM * BK];
    __shared__ ushort_t Bs[BN * BK];
    const int tid = threadIdx.x;
    const int lane = tid & 63;
    const int wid = tid >> 6;
    const int wm = wid >> 1, wn = wid & 1;

    f32x4 acc[4][4];
#pragma unroll
    for (int a = 0; a < 4; ++a)
#pragma unroll
        for (int b = 0; b < 4; ++b) { f32x4 z = {0.f, 0.f, 0.f, 0.f}; acc[a][b] = z; }

    short8 ra[4], rb[4];

    auto loadG = [&](int k0) {
#pragma unroll
        for (int u = 0; u < 4; ++u) {
            int id = u * 256 + tid;
            int row = id >> 3, j = id & 7;
            long grow = min(row0 + row, M - 1);
            ra[u] = *(const short8*)&A[grow * Kp + k0 + j * 8];
        }
#pragma unroll
        for (int u = 0; u < 4; ++u) {
            int id = u * 256 + tid;
            int row = id >> 3, j = id & 7;
            long gcol = min(colb + row, FC - 1);
            rb[u] = *(const short8*)&WT[gcol * Kp + k0 + j * 8];
        }
    };

    loadG(0);
    for (int k0 = 0; k0 < Kp; k0 += BK) {
        __syncthreads();
#pragma unroll
        for (int u = 0; u < 4; ++u) {
            int id = u * 256 + tid;
            int row = id >> 3, j = id & 7;
            *(short8*)&As[row * BK + ((j ^ (row & 7)) << 3)] = ra[u];
        }
#pragma unroll
        for (int u = 0; u < 4; ++u) {
            int id = u * 256 + tid;
            int row = id >> 3, j = id & 7;
            *(short8*)&Bs[row * BK + ((j ^ (row & 7)) << 3)] = rb[u];
        }
        __syncthreads();
        if (k0 + BK < Kp) loadG(k0 + BK);
#pragma unroll
        for (int ks = 0; ks < 2; ++ks) {
            short8 af[4], bfr[4];
            const int jr = ks * 4 + (lane >> 4);
#pragma unroll
            for (int fm = 0; fm < 4; ++fm) {
                int row = wm * 64 + fm * 16 + (lane & 15);
                af[fm] = *(const short8*)&As[row * BK + ((jr ^ (row & 7)) << 3)];
            }
#pragma unroll
            for (int fn = 0; fn < 4; ++fn) {
                int row = wn * 64 + fn * 16 + (lane & 15);
                bfr[fn] = *(const short8*)&Bs[row * BK + ((jr ^ (row & 7)) << 3)];
            }
#pragma unroll
            for (int fm = 0; fm < 4; ++fm)
#pragma unroll
                for (int fn = 0; fn < 4; ++fn)
                    acc[fm][fn] = __builtin_amdgcn_mfma_f32_16x16x32_bf16(
                        af[fm], bfr[fn], acc[fm][fn], 0, 0, 0);
        }
    }

#pragma unroll
    for (int fm = 0; fm < 4; ++fm) {
        int rbase = row0 + wm * 64 + fm * 16 + (lane >> 4) * 4;
#pragma unroll
        for (int fn = 0; fn < 4; ++fn) {
            int col = colb + wn * 64 + fn * 16 + (lane & 15);
            if (col >= FC) continue;
#pragma unroll
            for (int u = 0; u < 4; ++u) {
                int gr = rbase + u;
                if (gr < M) C[(long)gr * FC + col] = f2bf(acc[fm][fn][u]);
            }
        }
    }
}

// ---------------------------------------------------------------------------
// CSR gather, all heads, layers 1/2 (plain coalesced bf16 stores).
// Edge loop unrolled x2 with independent accumulators -> 2 row-reads in
// flight per wave (double memory-level parallelism).
// ---------------------------------------------------------------------------
__global__ __launch_bounds__(256) void gat_gather_all(const int* __restrict__ off,
                                                      const int* __restrict__ srcs,
                                                      const float* __restrict__ alphac,
                                                      const ushort_t* __restrict__ xh,
                                                      const float* __restrict__ bias,
                                                      ushort_t* __restrict__ outb, int ldo,
                                                      int HC, int FC)
{
    const int wv = threadIdx.x >> 6, lane = threadIdx.x & 63;
    const int n = blockIdx.x * 4 + wv;
    if (n >= N_NODES) return;
    const int nch = (HC + 255) >> 8;          // <= 3 for layers 1/2
    float acc0[3][4], acc1[3][4];
#pragma unroll
    for (int a = 0; a < 3; ++a)
#pragma unroll
        for (int j = 0; j < 4; ++j) { acc0[a][j] = 0.f; acc1[a][j] = 0.f; }

    const int s0 = off[n], s1 = off[n + 1];
    int i = s0;
    for (; i + 1 < s1; i += 2) {
        f32x4 alA = *(const f32x4*)&alphac[(long)i * HEADS];
        f32x4 alB = *(const f32x4*)&alphac[(long)(i + 1) * HEADS];
        int sA = srcs[i], sB = srcs[i + 1];
        const ushort_t* xA = xh + (long)sA * HC;
        const ushort_t* xB = xh + (long)sB * HC;
        for (int ch = 0; ch < nch; ++ch) {
            int base = (ch << 8) + lane * 4;
            if (base >= HC) break;
            ushort4_t vA = *(const ushort4_t*)&xA[base];
            ushort4_t vB = *(const ushort4_t*)&xB[base];
#pragma unroll
            for (int j = 0; j < 4; ++j) {
                int c = base + j;
                float wA = (c < FC) ? alA[0] : (c < 2 * FC) ? alA[1]
                          : (c < 3 * FC) ? alA[2] : alA[3];
                float wB = (c < FC) ? alB[0] : (c < 2 * FC) ? alB[1]
                          : (c < 3 * FC) ? alB[2] : alB[3];
                acc0[ch][j] += wA * bf2f(vA[j]);
                acc1[ch][j] += wB * bf2f(vB[j]);
            }
        }
    }
    if (i < s1) {
        f32x4 al = *(const f32x4*)&alphac[(long)i * HEADS];
        int s = srcs[i];
        const ushort_t* xs = xh + (long)s * HC;
        for (int ch = 0; ch < nch; ++ch) {
            int base = (ch << 8) + lane * 4;
            if (base >= HC) break;
            ushort4_t v = *(const ushort4_t*)&xs[base];
#pragma unroll
            for (int j = 0; j < 4; ++j) {
                int c = base + j;
                float w = (c < FC) ? al[0] : (c < 2 * FC) ? al[1]
                         : (c < 3 * FC) ? al[2] : al[3];
                acc0[ch][j] += w * bf2f(v[j]);
            }
        }
    }

    for (int ch = 0; ch < nch; ++ch) {
        int base = (ch << 8) + lane * 4;
        if (base >= HC) break;
        ushort4_t o;
#pragma unroll
        for (int j = 0; j < 4; ++j)
            o[j] = f2bf(fmaxf(acc0[ch][j] + acc1[ch][j] + bias[base + j], 0.f));
        *(ushort4_t*)&outb[(long)n * ldo + base] = o;
    }
}

// ---------------------------------------------------------------------------
// Layer 3 fused: gather + bias + relu + segment-max, node-split, vectorized.
// Edge loop unrolled x2 (2 independent row-reads in flight).
// ---------------------------------------------------------------------------
#define NSPLIT 8
__global__ __launch_bounds__(256) void pool_gather(const int* __restrict__ off,
                                                   const int* __restrict__ srcs,
                                                   const float* __restrict__ alphac,
                                                   const ushort_t* __restrict__ xh,
                                                   const float* __restrict__ bias,
                                                   const int* __restrict__ gstart,
                                                   float* __restrict__ G,
                                                   int HC, int FC)
{
    const int g = blockIdx.x / NSPLIT;
    const int sp = blockIdx.x - g * NSPLIT;
    const int col = blockIdx.y * 1024 + threadIdx.x * 4;
    if (col >= HC) return;
    const int h = col / FC;                  // uniform over the 4-col group
    const ushort_t* xcol = xh + col;

    const int n0 = gstart[g], n1 = gstart[g + 1];
    const int len = n1 - n0;
    const int ch = (len + NSPLIT - 1) / NSPLIT;
    const int na = n0 + sp * ch;
    const int nb = min(na + ch, n1);
    if (na >= nb) return;

    f32x4 bc = *(const f32x4*)&bias[col];
    float gmax[4] = {0.f, 0.f, 0.f, 0.f};    // relu floor
    for (int n = na; n < nb; ++n) {
        f32x4 a0 = {0.f, 0.f, 0.f, 0.f};
        f32x4 a1 = {0.f, 0.f, 0.f, 0.f};
        const int s0 = off[n], s1 = off[n + 1];
        int i = s0;
        for (; i + 1 < s1; i += 2) {
            float w0 = alphac[(long)i * HEADS + h];
            float w1 = alphac[(long)(i + 1) * HEADS + h];
            int sA = srcs[i], sB = srcs[i + 1];
            ushort4_t v0 = *(const ushort4_t*)&xcol[(long)sA * HC];
            ushort4_t v1 = *(const ushort4_t*)&xcol[(long)sB * HC];
#pragma unroll
            for (int j = 0; j < 4; ++j) {
                a0[j] += w0 * bf2f(v0[j]);
                a1[j] += w1 * bf2f(v1[j]);
            }
        }
        if (i < s1) {
            float w = alphac[(long)i * HEADS + h];
            int s = srcs[i];
            ushort4_t v = *(const ushort4_t*)&xcol[(long)s * HC];
#pragma unroll
            for (int j = 0; j < 4; ++j) a0[j] += w * bf2f(v[j]);
        }
#pragma unroll
        for (int j = 0; j < 4; ++j)
            gmax[j] = fmaxf(gmax[j], fmaxf(a0[j] + a1[j] + bc[j], 0.f));
    }
#pragma unroll
    for (int j = 0; j < 4; ++j)
        atomicMax((unsigned int*)&G[(long)g * 1248 + col + j], __float_as_uint(gmax[j]));
}

// ---------------------------------------------------------------------------
// MLP head, split-K (deterministic fixed-order reduce).
// ---------------------------------------------------------------------------
__global__ __launch_bounds__(256) void head_g1_sk(const float* __restrict__ Gp,
                                                  const float* __restrict__ W,
                                                  float* __restrict__ HP)
{
    __shared__ float a0[156], a1[156];
    const int m0 = blockIdx.x * 2;
    const int ks = blockIdx.y;
    const int k0 = ks * 156;
    if (threadIdx.x < 156) {
        a0[threadIdx.x] = Gp[(long)m0 * 1248 + k0 + threadIdx.x];
        a1[threadIdx.x] = Gp[(long)(m0 + 1) * 1248 + k0 + threadIdx.x];
    }
    __syncthreads();
    const int n4 = threadIdx.x * 4;
    float c0[4] = {}, c1[4] = {};
    for (int k = 0; k < 156; ++k) {
        f32x4 b = *(const f32x4*)&W[(long)(k0 + k) * 1024 + n4];
        float av0 = a0[k], av1 = a1[k];
#pragma unroll
        for (int j = 0; j < 4; ++j) { c0[j] += av0 * b[j]; c1[j] += av1 * b[j]; }
    }
    float* hp = HP + ((long)ks * 256 + m0) * 1024;
#pragma unroll
    for (int j = 0; j < 4; ++j) {
        hp[n4 + j]        = c0[j];
        hp[1024 + n4 + j] = c1[j];
    }
}

__global__ void head_g1_red(const float* __restrict__ HP,
                            const float* __restrict__ bias,
                            float* __restrict__ out)
{
    int i = blockIdx.x * 256 + threadIdx.x;      // 262144 total
    float s = 0.f;
#pragma unroll
    for (int ks = 0; ks < 8; ++ks) s += HP[(long)ks * 262144 + i];
    out[i] = fmaxf(s + bias[i & 1023], 0.f);
}

// g2: [256,1024]@[1024,128]. grid (128 row-pairs, 8 k-chunks of 128).
__global__ __launch_bounds__(256) void head_g2_sk(const float* __restrict__ G1,
                                                  const float* __restrict__ W,
                                                  float* __restrict__ HP)
{
    __shared__ float a[2][128];
    const int m0 = blockIdx.x * 2;
    const int ks = blockIdx.y;
    const int k0 = ks * 128;
    if (threadIdx.x < 128)
        a[0][threadIdx.x] = G1[(long)m0 * 1024 + k0 + threadIdx.x];
    else
        a[1][threadIdx.x - 128] = G1[(long)(m0 + 1) * 1024 + k0 + threadIdx.x - 128];
    __syncthreads();
    const int nn = threadIdx.x & 127;
    const int r = threadIdx.x >> 7;
    float acc = 0.f;
    for (int k = 0; k < 128; ++k)
        acc += a[r][k] * W[(long)(k0 + k) * 128 + nn];
    HP[((long)ks * 256 + m0 + r) * 128 + nn] = acc;
}

__global__ void head_g2_red(const float* __restrict__ HP,
                            const float* __restrict__ bias,
                            float* __restrict__ out)
{
    int i = blockIdx.x * 256 + threadIdx.x;      // 32768 total
    float s = 0.f;
#pragma unroll
    for (int ks = 0; ks < 8; ++ks) s += HP[(long)ks * 32768 + i];
    out[i] = s + bias[i & 127];
}

// g3: out[m] = dot(G2[m,:128], Wo) + bo. One wave per row.
__global__ __launch_bounds__(256) void head_g3(const float* __restrict__ G2,
                                               const float* __restrict__ Wo,
                                               const float* __restrict__ bo,
                                               float* __restrict__ out)
{
    const int wv = threadIdx.x >> 6, lane = threadIdx.x & 63;
    const int m = blockIdx.x * 4 + wv;
    if (m >= N_GRAPHS) return;
    float s = G2[(long)m * 128 + lane] * Wo[lane]
            + G2[(long)m * 128 + 64 + lane] * Wo[64 + lane];
#pragma unroll
    for (int o = 32; o; o >>= 1) s += __shfl_down(s, o);
    if (lane == 0) out[m] = s + bo[0];
}

// ---------------------------------------------------------------------------
extern "C" void kernel_launch(void* const* d_in, const int* in_sizes, int n_in,
                              void* d_out, int out_size, void* d_ws, size_t ws_size,
                              hipStream_t stream)
{
    const float* x    = (const float*)d_in[0];
    const void*  ei   = d_in[1];
    const void*  batch= d_in[2];
    const float* W1   = (const float*)d_in[3];
    const float* att1 = (const float*)d_in[4];
    const float* b1   = (const float*)d_in[5];
    const float* W2   = (const float*)d_in[6];
    const float* att2 = (const float*)d_in[7];
    const float* b2   = (const float*)d_in[8];
    const float* W3   = (const float*)d_in[9];
    const float* att3 = (const float*)d_in[10];
    const float* b3   = (const float*)d_in[11];
    const float* Wg1  = (const float*)d_in[12];
    const float* bg1  = (const float*)d_in[13];
    const float* Wg2  = (const float*)d_in[14];
    const float* bg2  = (const float*)d_in[15];
    const float* Wo   = (const float*)d_in[16];
    const float* bo   = (const float*)d_in[17];

    const int N = N_NODES;
    const int E = in_sizes[1] / 2;

    // ---- workspace layout (float units), ~149 MB ----
    float* ws = (float*)d_ws;
    ushort_t* H1b  = (ushort_t*)ws;                        // 30000*320 sh
    ushort_t* H2b  = (ushort_t*)(ws + 4800000);            // 30000*640 sh
    ushort_t* ABF1 = (ushort_t*)(ws + 14400000);           // 30000*128 sh
    ushort_t* XHb  = (ushort_t*)(ws + 16320000);           // 30000*1248 sh
    ushort_t* WT   = (ushort_t*)(ws + 35040000);           // 1248*640 sh
    float* ADST  = ws + 35440000;                          // 120000
    float* ASRC  = ws + 35560000;                          // 120000
    float* ALPHAC= ws + 35680000;                          // 400000 (CSR order)
    float* WD    = ws + 36080000;                          // 4096
    float* WSV   = ws + 36084096;                          // 4096
    float* G     = ws + 36088192;                          // 319488
    float* G1    = ws + 36407680;                          // 262144
    float* G2    = ws + 36669824;                          // 32768
    int*   INDEG = (int*)(ws + 36702592);                  // 30000
    int*   OFF   = (int*)(ws + 36732592);                  // 30001
    int*   CURS  = (int*)(ws + 36762593);                  // 30000
    int*   SLOTS = (int*)(ws + 36792593);                  // E (<=100000)
    int*   SRCS  = (int*)(ws + 36892593);                  // E (<=100000)
    int*   FLAGS = (int*)(ws + 36992593);                  // 2
    int*   GCNT  = (int*)(ws + 36992595);                  // 256
    int*   GSTART= (int*)(ws + 36992851);                  // 257
    // head split-K partials alias the retired H1b region (free after layer 2)
    float* HP1   = ws;                                     // 2,097,152 fl
    float* HP2   = ws + 2100000;                           // 262,144 fl

    dim3 blk(256);

    detect_fmt<<<dim3(1), blk, 0, stream>>>(ei, batch, E, FLAGS);

    hipMemsetAsync(H1b, 0, (size_t)N * 320 * sizeof(ushort_t), stream);
    hipMemsetAsync(H2b, 0, (size_t)N * 640 * sizeof(ushort_t), stream);
    hipMemsetAsync(G, 0, (size_t)N_GRAPHS * 1248 * sizeof(float), stream);
    hipMemsetAsync(INDEG, 0, (size_t)N * sizeof(int), stream);
    hipMemsetAsync(GCNT, 0, N_GRAPHS * sizeof(int), stream);

    csr_hist<<<dim3((E + 255) / 256), blk, 0, stream>>>(ei, FLAGS, INDEG, E);
    csr_scan<<<dim3(1), dim3(1024), 0, stream>>>(INDEG, OFF, CURS);
    csr_fill<<<dim3((E + 255) / 256), blk, 0, stream>>>(ei, FLAGS, CURS, SLOTS, SRCS, E);

    ghist<<<dim3((N + 255) / 256), blk, 0, stream>>>(batch, FLAGS, GCNT);
    gscan<<<dim3(1), blk, 0, stream>>>(GCNT, GSTART);

    conv_pad_bf16<<<dim3(8192), blk, 0, stream>>>(x, ABF1, 78, 128, (long)N);

    struct Layer {
        const void* A; int lda; int K; int isbf;   // node_proj input
        const ushort_t* Abf; int Kp;               // gemm A (padded bf16)
        const float *W, *att, *b;
        int C, HC;
        ushort_t* outb; int ldo;                   // layers 1,2
        int pool;                                  // layer 3
    };
    Layer L[3] = {
        { x,   78,  78,  0, ABF1, 128, W1, att1, b1,  78,  312, H1b, 320, 0 },
        { H1b, 320, 312, 1, H1b,  320, W2, att2, b2, 156,  624, H2b, 640, 0 },
        { H2b, 640, 624, 1, H2b,  640, W3, att3, b3, 312, 1248, nullptr, 0, 1 },
    };

    for (int li = 0; li < 3; ++li) {
        const Layer& l = L[li];
        int nch = l.Kp >> 3;
        wt_bf16<<<dim3((l.HC * nch + 255) / 256), blk, 0, stream>>>(l.W, WT, l.K, l.Kp, l.HC);
        make_watt<<<dim3((l.K * HEADS + 255) / 256), blk, 0, stream>>>(l.W, l.att, WD, WSV, l.K, l.C, l.HC);
        node_proj_any<<<dim3((N + 3) / 4), blk, 0, stream>>>(l.A, l.lda, l.K, l.isbf, WD, WSV, ADST, ASRC, N);
        edge_alpha_csr<<<dim3((E + 255) / 256), blk, 0, stream>>>(SLOTS, ei, FLAGS, ADST, ASRC, ALPHAC, E);

        // one GEMM over all heads: XHb[N][HC] = A @ WT^T  (1D grid + XCD swizzle)
        int ncols = (l.HC + BN - 1) / BN;
        int nrows = (N + BM - 1) / BM;
        gemm_bf16<<<dim3(ncols * nrows), blk, 0, stream>>>(l.Abf, WT, XHb, N, l.HC, l.Kp, ncols);

        if (l.pool) {
            dim3 pg(N_GRAPHS * NSPLIT, (l.HC + 1023) / 1024);
            pool_gather<<<pg, blk, 0, stream>>>(OFF, SRCS, ALPHAC, XHb, l.b,
                                                GSTART, G, l.HC, l.C);
        } else {
            gat_gather_all<<<dim3((N + 3) / 4), blk, 0, stream>>>(
                OFF, SRCS, ALPHAC, XHb, l.b, l.outb, l.ldo, l.HC, l.C);
        }
    }

    // ---- MLP head (f32 exact, split-K with fixed-order reduce) ----
    head_g1_sk <<<dim3(N_GRAPHS / 2, 8), blk, 0, stream>>>(G, Wg1, HP1);
    head_g1_red<<<dim3(1024), blk, 0, stream>>>(HP1, bg1, G1);
    head_g2_sk <<<dim3(N_GRAPHS / 2, 8), blk, 0, stream>>>(G1, Wg2, HP2);
    head_g2_red<<<dim3(128), blk, 0, stream>>>(HP2, bg2, G2);
    head_g3    <<<dim3(N_GRAPHS / 4), blk, 0, stream>>>(G2, Wo, bo, (float*)d_out);
}